// Round 4
// baseline (1055.610 us; speedup 1.0000x reference)
//
#include <hip/hip_runtime.h>
#include <hip/hip_bf16.h>
#include <stdint.h>

#define B_   8
#define L_   2048
#define D_   1024
#define NH_  32
#define M_   16
#define NM_  128
#define HD_  32
#define DI_  2048
#define BL_  16384
#define EPS_ 1e-6f

typedef __attribute__((ext_vector_type(8))) short  s16x8;
typedef __attribute__((ext_vector_type(4))) short  s16x4;
typedef __attribute__((ext_vector_type(8))) __bf16 bf16x8;
typedef __attribute__((ext_vector_type(4))) float  f32x4;

__device__ __forceinline__ float bf2f(short s){
  unsigned u = ((unsigned)(unsigned short)s) << 16;
  return __builtin_bit_cast(float, u);
}
__device__ __forceinline__ short f2bf(float f){
  unsigned u = __builtin_bit_cast(unsigned, f);
  u = u + 0x7FFFu + ((u >> 16) & 1u);   // RNE
  return (short)(u >> 16);
}
__device__ __forceinline__ float rsum16(float v){
  v += __shfl_xor(v, 1); v += __shfl_xor(v, 2);
  v += __shfl_xor(v, 4); v += __shfl_xor(v, 8);
  return v;
}
// async global->LDS, 16B per lane (dest = wave-uniform base + lane*16)
__device__ __forceinline__ void gl16(const void* g, void* l){
  __builtin_amdgcn_global_load_lds(
      (const __attribute__((address_space(1))) void*)g,
      (__attribute__((address_space(3))) void*)l, 16, 0, 0);
}

// ---------------- transpose + fp32->bf16 cast: out(Cc,R) = in(R,Cc)^T ------
__global__ __launch_bounds__(256) void transpose_cast(
    const float* __restrict__ in, short* __restrict__ out, int R, int Cc)
{
  __shared__ float t[32][33];
  const int lx = threadIdx.x & 31, ly = threadIdx.x >> 5;
  const int r0 = blockIdx.y * 32, c0 = blockIdx.x * 32;
  #pragma unroll
  for (int s = 0; s < 4; ++s){
    const int r = ly + s*8;
    t[r][lx] = in[(size_t)(r0 + r)*Cc + c0 + lx];
  }
  __syncthreads();
  #pragma unroll
  for (int s = 0; s < 4; ++s){
    const int r = ly + s*8;
    out[(size_t)(c0 + r)*R + r0 + lx] = f2bf(t[lx][r]);
  }
}

// batched 1024x1024 transposes (4 weights in one launch)
struct TC4 { const float *s0,*s1,*s2,*s3; short *d0,*d1,*d2,*d3; };
__global__ __launch_bounds__(256) void transpose_cast4(TC4 p)
{
  __shared__ float t[32][33];
  const int z = blockIdx.z;
  const float* in = (z==0)?p.s0:(z==1)?p.s1:(z==2)?p.s2:p.s3;
  short* out      = (z==0)?p.d0:(z==1)?p.d1:(z==2)?p.d2:p.d3;
  const int lx = threadIdx.x & 31, ly = threadIdx.x >> 5;
  const int r0 = blockIdx.y * 32, c0 = blockIdx.x * 32;
  #pragma unroll
  for (int s = 0; s < 4; ++s){
    const int r = ly + s*8;
    t[r][lx] = in[(size_t)(r0 + r)*1024 + c0 + lx];
  }
  __syncthreads();
  #pragma unroll
  for (int s = 0; s < 4; ++s){
    const int r = ly + s*8;
    out[(size_t)(c0 + r)*1024 + r0 + lx] = f2bf(t[lx][r]);
  }
}

// ---------------- misc prep: lr_w cast + rope tables -----------------------
__global__ __launch_bounds__(256) void misc_prep(
    const float* __restrict__ lr_w, short* __restrict__ lrwb,
    float* __restrict__ ct, float* __restrict__ st)
{
  const int idx = blockIdx.x*256 + threadIdx.x;
  if (idx < NH_*D_){
    lrwb[idx] = f2bf(lr_w[idx]);
  } else {
    const int k = idx - NH_*D_;       // 0 .. L_*16-1
    const int l = k >> 4, j = k & 15;
    const float inv = powf(10000.f, -(float)j * (1.f/16.f));
    const float fr  = (float)l * inv;
    ct[k] = cosf(fr);
    st[k] = sinf(fr);
  }
}

// ---------------- row layernorm fp32 -> bf16 (D=1024) ----------------------
__global__ __launch_bounds__(256) void ln_rows(
    const float* __restrict__ in, const float* __restrict__ g,
    const float* __restrict__ bta, short* __restrict__ out)
{
  const int row = blockIdx.x, tid = threadIdx.x;
  const float4 v = ((const float4*)(in + (size_t)row*D_))[tid];
  float s  = v.x + v.y + v.z + v.w;
  float s2 = v.x*v.x + v.y*v.y + v.z*v.z + v.w*v.w;
  #pragma unroll
  for (int m = 1; m < 64; m <<= 1){ s += __shfl_xor(s, m); s2 += __shfl_xor(s2, m); }
  __shared__ float rs[4], rq[4];
  if ((tid & 63) == 0){ rs[tid>>6] = s; rq[tid>>6] = s2; }
  __syncthreads();
  s  = rs[0] + rs[1] + rs[2] + rs[3];
  s2 = rq[0] + rq[1] + rq[2] + rq[3];
  const float mu   = s  * (1.f/D_);
  const float var  = s2 * (1.f/D_) - mu*mu;
  const float rstd = rsqrtf(var + EPS_);
  const float4 gg = ((const float4*)g)[tid];
  const float4 bb = ((const float4*)bta)[tid];
  s16x4 o;
  o[0] = f2bf((v.x - mu)*rstd*gg.x + bb.x);
  o[1] = f2bf((v.y - mu)*rstd*gg.y + bb.y);
  o[2] = f2bf((v.z - mu)*rstd*gg.z + bb.z);
  o[3] = f2bf((v.w - mu)*rstd*gg.w + bb.w);
  ((s16x4*)(out + (size_t)row*D_))[tid] = o;
}

// ---------------- row layernorm bf16 -> bf16 (D=1024) ----------------------
__global__ __launch_bounds__(256) void ln_rows_bf(
    const short* __restrict__ in, const float* __restrict__ g,
    const float* __restrict__ bta, short* __restrict__ out)
{
  const int row = blockIdx.x, tid = threadIdx.x;
  const s16x4 v4 = ((const s16x4*)(in + (size_t)row*D_))[tid];
  float v[4];
  #pragma unroll
  for (int e = 0; e < 4; ++e) v[e] = bf2f(v4[e]);
  float s  = v[0]+v[1]+v[2]+v[3];
  float s2 = v[0]*v[0]+v[1]*v[1]+v[2]*v[2]+v[3]*v[3];
  #pragma unroll
  for (int m = 1; m < 64; m <<= 1){ s += __shfl_xor(s, m); s2 += __shfl_xor(s2, m); }
  __shared__ float rs[4], rq[4];
  if ((tid & 63) == 0){ rs[tid>>6] = s; rq[tid>>6] = s2; }
  __syncthreads();
  s  = rs[0] + rs[1] + rs[2] + rs[3];
  s2 = rq[0] + rq[1] + rq[2] + rq[3];
  const float mu   = s  * (1.f/D_);
  const float var  = s2 * (1.f/D_) - mu*mu;
  const float rstd = rsqrtf(var + EPS_);
  const float4 gg = ((const float4*)g)[tid];
  const float4 bb = ((const float4*)bta)[tid];
  s16x4 o;
  #pragma unroll
  for (int e = 0; e < 4; ++e){
    const float gv = (e==0)?gg.x:(e==1)?gg.y:(e==2)?gg.z:gg.w;
    const float bv = (e==0)?bb.x:(e==1)?bb.y:(e==2)?bb.z:bb.w;
    o[e] = f2bf((v[e] - mu)*rstd*gv + bv);
  }
  ((s16x4*)(out + (size_t)row*D_))[tid] = o;
}

// ---------------- bf16 MFMA GEMM: C(Mr,N) = A(Mr,K) @ Bt(N,K)^T ------------
// 128x128 tile, BK=32, 4 waves of 64x64. global_load_lds staging. XCD swizzle.
// QKVOUT: fused RoPE + scan-tile output {q,k,kT,vT} per (b,h,n)
template<int ACT, int OUTBF, int BIAS, int RES, int QKVOUT>
__global__ __launch_bounds__(256) void gemm_bt(
    const short* __restrict__ A, const short* __restrict__ Bt,
    const float* __restrict__ bias, const float* __restrict__ res,
    float* __restrict__ Cf, short* __restrict__ Cb,
    const float* __restrict__ ct, const float* __restrict__ st,
    int Mr, int N, int K)
{
  __shared__ __align__(16) short As[128*32];
  __shared__ __align__(16) short Bs[128*32];
  const int tid  = threadIdx.x;
  const int lane = tid & 63, wid = tid >> 6;
  // XCD-aware bijective swizzle (nwg always % 8 == 0 here)
  const int nwg = gridDim.x * gridDim.y;
  const int wg  = blockIdx.y * gridDim.x + blockIdx.x;
  const int swz = (wg & 7) * (nwg >> 3) + (wg >> 3);
  const int bx  = swz % gridDim.x, by = swz / gridDim.x;
  const int row0 = by * 128, col0 = bx * 128;
  const int wm = (wid >> 1) * 64, wn = (wid & 1) * 64;
  f32x4 acc[4][4] = {};

  const int sr = tid >> 2, sk = (tid & 3) * 8;
  const short* gA0 = A  + (size_t)(row0 + sr)      * K + sk;
  const short* gA1 = A  + (size_t)(row0 + sr + 64) * K + sk;
  const short* gB0 = Bt + (size_t)(col0 + sr)      * K + sk;
  const short* gB1 = Bt + (size_t)(col0 + sr + 64) * K + sk;
  short* lA0 = As + 8*tid;  short* lA1 = As + 2048 + 8*tid;
  short* lB0 = Bs + 8*tid;  short* lB1 = Bs + 2048 + 8*tid;

  const int fr = lane & 15, fk = (lane >> 4) * 8;
  const int nK = K >> 5;
  for (int kt = 0; kt < nK; ++kt){
    __syncthreads();
    const int ko = kt << 5;
    gl16(gA0 + ko, lA0);
    gl16(gA1 + ko, lA1);
    gl16(gB0 + ko, lB0);
    gl16(gB1 + ko, lB1);
    asm volatile("s_waitcnt vmcnt(0)" ::: "memory");
    __syncthreads();
    bf16x8 af[4], bfv[4];
    #pragma unroll
    for (int f = 0; f < 4; ++f){
      af[f]  = __builtin_bit_cast(bf16x8, *(const s16x8*)(As + (wm + f*16 + fr)*32 + fk));
      bfv[f] = __builtin_bit_cast(bf16x8, *(const s16x8*)(Bs + (wn + f*16 + fr)*32 + fk));
    }
    #pragma unroll
    for (int i = 0; i < 4; ++i)
      #pragma unroll
      for (int j = 0; j < 4; ++j)
        acc[i][j] = __builtin_amdgcn_mfma_f32_16x16x32_bf16(af[i], bfv[j], acc[i][j], 0, 0, 0);
  }
  const int cr = (lane >> 4) * 4, cc = lane & 15;
  if (QKVOUT){
    const int part = col0 >> 10;   // 0=q, 1=k, 2=v (uniform per block)
    #pragma unroll
    for (int i = 0; i < 4; ++i){
      const int gr0 = row0 + wm + i*16 + cr;       // ii = cr + r, same nn for r=0..3
      const int bidx = gr0 >> 11, l0 = gr0 & (L_-1);
      const int nn = l0 >> 4;
      if (part < 2){
        #pragma unroll
        for (int jp = 0; jp < 2; ++jp){
          const int gc = col0 + wn + jp*32 + cc;
          const int hh = (gc & 1023) >> 5;
          short* tile = Cb + ((size_t)(bidx*NH_ + hh)*NM_ + nn)*2048;
          s16x4 r0v, r1v;
          #pragma unroll
          for (int r = 0; r < 4; ++r){
            const int l = l0 + r;
            const float cv = ct[l*16 + cc], sv = st[l*16 + cc];
            const float x0 = acc[i][jp*2][r], x1 = acc[i][jp*2+1][r];
            const short q0 = f2bf(x0*cv - x1*sv);
            const short q1 = f2bf(x1*cv + x0*sv);
            tile[part*512 + (cr + r)*32 + cc]      = q0;
            tile[part*512 + (cr + r)*32 + cc + 16] = q1;
            r0v[r] = q0; r1v[r] = q1;
          }
          if (part == 1){
            *(s16x4*)(tile + 1024 + cc*16 + cr)        = r0v;   // kT rows
            *(s16x4*)(tile + 1024 + (cc+16)*16 + cr)   = r1v;
          }
        }
      } else {
        #pragma unroll
        for (int j = 0; j < 4; ++j){
          const int gc = col0 + wn + j*16 + cc;
          const int hh = (gc & 1023) >> 5, dd = gc & 31;
          short* tile = Cb + ((size_t)(bidx*NH_ + hh)*NM_ + nn)*2048;
          s16x4 p;
          #pragma unroll
          for (int r = 0; r < 4; ++r) p[r] = f2bf(acc[i][j][r]);
          *(s16x4*)(tile + 1536 + dd*16 + cr) = p;              // vT rows
        }
      }
    }
    return;
  }
  #pragma unroll
  for (int i = 0; i < 4; ++i){
    #pragma unroll
    for (int j = 0; j < 4; ++j){
      const int gc = col0 + wn + j*16 + cc;
      float bv = 0.f;
      if (BIAS) bv = bias[gc];
      #pragma unroll
      for (int r = 0; r < 4; ++r){
        const int gr = row0 + wm + i*16 + cr + r;
        float v = acc[i][j][r] + bv;
        if (RES) v += res[(size_t)gr*N + gc];
        if (ACT == 1) v = fmaxf(v, 0.f);
        if (OUTBF) Cb[(size_t)gr*N + gc] = f2bf(v);
        else       Cf[(size_t)gr*N + gc] = v;
      }
    }
  }
}

// ---------------- eta: sigmoid(x . lr_w[h] + lr_b[h]) / HD -----------------
__global__ __launch_bounds__(256) void eta_kernel(
    const short* __restrict__ xb, const short* __restrict__ lrwb,
    const float* __restrict__ lr_b, float* __restrict__ eta)
{
  __shared__ __align__(16) short wl[NH_*D_];   // 64 KB
  __shared__ __align__(16) short xr[D_];
  const int tid = threadIdx.x;
  const int wid = tid >> 6, lane = tid & 63;
  #pragma unroll
  for (int s = 0; s < 16; ++s){
    const int e8 = tid + 256*s;
    ((s16x8*)wl)[e8] = ((const s16x8*)lrwb)[e8];
  }
  for (int tk = 0; tk < 32; ++tk){
    const int token = blockIdx.x*32 + tk;
    __syncthreads();
    if (tid < 128) ((s16x8*)xr)[tid] = ((const s16x8*)(xb + (size_t)token*D_))[tid];
    __syncthreads();
    const s16x8 x0 = ((const s16x8*)xr)[lane*2];
    const s16x8 x1 = ((const s16x8*)xr)[lane*2 + 1];
    #pragma unroll 1
    for (int hh = 0; hh < 8; ++hh){
      const int h = wid*8 + hh;
      const s16x8 w0 = ((const s16x8*)(wl + h*D_))[lane*2];
      const s16x8 w1 = ((const s16x8*)(wl + h*D_))[lane*2 + 1];
      float s = 0.f;
      #pragma unroll
      for (int e = 0; e < 8; ++e)
        s += bf2f(x0[e])*bf2f(w0[e]) + bf2f(x1[e])*bf2f(w1[e]);
      #pragma unroll
      for (int m = 1; m < 64; m <<= 1) s += __shfl_xor(s, m);
      if (lane == 0){
        const float v = 1.f/(1.f + __expf(-(s + lr_b[h]))) * (1.f/32.f);
        const int bidx = token >> 11, l = token & (L_-1), n = l >> 4, im = l & 15;
        eta[(((size_t)bidx*NH_ + h)*NM_ + n)*M_ + im] = v;
      }
    }
  }
}

// ---------------- TTT scan v4: 8 chains per block (wave-packed MFMA) --------
// tile layout per (b,h,n), 2048 shorts: q[16][32] | k[16][32] | kT[32][16] | vT[32][16]
struct Pf {
  s16x8 qA, kA, kTq0, kTq1;
  s16x4 kTe0, kTe1, vTe0, vTe1;
  f32x4 lr0, lr1, lr2, lr3;
};

__global__ __launch_bounds__(512, 2) void scan_kernel(
    const short* __restrict__ Q5, const float* __restrict__ eta,
    const float* __restrict__ W1, const float* __restrict__ b1,
    const float* __restrict__ tdelta, const float* __restrict__ lng,
    const float* __restrict__ lnb, short* __restrict__ out)
{
  const int wv = threadIdx.x >> 6;
  const int bh = blockIdx.x * 8 + wv;
  const int h = bh & 31, b = bh >> 5;
  const int lane = threadIdx.x & 63;
  const int li = lane & 15, lh = lane >> 4;

  __shared__ __align__(16) short WTs[8][32*40];   // W^T bf16, pitch 40 shorts
  __shared__ __align__(16) short GTs[8][32*24];   // grad^T bf16, pitch 24
  __shared__ __align__(16) float ATs[8][16*20];   // attn f32, pitch 20
  __shared__ __align__(16) short QLs[8][16*40];   // q row-major, pitch 40
  short* WT = WTs[wv];
  short* GT = GTs[wv];
  float* AT = ATs[wv];
  short* QL = QLs[wv];

  // W in four 16x16 C-layout quadrants: Wq[rb][cb][r] = W[16rb+4lh+r][16cb+li]
  f32x4 Wq[2][2];
  #pragma unroll
  for (int rb = 0; rb < 2; ++rb)
    #pragma unroll
    for (int cb = 0; cb < 2; ++cb)
      #pragma unroll
      for (int r = 0; r < 4; ++r)
        Wq[rb][cb][r] = W1[h*1024 + (16*rb + 4*lh + r)*32 + 16*cb + li];

  float bb[2], lw[2], lbv[2];
  #pragma unroll
  for (int hh = 0; hh < 2; ++hh){
    bb[hh]  = b1[h*32 + 16*hh + li];
    lw[hh]  = lng[h*32 + 16*hh + li];
    lbv[hh] = lnb[h*32 + 16*hh + li];
  }
  const float tok_i = fmaxf(1.f/(float)(li+1) + tdelta[li], 0.f);
  const float lef   = fmaxf(1.f/16.f + tdelta[15], 0.f);

  const short* chain = Q5 + (size_t)bh * (NM_*2048);
  const float* ech   = eta + (size_t)bh * (NM_*16);
  short* outp = out + (size_t)b*L_*D_ + h*32;

  // write W^T bf16 to LDS (for B-fragment reads)
  auto writeWT = [&]{
    #pragma unroll
    for (int rb = 0; rb < 2; ++rb)
      #pragma unroll
      for (int cb = 0; cb < 2; ++cb){
        s16x4 p;
        #pragma unroll
        for (int r = 0; r < 4; ++r) p[r] = f2bf(Wq[rb][cb][r]);
        *(s16x4*)(WT + (16*cb + li)*40 + 16*rb + 4*lh) = p;
      }
  };
  writeWT();

  auto load_tile = [&](int n) -> Pf {
    const short* t = chain + (size_t)n*2048;
    const float* e = ech + n*16;
    Pf p;
    p.qA   = *(const s16x8*)(t + li*32 + 8*lh);
    p.kA   = *(const s16x8*)(t + 512 + li*32 + 8*lh);
    p.kTq0 = *(const s16x8*)(t + 1024 + li*16 + 8*(lh & 1));
    p.kTq1 = *(const s16x8*)(t + 1024 + (16 + li)*16 + 8*(lh & 1));
    p.kTe0 = *(const s16x4*)(t + 1024 + li*16 + 4*lh);
    p.kTe1 = *(const s16x4*)(t + 1024 + (16 + li)*16 + 4*lh);
    p.vTe0 = *(const s16x4*)(t + 1536 + li*16 + 4*lh);
    p.vTe1 = *(const s16x4*)(t + 1536 + (16 + li)*16 + 4*lh);
    p.lr0 = *(const f32x4*)(e);
    p.lr1 = *(const f32x4*)(e + 4);
    p.lr2 = *(const f32x4*)(e + 8);
    p.lr3 = *(const f32x4*)(e + 12);
    return p;
  };

  Pf cur = load_tile(0);
  #pragma unroll 1
  for (int n = 0; n < NM_; ++n){
    Pf nxt = load_tile(n + 1 < NM_ ? n + 1 : NM_ - 1);

    const bf16x8 qAf = __builtin_bit_cast(bf16x8, cur.qA);
    const bf16x8 kAf = __builtin_bit_cast(bf16x8, cur.kA);
    bf16x8 Wf[2];
    Wf[0] = __builtin_bit_cast(bf16x8, *(const s16x8*)(WT + li*40 + 8*lh));
    Wf[1] = __builtin_bit_cast(bf16x8, *(const s16x8*)(WT + (16 + li)*40 + 8*lh));

    // q row-major into LDS for transpose reads at output time
    *(s16x8*)(QL + li*40 + 8*lh) = cur.qA;

    // Z1 = k@W + b ; Y = q@W + b ; a = q@kT
    f32x4 zac[2], yac[2], aac = {};
    #pragma unroll
    for (int hh = 0; hh < 2; ++hh){
      f32x4 c0; c0[0]=bb[hh]; c0[1]=bb[hh]; c0[2]=bb[hh]; c0[3]=bb[hh];
      zac[hh] = __builtin_amdgcn_mfma_f32_16x16x32_bf16(kAf, Wf[hh], c0, 0,0,0);
      yac[hh] = __builtin_amdgcn_mfma_f32_16x16x32_bf16(qAf, Wf[hh], c0, 0,0,0);
    }
    aac = __builtin_amdgcn_mfma_f32_16x16x32_bf16(qAf, kAf, aac, 0,0,0);

    #pragma unroll
    for (int r = 0; r < 4; ++r)
      AT[(4*lh + r)*20 + li] = aac[r];

    // grad = ln_l2_bwd(Z1, v-k), elementwise in C-layout
    float xh[2][4], grad[2][4], rstdv[4];
    #pragma unroll
    for (int r = 0; r < 4; ++r){
      float s  = zac[0][r] + zac[1][r];
      float q2 = zac[0][r]*zac[0][r] + zac[1][r]*zac[1][r];
      s = rsum16(s); q2 = rsum16(q2);
      const float mu  = s * (1.f/32.f);
      const float var = q2 * (1.f/32.f) - mu*mu;
      const float rstd = rsqrtf(var + EPS_);
      rstdv[r] = rstd;
      xh[0][r] = (zac[0][r] - mu) * rstd;
      xh[1][r] = (zac[1][r] - mu) * rstd;
    }
    #pragma unroll
    for (int r = 0; r < 4; ++r){
      const float t0 = bf2f(cur.vTe0[r]) - bf2f(cur.kTe0[r]);
      const float t1 = bf2f(cur.vTe1[r]) - bf2f(cur.kTe1[r]);
      const float g0 = (xh[0][r]*lw[0] + lbv[0] - t0)*lw[0];
      const float g1 = (xh[1][r]*lw[1] + lbv[1] - t1)*lw[1];
      float sg  = rsum16(g0 + g1);
      float sgx = rsum16(g0*xh[0][r] + g1*xh[1][r]);
      const float f = rstdv[r] * (1.f/32.f);
      grad[0][r] = (32.f*g0 - sg - xh[0][r]*sgx) * f;
      grad[1][r] = (32.f*g1 - sg - xh[1][r]*sgx) * f;
    }

    // grad^T bf16 to LDS
    #pragma unroll
    for (int hh = 0; hh < 2; ++hh){
      s16x4 p;
      #pragma unroll
      for (int r = 0; r < 4; ++r) p[r] = f2bf(grad[hh][r]);
      *(s16x4*)(GT + (16*hh + li)*24 + 4*lh) = p;
    }

    // grad B-fragments (rows 16..31 of zero-extended K are 0)
    const s16x8 zz = {};
    bf16x8 gf[2];
    gf[0] = __builtin_bit_cast(bf16x8, (lh < 2) ? *(const s16x8*)(GT + li*24 + 8*lh) : zz);
    gf[1] = __builtin_bit_cast(bf16x8, (lh < 2) ? *(const s16x8*)(GT + (16 + li)*24 + 8*lh) : zz);

    // P fragment: P[i][j] = -tok_i*lr_j*(1+a[i][j])*[j<=i]  (negated for subtraction)
    f32x4 arA = {}, arB = {};
    if (lh < 2){
      arA = *(const f32x4*)(AT + li*20 + 8*lh);
      arB = *(const f32x4*)(AT + li*20 + 8*lh + 4);
    }
    const f32x4 plA = (lh & 1) ? cur.lr2 : cur.lr0;
    const f32x4 plB = (lh & 1) ? cur.lr3 : cur.lr1;
    s16x8 pp;
    #pragma unroll
    for (int jj = 0; jj < 8; ++jj){
      const float av  = (jj < 4) ? arA[jj] : arB[jj - 4];
      const float lrv = (jj < 4) ? plA[jj] : plB[jj - 4];
      const bool ok = (lh < 2) && (8*lh + jj <= li);
      pp[jj] = f2bf(ok ? -tok_i * lrv * (1.f + av) : 0.f);
    }
    const bf16x8 pAf = __builtin_bit_cast(bf16x8, pp);

    // Z1_bar = Y - P@grad
    #pragma unroll
    for (int hh = 0; hh < 2; ++hh)
      yac[hh] = __builtin_amdgcn_mfma_f32_16x16x32_bf16(pAf, gf[hh], yac[hh], 0,0,0);

    // W update: W -= (lef*lr (.) k)^T @ grad  (4 quadrant MFMAs, A pre-negated)
    #pragma unroll
    for (int rb = 0; rb < 2; ++rb){
      const s16x8 kq = rb ? cur.kTq1 : cur.kTq0;
      s16x8 au;
      #pragma unroll
      for (int jj = 0; jj < 8; ++jj){
        const float lrv = (jj < 4) ? plA[jj] : plB[jj - 4];
        au[jj] = f2bf((lh < 2) ? -lef * lrv * bf2f(kq[jj]) : 0.f);
      }
      const bf16x8 af = __builtin_bit_cast(bf16x8, au);
      #pragma unroll
      for (int cb = 0; cb < 2; ++cb)
        Wq[rb][cb] = __builtin_amdgcn_mfma_f32_16x16x32_bf16(af, gf[cb], Wq[rb][cb], 0,0,0);
    }

    // W^T for next step — issued EARLY to shorten the W -> next-z chain
    writeWT();

    // b update: b[c] -= lef * sum_j lr_j * grad[j][c]
    f32x4 lrq;
    { const f32x4 t0 = (lh & 1) ? cur.lr1 : cur.lr0;
      const f32x4 t1 = (lh & 1) ? cur.lr3 : cur.lr2;
      lrq = (lh & 2) ? t1 : t0; }
    #pragma unroll
    for (int hh = 0; hh < 2; ++hh){
      float t = 0.f;
      #pragma unroll
      for (int r = 0; r < 4; ++r) t += lrq[r]*grad[hh][r];
      t += __shfl_xor(t, 16); t += __shfl_xor(t, 32);
      bb[hh] -= lef * t;
    }

    // out = q + ln_fwd(Z1_bar)
    #pragma unroll
    for (int r = 0; r < 4; ++r){
      float s  = yac[0][r] + yac[1][r];
      float q2 = yac[0][r]*yac[0][r] + yac[1][r]*yac[1][r];
      s = rsum16(s); q2 = rsum16(q2);
      const float mu   = s * (1.f/32.f);
      const float var  = q2 * (1.f/32.f) - mu*mu;
      const float rstd = rsqrtf(var + EPS_);
      const int row = 4*lh + r;
      #pragma unroll
      for (int hh = 0; hh < 2; ++hh){
        const float qv = bf2f(QL[row*40 + 16*hh + li]);
        const float o  = qv + (yac[hh][r] - mu)*rstd*lw[hh] + lbv[hh];
        outp[(size_t)(n*16 + row)*D_ + 16*hh + li] = f2bf(o);
      }
    }

    cur = nxt;
  }
}

// ---------------------------------------------------------------------------
extern "C" void kernel_launch(void* const* d_in, const int* in_sizes, int n_in,
                              void* d_out, int out_size, void* d_ws, size_t ws_size,
                              hipStream_t stream)
{
  const float* enc    = (const float*)d_in[0];
  const float* ln0_g  = (const float*)d_in[1];
  const float* ln0_b  = (const float*)d_in[2];
  const float* Wq     = (const float*)d_in[3];
  const float* Wk     = (const float*)d_in[4];
  const float* Wv     = (const float*)d_in[5];
  const float* Wo     = (const float*)d_in[6];
  const float* W1     = (const float*)d_in[7];
  const float* b1     = (const float*)d_in[8];
  const float* tdelta = (const float*)d_in[9];
  const float* lr_w   = (const float*)d_in[10];
  const float* lr_b   = (const float*)d_in[11];
  const float* ttt_g  = (const float*)d_in[12];
  const float* ttt_b  = (const float*)d_in[13];
  const float* post_g = (const float*)d_in[14];
  const float* post_b = (const float*)d_in[15];
  const float* ffn_g  = (const float*)d_in[16];
  const float* ffn_b  = (const float*)d_in[17];
  const float* fw1    = (const float*)d_in[18];
  const float* fb1    = (const float*)d_in[19];
  const float* fw2    = (const float*)d_in[20];
  const float* fb2    = (const float*)d_in[21];

  char* ws = (char*)d_ws;
  short* Q5    = (short*)(ws + 0);            // 134,217,728 B (scan tiles)
  short* XB    = (short*)(ws + 134217728);    //  33,554,432 B
  short* SCANB = (short*)(ws + 134217728);    //  alias XB (XB dead pre-scan)
  short* WQKVT = (short*)(ws + 167772160);    //   6,291,456 B
  short* WOT   = (short*)(ws + 174063616);    //   2,097,152 B
  short* FW1T  = (short*)(ws + 176160768);    //   4,194,304 B
  short* FW2T  = (short*)(ws + 180355072);    //   4,194,304 B
  short* LRWB  = (short*)(ws + 184549376);    //      65,536 B
  float* CT    = (float*)(ws + 184614912);    //     131,072 B
  float* ST    = (float*)(ws + 184745984);    //     131,072 B
  float* ETA   = (float*)(ws + 184877056);    //   2,097,152 B
  short* YB    = (short*)(ws + 0);            // alias Q5 (post-scan)
  short* HB    = (short*)(ws + 33554432);     // alias Q5
  short* T1    = (short*)(ws + 67108864);     // alias Q5
  float* R2    = (float*)d_out;

  dim3 b256(256);
  TC4 tc;
  tc.s0 = Wq; tc.s1 = Wk; tc.s2 = Wv; tc.s3 = Wo;
  tc.d0 = WQKVT; tc.d1 = WQKVT + 1048576; tc.d2 = WQKVT + 2097152; tc.d3 = WOT;
  transpose_cast4<<<dim3(32,32,4), b256, 0, stream>>>(tc);
  transpose_cast<<<dim3(64,32), b256, 0, stream>>>(fw1, FW1T, D_, DI_);
  transpose_cast<<<dim3(32,64), b256, 0, stream>>>(fw2, FW2T, DI_, D_);
  misc_prep<<<dim3(256), b256, 0, stream>>>(lr_w, LRWB, CT, ST);

  ln_rows<<<BL_, b256, 0, stream>>>(enc, ln0_g, ln0_b, XB);
  gemm_bt<0,0,0,0,1><<<dim3(24,128), b256, 0, stream>>>(XB, WQKVT, nullptr, nullptr,
                                                        nullptr, Q5, CT, ST, BL_, 3072, D_);
  eta_kernel<<<dim3(512), b256, 0, stream>>>(XB, LRWB, lr_b, ETA);
  scan_kernel<<<dim3(32), dim3(512), 0, stream>>>(Q5, ETA, W1, b1, tdelta,
                                                  ttt_g, ttt_b, SCANB);
  ln_rows_bf<<<BL_, b256, 0, stream>>>(SCANB, post_g, post_b, YB);
  gemm_bt<0,0,0,1,0><<<dim3(8,128), b256, 0, stream>>>(YB, WOT, nullptr, enc,
                                                       R2, nullptr, nullptr, nullptr, BL_, D_, D_);
  ln_rows<<<BL_, b256, 0, stream>>>(R2, ffn_g, ffn_b, HB);
  gemm_bt<1,1,1,0,0><<<dim3(16,128), b256, 0, stream>>>(HB, FW1T, fb1, nullptr,
                                                        nullptr, T1, nullptr, nullptr, BL_, DI_, D_);
  gemm_bt<0,0,1,1,0><<<dim3(8,128), b256, 0, stream>>>(T1, FW2T, fb2, R2,
                                                       R2, nullptr, nullptr, nullptr, BL_, D_, DI_);
}

// Round 5
// 850.409 us; speedup vs baseline: 1.2413x; 1.2413x over previous
//
#include <hip/hip_runtime.h>
#include <hip/hip_bf16.h>
#include <stdint.h>

#define B_   8
#define L_   2048
#define D_   1024
#define NH_  32
#define M_   16
#define NM_  128
#define HD_  32
#define DI_  2048
#define BL_  16384
#define EPS_ 1e-6f

typedef __attribute__((ext_vector_type(8))) short  s16x8;
typedef __attribute__((ext_vector_type(4))) short  s16x4;
typedef __attribute__((ext_vector_type(8))) __bf16 bf16x8;
typedef __attribute__((ext_vector_type(4))) float  f32x4;
typedef __attribute__((ext_vector_type(4))) unsigned u32x4;

__device__ __forceinline__ float bf2f(short s){
  unsigned u = ((unsigned)(unsigned short)s) << 16;
  return __builtin_bit_cast(float, u);
}
__device__ __forceinline__ short f2bf(float f){
  unsigned u = __builtin_bit_cast(unsigned, f);
  u = u + 0x7FFFu + ((u >> 16) & 1u);   // RNE
  return (short)(u >> 16);
}
// pack 2 f32 -> 2 bf16 in one VALU op
__device__ __forceinline__ unsigned cvtpk(float lo, float hi){
  unsigned r;
  asm("v_cvt_pk_bf16_f32 %0, %1, %2" : "=v"(r) : "v"(lo), "v"(hi));
  return r;
}
// DPP row_ror reduction across 16-lane rows (VALU only, no LDS pipe)
template<int N>
__device__ __forceinline__ float ror_add(float v){
  const int y = __builtin_amdgcn_update_dpp(
      0, __builtin_bit_cast(int, v), 0x120 + N, 0xF, 0xF, true);
  return v + __builtin_bit_cast(float, y);
}
__device__ __forceinline__ float rsum16d(float v){
  v = ror_add<1>(v); v = ror_add<2>(v); v = ror_add<4>(v); v = ror_add<8>(v);
  return v;
}
// async global->LDS, 16B per lane (dest = wave-uniform base + lane*16)
__device__ __forceinline__ void gl16(const void* g, void* l){
  __builtin_amdgcn_global_load_lds(
      (const __attribute__((address_space(1))) void*)g,
      (__attribute__((address_space(3))) void*)l, 16, 0, 0);
}

// ---------------- transpose + fp32->bf16 cast: out(Cc,R) = in(R,Cc)^T ------
__global__ __launch_bounds__(256) void transpose_cast(
    const float* __restrict__ in, short* __restrict__ out, int R, int Cc)
{
  __shared__ float t[32][33];
  const int lx = threadIdx.x & 31, ly = threadIdx.x >> 5;
  const int r0 = blockIdx.y * 32, c0 = blockIdx.x * 32;
  #pragma unroll
  for (int s = 0; s < 4; ++s){
    const int r = ly + s*8;
    t[r][lx] = in[(size_t)(r0 + r)*Cc + c0 + lx];
  }
  __syncthreads();
  #pragma unroll
  for (int s = 0; s < 4; ++s){
    const int r = ly + s*8;
    out[(size_t)(c0 + r)*R + r0 + lx] = f2bf(t[lx][r]);
  }
}

// batched 1024x1024 transposes (4 weights in one launch)
struct TC4 { const float *s0,*s1,*s2,*s3; short *d0,*d1,*d2,*d3; };
__global__ __launch_bounds__(256) void transpose_cast4(TC4 p)
{
  __shared__ float t[32][33];
  const int z = blockIdx.z;
  const float* in = (z==0)?p.s0:(z==1)?p.s1:(z==2)?p.s2:p.s3;
  short* out      = (z==0)?p.d0:(z==1)?p.d1:(z==2)?p.d2:p.d3;
  const int lx = threadIdx.x & 31, ly = threadIdx.x >> 5;
  const int r0 = blockIdx.y * 32, c0 = blockIdx.x * 32;
  #pragma unroll
  for (int s = 0; s < 4; ++s){
    const int r = ly + s*8;
    t[r][lx] = in[(size_t)(r0 + r)*1024 + c0 + lx];
  }
  __syncthreads();
  #pragma unroll
  for (int s = 0; s < 4; ++s){
    const int r = ly + s*8;
    out[(size_t)(c0 + r)*1024 + r0 + lx] = f2bf(t[lx][r]);
  }
}

// ---------------- misc prep: lr_w cast + rope tables -----------------------
__global__ __launch_bounds__(256) void misc_prep(
    const float* __restrict__ lr_w, short* __restrict__ lrwb,
    float* __restrict__ ct, float* __restrict__ st)
{
  const int idx = blockIdx.x*256 + threadIdx.x;
  if (idx < NH_*D_){
    lrwb[idx] = f2bf(lr_w[idx]);
  } else {
    const int k = idx - NH_*D_;       // 0 .. L_*16-1
    const int l = k >> 4, j = k & 15;
    const float inv = powf(10000.f, -(float)j * (1.f/16.f));
    const float fr  = (float)l * inv;
    ct[k] = cosf(fr);
    st[k] = sinf(fr);
  }
}

// ---------------- row layernorm fp32 -> bf16 (D=1024) ----------------------
__global__ __launch_bounds__(256) void ln_rows(
    const float* __restrict__ in, const float* __restrict__ g,
    const float* __restrict__ bta, short* __restrict__ out)
{
  const int row = blockIdx.x, tid = threadIdx.x;
  const float4 v = ((const float4*)(in + (size_t)row*D_))[tid];
  float s  = v.x + v.y + v.z + v.w;
  float s2 = v.x*v.x + v.y*v.y + v.z*v.z + v.w*v.w;
  #pragma unroll
  for (int m = 1; m < 64; m <<= 1){ s += __shfl_xor(s, m); s2 += __shfl_xor(s2, m); }
  __shared__ float rs[4], rq[4];
  if ((tid & 63) == 0){ rs[tid>>6] = s; rq[tid>>6] = s2; }
  __syncthreads();
  s  = rs[0] + rs[1] + rs[2] + rs[3];
  s2 = rq[0] + rq[1] + rq[2] + rq[3];
  const float mu   = s  * (1.f/D_);
  const float var  = s2 * (1.f/D_) - mu*mu;
  const float rstd = rsqrtf(var + EPS_);
  const float4 gg = ((const float4*)g)[tid];
  const float4 bb = ((const float4*)bta)[tid];
  s16x4 o;
  o[0] = f2bf((v.x - mu)*rstd*gg.x + bb.x);
  o[1] = f2bf((v.y - mu)*rstd*gg.y + bb.y);
  o[2] = f2bf((v.z - mu)*rstd*gg.z + bb.z);
  o[3] = f2bf((v.w - mu)*rstd*gg.w + bb.w);
  ((s16x4*)(out + (size_t)row*D_))[tid] = o;
}

// ---------------- row layernorm bf16 -> bf16 (D=1024) ----------------------
__global__ __launch_bounds__(256) void ln_rows_bf(
    const short* __restrict__ in, const float* __restrict__ g,
    const float* __restrict__ bta, short* __restrict__ out)
{
  const int row = blockIdx.x, tid = threadIdx.x;
  const s16x4 v4 = ((const s16x4*)(in + (size_t)row*D_))[tid];
  float v[4];
  #pragma unroll
  for (int e = 0; e < 4; ++e) v[e] = bf2f(v4[e]);
  float s  = v[0]+v[1]+v[2]+v[3];
  float s2 = v[0]*v[0]+v[1]*v[1]+v[2]*v[2]+v[3]*v[3];
  #pragma unroll
  for (int m = 1; m < 64; m <<= 1){ s += __shfl_xor(s, m); s2 += __shfl_xor(s2, m); }
  __shared__ float rs[4], rq[4];
  if ((tid & 63) == 0){ rs[tid>>6] = s; rq[tid>>6] = s2; }
  __syncthreads();
  s  = rs[0] + rs[1] + rs[2] + rs[3];
  s2 = rq[0] + rq[1] + rq[2] + rq[3];
  const float mu   = s  * (1.f/D_);
  const float var  = s2 * (1.f/D_) - mu*mu;
  const float rstd = rsqrtf(var + EPS_);
  const float4 gg = ((const float4*)g)[tid];
  const float4 bb = ((const float4*)bta)[tid];
  s16x4 o;
  #pragma unroll
  for (int e = 0; e < 4; ++e){
    const float gv = (e==0)?gg.x:(e==1)?gg.y:(e==2)?gg.z:gg.w;
    const float bv = (e==0)?bb.x:(e==1)?bb.y:(e==2)?bb.z:bb.w;
    o[e] = f2bf((v[e] - mu)*rstd*gv + bv);
  }
  ((s16x4*)(out + (size_t)row*D_))[tid] = o;
}

// ---------------- bf16 MFMA GEMM: C(Mr,N) = A(Mr,K) @ Bt(N,K)^T ------------
// 128x128 tile, BK=32, 4 waves of 64x64. global_load_lds staging. XCD swizzle.
// QKVOUT: fused RoPE + scan-tile output {q,k,kT,vT} per (b,h,n)
template<int ACT, int OUTBF, int BIAS, int RES, int QKVOUT>
__global__ __launch_bounds__(256) void gemm_bt(
    const short* __restrict__ A, const short* __restrict__ Bt,
    const float* __restrict__ bias, const float* __restrict__ res,
    float* __restrict__ Cf, short* __restrict__ Cb,
    const float* __restrict__ ct, const float* __restrict__ st,
    int Mr, int N, int K)
{
  __shared__ __align__(16) short As[128*32];
  __shared__ __align__(16) short Bs[128*32];
  const int tid  = threadIdx.x;
  const int lane = tid & 63, wid = tid >> 6;
  // XCD-aware bijective swizzle (nwg always % 8 == 0 here)
  const int nwg = gridDim.x * gridDim.y;
  const int wg  = blockIdx.y * gridDim.x + blockIdx.x;
  const int swz = (wg & 7) * (nwg >> 3) + (wg >> 3);
  const int bx  = swz % gridDim.x, by = swz / gridDim.x;
  const int row0 = by * 128, col0 = bx * 128;
  const int wm = (wid >> 1) * 64, wn = (wid & 1) * 64;
  f32x4 acc[4][4] = {};

  const int sr = tid >> 2, sk = (tid & 3) * 8;
  const short* gA0 = A  + (size_t)(row0 + sr)      * K + sk;
  const short* gA1 = A  + (size_t)(row0 + sr + 64) * K + sk;
  const short* gB0 = Bt + (size_t)(col0 + sr)      * K + sk;
  const short* gB1 = Bt + (size_t)(col0 + sr + 64) * K + sk;
  short* lA0 = As + 8*tid;  short* lA1 = As + 2048 + 8*tid;
  short* lB0 = Bs + 8*tid;  short* lB1 = Bs + 2048 + 8*tid;

  const int fr = lane & 15, fk = (lane >> 4) * 8;
  const int nK = K >> 5;
  for (int kt = 0; kt < nK; ++kt){
    __syncthreads();
    const int ko = kt << 5;
    gl16(gA0 + ko, lA0);
    gl16(gA1 + ko, lA1);
    gl16(gB0 + ko, lB0);
    gl16(gB1 + ko, lB1);
    asm volatile("s_waitcnt vmcnt(0)" ::: "memory");
    __syncthreads();
    bf16x8 af[4], bfv[4];
    #pragma unroll
    for (int f = 0; f < 4; ++f){
      af[f]  = __builtin_bit_cast(bf16x8, *(const s16x8*)(As + (wm + f*16 + fr)*32 + fk));
      bfv[f] = __builtin_bit_cast(bf16x8, *(const s16x8*)(Bs + (wn + f*16 + fr)*32 + fk));
    }
    #pragma unroll
    for (int i = 0; i < 4; ++i)
      #pragma unroll
      for (int j = 0; j < 4; ++j)
        acc[i][j] = __builtin_amdgcn_mfma_f32_16x16x32_bf16(af[i], bfv[j], acc[i][j], 0, 0, 0);
  }
  const int cr = (lane >> 4) * 4, cc = lane & 15;
  if (QKVOUT){
    const int part = col0 >> 10;   // 0=q, 1=k, 2=v (uniform per block)
    #pragma unroll
    for (int i = 0; i < 4; ++i){
      const int gr0 = row0 + wm + i*16 + cr;       // ii = cr + r, same nn for r=0..3
      const int bidx = gr0 >> 11, l0 = gr0 & (L_-1);
      const int nn = l0 >> 4;
      if (part < 2){
        #pragma unroll
        for (int jp = 0; jp < 2; ++jp){
          const int gc = col0 + wn + jp*32 + cc;
          const int hh = (gc & 1023) >> 5;
          short* tile = Cb + ((size_t)(bidx*NH_ + hh)*NM_ + nn)*2048;
          s16x4 r0v, r1v;
          #pragma unroll
          for (int r = 0; r < 4; ++r){
            const int l = l0 + r;
            const float cv = ct[l*16 + cc], sv = st[l*16 + cc];
            const float x0 = acc[i][jp*2][r], x1 = acc[i][jp*2+1][r];
            const short q0 = f2bf(x0*cv - x1*sv);
            const short q1 = f2bf(x1*cv + x0*sv);
            tile[part*512 + (cr + r)*32 + cc]      = q0;
            tile[part*512 + (cr + r)*32 + cc + 16] = q1;
            r0v[r] = q0; r1v[r] = q1;
          }
          if (part == 1){
            *(s16x4*)(tile + 1024 + cc*16 + cr)        = r0v;   // kT rows
            *(s16x4*)(tile + 1024 + (cc+16)*16 + cr)   = r1v;
          }
        }
      } else {
        #pragma unroll
        for (int j = 0; j < 4; ++j){
          const int gc = col0 + wn + j*16 + cc;
          const int hh = (gc & 1023) >> 5, dd = gc & 31;
          short* tile = Cb + ((size_t)(bidx*NH_ + hh)*NM_ + nn)*2048;
          s16x4 p;
          #pragma unroll
          for (int r = 0; r < 4; ++r) p[r] = f2bf(acc[i][j][r]);
          *(s16x4*)(tile + 1536 + dd*16 + cr) = p;              // vT rows
        }
      }
    }
    return;
  }
  #pragma unroll
  for (int i = 0; i < 4; ++i){
    #pragma unroll
    for (int j = 0; j < 4; ++j){
      const int gc = col0 + wn + j*16 + cc;
      float bv = 0.f;
      if (BIAS) bv = bias[gc];
      #pragma unroll
      for (int r = 0; r < 4; ++r){
        const int gr = row0 + wm + i*16 + cr + r;
        float v = acc[i][j][r] + bv;
        if (RES) v += res[(size_t)gr*N + gc];
        if (ACT == 1) v = fmaxf(v, 0.f);
        if (OUTBF) Cb[(size_t)gr*N + gc] = f2bf(v);
        else       Cf[(size_t)gr*N + gc] = v;
      }
    }
  }
}

// ---------------- eta: sigmoid(x . lr_w[h] + lr_b[h]) / HD -----------------
__global__ __launch_bounds__(256) void eta_kernel(
    const short* __restrict__ xb, const short* __restrict__ lrwb,
    const float* __restrict__ lr_b, float* __restrict__ eta)
{
  __shared__ __align__(16) short wl[NH_*D_];   // 64 KB
  __shared__ __align__(16) short xr[D_];
  const int tid = threadIdx.x;
  const int wid = tid >> 6, lane = tid & 63;
  #pragma unroll
  for (int s = 0; s < 16; ++s){
    const int e8 = tid + 256*s;
    ((s16x8*)wl)[e8] = ((const s16x8*)lrwb)[e8];
  }
  for (int tk = 0; tk < 32; ++tk){
    const int token = blockIdx.x*32 + tk;
    __syncthreads();
    if (tid < 128) ((s16x8*)xr)[tid] = ((const s16x8*)(xb + (size_t)token*D_))[tid];
    __syncthreads();
    const s16x8 x0 = ((const s16x8*)xr)[lane*2];
    const s16x8 x1 = ((const s16x8*)xr)[lane*2 + 1];
    #pragma unroll 1
    for (int hh = 0; hh < 8; ++hh){
      const int h = wid*8 + hh;
      const s16x8 w0 = ((const s16x8*)(wl + h*D_))[lane*2];
      const s16x8 w1 = ((const s16x8*)(wl + h*D_))[lane*2 + 1];
      float s = 0.f;
      #pragma unroll
      for (int e = 0; e < 8; ++e)
        s += bf2f(x0[e])*bf2f(w0[e]) + bf2f(x1[e])*bf2f(w1[e]);
      #pragma unroll
      for (int m = 1; m < 64; m <<= 1) s += __shfl_xor(s, m);
      if (lane == 0){
        const float v = 1.f/(1.f + __expf(-(s + lr_b[h]))) * (1.f/32.f);
        const int bidx = token >> 11, l = token & (L_-1), n = l >> 4, im = l & 15;
        eta[(((size_t)bidx*NH_ + h)*NM_ + n)*M_ + im] = v;
      }
    }
  }
}

// ---------------- TTT scan v5: 1 wave/(b,h), DPP reduce + bperm layout ------
// tile layout per (b,h,n), 2048 shorts: q[16][32] | k[16][32] | kT[32][16] | vT[32][16]
struct Pf {
  s16x8 qA, kA, kTq0, kTq1;
  s16x4 kTe0, kTe1, vTe0, vTe1;
  f32x4 lr0, lr1, lr2, lr3;
};

__global__ __launch_bounds__(64) void scan_kernel(
    const short* __restrict__ Q5, const float* __restrict__ eta,
    const float* __restrict__ W1, const float* __restrict__ b1,
    const float* __restrict__ tdelta, const float* __restrict__ lng,
    const float* __restrict__ lnb, short* __restrict__ out)
{
  const int bh = blockIdx.x;
  const int h = bh & 31, b = bh >> 5;
  const int lane = threadIdx.x;
  const int li = lane & 15, lh = lane >> 4;

  __shared__ __align__(16) short QL[16*40];   // q row-major, pitch 40
  __shared__ __align__(16) float AT[16*20];   // attn f32, pitch 20

  // W in four 16x16 C-layout quadrants: Wq[rb][cb][r] = W[16rb+4lh+r][16cb+li]
  f32x4 Wq[2][2];
  #pragma unroll
  for (int rb = 0; rb < 2; ++rb)
    #pragma unroll
    for (int cb = 0; cb < 2; ++cb)
      #pragma unroll
      for (int r = 0; r < 4; ++r)
        Wq[rb][cb][r] = W1[h*1024 + (16*rb + 4*lh + r)*32 + 16*cb + li];

  float bb[2], lw[2], lbv[2];
  #pragma unroll
  for (int hh = 0; hh < 2; ++hh){
    bb[hh]  = b1[h*32 + 16*hh + li];
    lw[hh]  = lng[h*32 + 16*hh + li];
    lbv[hh] = lnb[h*32 + 16*hh + li];
  }
  const float tok_i = fmaxf(1.f/(float)(li+1) + tdelta[li], 0.f);
  const float lef   = fmaxf(1.f/16.f + tdelta[15], 0.f);

  // bpermute byte addrs (src_lane * 4)
  const int wa0 = ((lh & 1)*32 + li)*4;           // W^T gather
  const int wa1 = wa0 + 64;
  const int ga0 = ((lh*32 + li) & 63)*4;          // grad^T gather
  const int ga1 = ((lh*32 + 16 + li) & 63)*4;

  const short* chain = Q5 + (size_t)bh * (NM_*2048);
  const float* ech   = eta + (size_t)bh * (NM_*16);
  short* outp = out + (size_t)b*L_*D_ + h*32;

  auto load_tile = [&](int n) -> Pf {
    const short* t = chain + (size_t)n*2048;
    const float* e = ech + n*16;
    Pf p;
    p.qA   = *(const s16x8*)(t + li*32 + 8*lh);
    p.kA   = *(const s16x8*)(t + 512 + li*32 + 8*lh);
    p.kTq0 = *(const s16x8*)(t + 1024 + li*16 + 8*(lh & 1));
    p.kTq1 = *(const s16x8*)(t + 1024 + (16 + li)*16 + 8*(lh & 1));
    p.kTe0 = *(const s16x4*)(t + 1024 + li*16 + 4*lh);
    p.kTe1 = *(const s16x4*)(t + 1024 + (16 + li)*16 + 4*lh);
    p.vTe0 = *(const s16x4*)(t + 1536 + li*16 + 4*lh);
    p.vTe1 = *(const s16x4*)(t + 1536 + (16 + li)*16 + 4*lh);
    p.lr0 = *(const f32x4*)(e);
    p.lr1 = *(const f32x4*)(e + 4);
    p.lr2 = *(const f32x4*)(e + 8);
    p.lr3 = *(const f32x4*)(e + 12);
    return p;
  };

  Pf cur = load_tile(0);
  #pragma unroll 1
  for (int n = 0; n < NM_; ++n){
    Pf nxt = load_tile(n + 1 < NM_ ? n + 1 : NM_ - 1);

    // ---- Wf (B-frag of W) from Wq registers: cvt_pk + ds_bpermute
    unsigned wpk[2][2][2];
    #pragma unroll
    for (int rb = 0; rb < 2; ++rb)
      #pragma unroll
      for (int cb = 0; cb < 2; ++cb){
        wpk[rb][cb][0] = cvtpk(Wq[rb][cb][0], Wq[rb][cb][1]);
        wpk[rb][cb][1] = cvtpk(Wq[rb][cb][2], Wq[rb][cb][3]);
      }
    const bool rbs = (lh & 2) != 0;
    bf16x8 Wf[2];
    #pragma unroll
    for (int hh = 0; hh < 2; ++hh){
      const int a00 = __builtin_amdgcn_ds_bpermute(wa0, (int)wpk[0][hh][0]);
      const int a10 = __builtin_amdgcn_ds_bpermute(wa0, (int)wpk[1][hh][0]);
      const int a01 = __builtin_amdgcn_ds_bpermute(wa0, (int)wpk[0][hh][1]);
      const int a11 = __builtin_amdgcn_ds_bpermute(wa0, (int)wpk[1][hh][1]);
      const int c00 = __builtin_amdgcn_ds_bpermute(wa1, (int)wpk[0][hh][0]);
      const int c10 = __builtin_amdgcn_ds_bpermute(wa1, (int)wpk[1][hh][0]);
      const int c01 = __builtin_amdgcn_ds_bpermute(wa1, (int)wpk[0][hh][1]);
      const int c11 = __builtin_amdgcn_ds_bpermute(wa1, (int)wpk[1][hh][1]);
      u32x4 wv;
      wv[0] = (unsigned)(rbs ? a10 : a00);
      wv[1] = (unsigned)(rbs ? a11 : a01);
      wv[2] = (unsigned)(rbs ? c10 : c00);
      wv[3] = (unsigned)(rbs ? c11 : c01);
      Wf[hh] = __builtin_bit_cast(bf16x8, wv);
    }

    const bf16x8 qAf = __builtin_bit_cast(bf16x8, cur.qA);
    const bf16x8 kAf = __builtin_bit_cast(bf16x8, cur.kA);

    // q row-major into LDS for transpose reads at output time
    *(s16x8*)(QL + li*40 + 8*lh) = cur.qA;

    // Z1 = k@W + b ; Y = q@W + b ; a = q@kT
    f32x4 zac[2], yac[2], aac = {};
    #pragma unroll
    for (int hh = 0; hh < 2; ++hh){
      f32x4 c0; c0[0]=bb[hh]; c0[1]=bb[hh]; c0[2]=bb[hh]; c0[3]=bb[hh];
      zac[hh] = __builtin_amdgcn_mfma_f32_16x16x32_bf16(kAf, Wf[hh], c0, 0,0,0);
      yac[hh] = __builtin_amdgcn_mfma_f32_16x16x32_bf16(qAf, Wf[hh], c0, 0,0,0);
    }
    aac = __builtin_amdgcn_mfma_f32_16x16x32_bf16(qAf, kAf, aac, 0,0,0);

    #pragma unroll
    for (int r = 0; r < 4; ++r)
      AT[(4*lh + r)*20 + li] = aac[r];

    // grad = ln_l2_bwd(Z1, v-k), elementwise in C-layout (DPP reductions)
    float xh[2][4], grad[2][4], rstdv[4];
    #pragma unroll
    for (int r = 0; r < 4; ++r){
      float s  = rsum16d(zac[0][r] + zac[1][r]);
      float q2 = rsum16d(zac[0][r]*zac[0][r] + zac[1][r]*zac[1][r]);
      const float mu  = s * (1.f/32.f);
      const float var = q2 * (1.f/32.f) - mu*mu;
      const float rstd = rsqrtf(var + EPS_);
      rstdv[r] = rstd;
      xh[0][r] = (zac[0][r] - mu) * rstd;
      xh[1][r] = (zac[1][r] - mu) * rstd;
    }
    #pragma unroll
    for (int r = 0; r < 4; ++r){
      const float t0 = bf2f(cur.vTe0[r]) - bf2f(cur.kTe0[r]);
      const float t1 = bf2f(cur.vTe1[r]) - bf2f(cur.kTe1[r]);
      const float g0 = (xh[0][r]*lw[0] + lbv[0] - t0)*lw[0];
      const float g1 = (xh[1][r]*lw[1] + lbv[1] - t1)*lw[1];
      const float sg  = rsum16d(g0 + g1);
      const float sgx = rsum16d(g0*xh[0][r] + g1*xh[1][r]);
      const float f = rstdv[r] * (1.f/32.f);
      grad[0][r] = (32.f*g0 - sg - xh[0][r]*sgx) * f;
      grad[1][r] = (32.f*g1 - sg - xh[1][r]*sgx) * f;
    }

    // ---- gf (B-frag of grad) from registers: cvt_pk + ds_bpermute
    unsigned gpk[2][2];
    gpk[0][0] = cvtpk(grad[0][0], grad[0][1]);
    gpk[0][1] = cvtpk(grad[0][2], grad[0][3]);
    gpk[1][0] = cvtpk(grad[1][0], grad[1][1]);
    gpk[1][1] = cvtpk(grad[1][2], grad[1][3]);
    bf16x8 gf[2];
    #pragma unroll
    for (int hh = 0; hh < 2; ++hh){
      u32x4 gv;
      gv[0] = (unsigned)__builtin_amdgcn_ds_bpermute(ga0, (int)gpk[hh][0]);
      gv[1] = (unsigned)__builtin_amdgcn_ds_bpermute(ga0, (int)gpk[hh][1]);
      gv[2] = (unsigned)__builtin_amdgcn_ds_bpermute(ga1, (int)gpk[hh][0]);
      gv[3] = (unsigned)__builtin_amdgcn_ds_bpermute(ga1, (int)gpk[hh][1]);
      gf[hh] = __builtin_bit_cast(bf16x8, gv);
    }

    // P fragment: P[i][j] = -tok_i*lr_j*(1+a[i][j])*[j<=i]  (negated)
    f32x4 arA = {}, arB = {};
    if (lh < 2){
      arA = *(const f32x4*)(AT + li*20 + 8*lh);
      arB = *(const f32x4*)(AT + li*20 + 8*lh + 4);
    }
    const f32x4 plA = (lh & 1) ? cur.lr2 : cur.lr0;
    const f32x4 plB = (lh & 1) ? cur.lr3 : cur.lr1;
    float pv[8];
    #pragma unroll
    for (int jj = 0; jj < 8; ++jj){
      const float av  = (jj < 4) ? arA[jj] : arB[jj - 4];
      const float lrv = (jj < 4) ? plA[jj] : plB[jj - 4];
      const bool ok = (lh < 2) && (8*lh + jj <= li);
      pv[jj] = ok ? -tok_i * lrv * (1.f + av) : 0.f;
    }
    u32x4 ppv;
    ppv[0] = cvtpk(pv[0], pv[1]); ppv[1] = cvtpk(pv[2], pv[3]);
    ppv[2] = cvtpk(pv[4], pv[5]); ppv[3] = cvtpk(pv[6], pv[7]);
    const bf16x8 pAf = __builtin_bit_cast(bf16x8, ppv);

    // Z1_bar = Y - P@grad
    #pragma unroll
    for (int hh = 0; hh < 2; ++hh)
      yac[hh] = __builtin_amdgcn_mfma_f32_16x16x32_bf16(pAf, gf[hh], yac[hh], 0,0,0);

    // W update: W -= (lef*lr (.) k)^T @ grad  (4 quadrant MFMAs, A pre-negated)
    #pragma unroll
    for (int rb = 0; rb < 2; ++rb){
      const s16x8 kq = rb ? cur.kTq1 : cur.kTq0;
      float av8[8];
      #pragma unroll
      for (int jj = 0; jj < 8; ++jj){
        const float lrv = (jj < 4) ? plA[jj] : plB[jj - 4];
        av8[jj] = (lh < 2) ? -lef * lrv * bf2f(kq[jj]) : 0.f;
      }
      u32x4 auv;
      auv[0] = cvtpk(av8[0], av8[1]); auv[1] = cvtpk(av8[2], av8[3]);
      auv[2] = cvtpk(av8[4], av8[5]); auv[3] = cvtpk(av8[6], av8[7]);
      const bf16x8 af = __builtin_bit_cast(bf16x8, auv);
      #pragma unroll
      for (int cb = 0; cb < 2; ++cb)
        Wq[rb][cb] = __builtin_amdgcn_mfma_f32_16x16x32_bf16(af, gf[cb], Wq[rb][cb], 0,0,0);
    }

    // b update: b[c] -= lef * sum_j lr_j * grad[j][c]
    f32x4 lrq;
    { const f32x4 t0 = (lh & 1) ? cur.lr1 : cur.lr0;
      const f32x4 t1 = (lh & 1) ? cur.lr3 : cur.lr2;
      lrq = (lh & 2) ? t1 : t0; }
    #pragma unroll
    for (int hh = 0; hh < 2; ++hh){
      float t = 0.f;
      #pragma unroll
      for (int r = 0; r < 4; ++r) t += lrq[r]*grad[hh][r];
      t += __shfl_xor(t, 16); t += __shfl_xor(t, 32);
      bb[hh] -= lef * t;
    }

    // out = q + ln_fwd(Z1_bar)  (DPP reductions)
    #pragma unroll
    for (int r = 0; r < 4; ++r){
      const float s  = rsum16d(yac[0][r] + yac[1][r]);
      const float q2 = rsum16d(yac[0][r]*yac[0][r] + yac[1][r]*yac[1][r]);
      const float mu   = s * (1.f/32.f);
      const float var  = q2 * (1.f/32.f) - mu*mu;
      const float rstd = rsqrtf(var + EPS_);
      const int row = 4*lh + r;
      #pragma unroll
      for (int hh = 0; hh < 2; ++hh){
        const float qv = bf2f(QL[row*40 + 16*hh + li]);
        const float o  = qv + (yac[hh][r] - mu)*rstd*lw[hh] + lbv[hh];
        outp[(size_t)(n*16 + row)*D_ + 16*hh + li] = f2bf(o);
      }
    }

    cur = nxt;
  }
}

// ---------------------------------------------------------------------------
extern "C" void kernel_launch(void* const* d_in, const int* in_sizes, int n_in,
                              void* d_out, int out_size, void* d_ws, size_t ws_size,
                              hipStream_t stream)
{
  const float* enc    = (const float*)d_in[0];
  const float* ln0_g  = (const float*)d_in[1];
  const float* ln0_b  = (const float*)d_in[2];
  const float* Wq     = (const float*)d_in[3];
  const float* Wk     = (const float*)d_in[4];
  const float* Wv     = (const float*)d_in[5];
  const float* Wo     = (const float*)d_in[6];
  const float* W1     = (const float*)d_in[7];
  const float* b1     = (const float*)d_in[8];
  const float* tdelta = (const float*)d_in[9];
  const float* lr_w   = (const float*)d_in[10];
  const float* lr_b   = (const float*)d_in[11];
  const float* ttt_g  = (const float*)d_in[12];
  const float* ttt_b  = (const float*)d_in[13];
  const float* post_g = (const float*)d_in[14];
  const float* post_b = (const float*)d_in[15];
  const float* ffn_g  = (const float*)d_in[16];
  const float* ffn_b  = (const float*)d_in[17];
  const float* fw1    = (const float*)d_in[18];
  const float* fb1    = (const float*)d_in[19];
  const float* fw2    = (const float*)d_in[20];
  const float* fb2    = (const float*)d_in[21];

  char* ws = (char*)d_ws;
  short* Q5    = (short*)(ws + 0);            // 134,217,728 B (scan tiles)
  short* XB    = (short*)(ws + 134217728);    //  33,554,432 B
  short* SCANB = (short*)(ws + 134217728);    //  alias XB (XB dead pre-scan)
  short* WQKVT = (short*)(ws + 167772160);    //   6,291,456 B
  short* WOT   = (short*)(ws + 174063616);    //   2,097,152 B
  short* FW1T  = (short*)(ws + 176160768);    //   4,194,304 B
  short* FW2T  = (short*)(ws + 180355072);    //   4,194,304 B
  short* LRWB  = (short*)(ws + 184549376);    //      65,536 B
  float* CT    = (float*)(ws + 184614912);    //     131,072 B
  float* ST    = (float*)(ws + 184745984);    //     131,072 B
  float* ETA   = (float*)(ws + 184877056);    //   2,097,152 B
  short* YB    = (short*)(ws + 0);            // alias Q5 (post-scan)
  short* HB    = (short*)(ws + 33554432);     // alias Q5
  short* T1    = (short*)(ws + 67108864);     // alias Q5
  float* R2    = (float*)d_out;

  dim3 b256(256);
  TC4 tc;
  tc.s0 = Wq; tc.s1 = Wk; tc.s2 = Wv; tc.s3 = Wo;
  tc.d0 = WQKVT; tc.d1 = WQKVT + 1048576; tc.d2 = WQKVT + 2097152; tc.d3 = WOT;
  transpose_cast4<<<dim3(32,32,4), b256, 0, stream>>>(tc);
  transpose_cast<<<dim3(64,32), b256, 0, stream>>>(fw1, FW1T, D_, DI_);
  transpose_cast<<<dim3(32,64), b256, 0, stream>>>(fw2, FW2T, DI_, D_);
  misc_prep<<<dim3(256), b256, 0, stream>>>(lr_w, LRWB, CT, ST);

  ln_rows<<<BL_, b256, 0, stream>>>(enc, ln0_g, ln0_b, XB);
  gemm_bt<0,0,0,0,1><<<dim3(24,128), b256, 0, stream>>>(XB, WQKVT, nullptr, nullptr,
                                                        nullptr, Q5, CT, ST, BL_, 3072, D_);
  eta_kernel<<<dim3(512), b256, 0, stream>>>(XB, LRWB, lr_b, ETA);
  scan_kernel<<<dim3(256), dim3(64), 0, stream>>>(Q5, ETA, W1, b1, tdelta,
                                                  ttt_g, ttt_b, SCANB);
  ln_rows_bf<<<BL_, b256, 0, stream>>>(SCANB, post_g, post_b, YB);
  gemm_bt<0,0,0,1,0><<<dim3(8,128), b256, 0, stream>>>(YB, WOT, nullptr, enc,
                                                       R2, nullptr, nullptr, nullptr, BL_, D_, D_);
  ln_rows<<<BL_, b256, 0, stream>>>(R2, ffn_g, ffn_b, HB);
  gemm_bt<1,1,1,0,0><<<dim3(16,128), b256, 0, stream>>>(HB, FW1T, fb1, nullptr,
                                                        nullptr, T1, nullptr, nullptr, BL_, DI_, D_);
  gemm_bt<0,0,1,1,0><<<dim3(8,128), b256, 0, stream>>>(T1, FW2T, fb2, R2,
                                                       R2, nullptr, nullptr, nullptr, BL_, D_, DI_);
}

// Round 6
// 848.070 us; speedup vs baseline: 1.2447x; 1.0028x over previous
//
#include <hip/hip_runtime.h>
#include <hip/hip_bf16.h>
#include <stdint.h>

#define B_   8
#define L_   2048
#define D_   1024
#define NH_  32
#define M_   16
#define NM_  128
#define HD_  32
#define DI_  2048
#define BL_  16384
#define EPS_ 1e-6f

typedef __attribute__((ext_vector_type(8))) short  s16x8;
typedef __attribute__((ext_vector_type(4))) short  s16x4;
typedef __attribute__((ext_vector_type(8))) __bf16 bf16x8;
typedef __attribute__((ext_vector_type(4))) float  f32x4;
typedef __attribute__((ext_vector_type(4))) unsigned u32x4;

__device__ __forceinline__ float bf2f(short s){
  unsigned u = ((unsigned)(unsigned short)s) << 16;
  return __builtin_bit_cast(float, u);
}
__device__ __forceinline__ short f2bf(float f){
  unsigned u = __builtin_bit_cast(unsigned, f);
  u = u + 0x7FFFu + ((u >> 16) & 1u);   // RNE
  return (short)(u >> 16);
}
// pack 2 f32 -> 2 bf16 in one VALU op
__device__ __forceinline__ unsigned cvtpk(float lo, float hi){
  unsigned r;
  asm("v_cvt_pk_bf16_f32 %0, %1, %2" : "=v"(r) : "v"(lo), "v"(hi));
  return r;
}
// DPP row_ror reduction across 16-lane rows (VALU only, no LDS pipe)
template<int N>
__device__ __forceinline__ float ror_add(float v){
  const int y = __builtin_amdgcn_update_dpp(
      0, __builtin_bit_cast(int, v), 0x120 + N, 0xF, 0xF, true);
  return v + __builtin_bit_cast(float, y);
}
__device__ __forceinline__ float rsum16d(float v){
  v = ror_add<1>(v); v = ror_add<2>(v); v = ror_add<4>(v); v = ror_add<8>(v);
  return v;
}
// workgroup barrier WITHOUT draining vmcnt (keeps global prefetch in flight)
__device__ __forceinline__ void wgbar(){
  asm volatile("s_waitcnt lgkmcnt(0)" ::: "memory");
  __builtin_amdgcn_s_barrier();
  __builtin_amdgcn_sched_barrier(0);
}
// async global->LDS, 16B per lane (dest = wave-uniform base + lane*16)
__device__ __forceinline__ void gl16(const void* g, void* l){
  __builtin_amdgcn_global_load_lds(
      (const __attribute__((address_space(1))) void*)g,
      (__attribute__((address_space(3))) void*)l, 16, 0, 0);
}

// ---------------- transpose + fp32->bf16 cast: out(Cc,R) = in(R,Cc)^T ------
__global__ __launch_bounds__(256) void transpose_cast(
    const float* __restrict__ in, short* __restrict__ out, int R, int Cc)
{
  __shared__ float t[32][33];
  const int lx = threadIdx.x & 31, ly = threadIdx.x >> 5;
  const int r0 = blockIdx.y * 32, c0 = blockIdx.x * 32;
  #pragma unroll
  for (int s = 0; s < 4; ++s){
    const int r = ly + s*8;
    t[r][lx] = in[(size_t)(r0 + r)*Cc + c0 + lx];
  }
  __syncthreads();
  #pragma unroll
  for (int s = 0; s < 4; ++s){
    const int r = ly + s*8;
    out[(size_t)(c0 + r)*R + r0 + lx] = f2bf(t[lx][r]);
  }
}

// batched 1024x1024 transposes (4 weights in one launch)
struct TC4 { const float *s0,*s1,*s2,*s3; short *d0,*d1,*d2,*d3; };
__global__ __launch_bounds__(256) void transpose_cast4(TC4 p)
{
  __shared__ float t[32][33];
  const int z = blockIdx.z;
  const float* in = (z==0)?p.s0:(z==1)?p.s1:(z==2)?p.s2:p.s3;
  short* out      = (z==0)?p.d0:(z==1)?p.d1:(z==2)?p.d2:p.d3;
  const int lx = threadIdx.x & 31, ly = threadIdx.x >> 5;
  const int r0 = blockIdx.y * 32, c0 = blockIdx.x * 32;
  #pragma unroll
  for (int s = 0; s < 4; ++s){
    const int r = ly + s*8;
    t[r][lx] = in[(size_t)(r0 + r)*1024 + c0 + lx];
  }
  __syncthreads();
  #pragma unroll
  for (int s = 0; s < 4; ++s){
    const int r = ly + s*8;
    out[(size_t)(c0 + r)*1024 + r0 + lx] = f2bf(t[lx][r]);
  }
}

// ---------------- misc prep: lr_w cast + rope tables -----------------------
__global__ __launch_bounds__(256) void misc_prep(
    const float* __restrict__ lr_w, short* __restrict__ lrwb,
    float* __restrict__ ct, float* __restrict__ st)
{
  const int idx = blockIdx.x*256 + threadIdx.x;
  if (idx < NH_*D_){
    lrwb[idx] = f2bf(lr_w[idx]);
  } else {
    const int k = idx - NH_*D_;       // 0 .. L_*16-1
    const int l = k >> 4, j = k & 15;
    const float inv = powf(10000.f, -(float)j * (1.f/16.f));
    const float fr  = (float)l * inv;
    ct[k] = cosf(fr);
    st[k] = sinf(fr);
  }
}

// ---------------- row layernorm fp32 -> bf16 (D=1024) ----------------------
__global__ __launch_bounds__(256) void ln_rows(
    const float* __restrict__ in, const float* __restrict__ g,
    const float* __restrict__ bta, short* __restrict__ out)
{
  const int row = blockIdx.x, tid = threadIdx.x;
  const float4 v = ((const float4*)(in + (size_t)row*D_))[tid];
  float s  = v.x + v.y + v.z + v.w;
  float s2 = v.x*v.x + v.y*v.y + v.z*v.z + v.w*v.w;
  #pragma unroll
  for (int m = 1; m < 64; m <<= 1){ s += __shfl_xor(s, m); s2 += __shfl_xor(s2, m); }
  __shared__ float rs[4], rq[4];
  if ((tid & 63) == 0){ rs[tid>>6] = s; rq[tid>>6] = s2; }
  __syncthreads();
  s  = rs[0] + rs[1] + rs[2] + rs[3];
  s2 = rq[0] + rq[1] + rq[2] + rq[3];
  const float mu   = s  * (1.f/D_);
  const float var  = s2 * (1.f/D_) - mu*mu;
  const float rstd = rsqrtf(var + EPS_);
  const float4 gg = ((const float4*)g)[tid];
  const float4 bb = ((const float4*)bta)[tid];
  s16x4 o;
  o[0] = f2bf((v.x - mu)*rstd*gg.x + bb.x);
  o[1] = f2bf((v.y - mu)*rstd*gg.y + bb.y);
  o[2] = f2bf((v.z - mu)*rstd*gg.z + bb.z);
  o[3] = f2bf((v.w - mu)*rstd*gg.w + bb.w);
  ((s16x4*)(out + (size_t)row*D_))[tid] = o;
}

// ---------------- row layernorm bf16 -> bf16 (D=1024) ----------------------
__global__ __launch_bounds__(256) void ln_rows_bf(
    const short* __restrict__ in, const float* __restrict__ g,
    const float* __restrict__ bta, short* __restrict__ out)
{
  const int row = blockIdx.x, tid = threadIdx.x;
  const s16x4 v4 = ((const s16x4*)(in + (size_t)row*D_))[tid];
  float v[4];
  #pragma unroll
  for (int e = 0; e < 4; ++e) v[e] = bf2f(v4[e]);
  float s  = v[0]+v[1]+v[2]+v[3];
  float s2 = v[0]*v[0]+v[1]*v[1]+v[2]*v[2]+v[3]*v[3];
  #pragma unroll
  for (int m = 1; m < 64; m <<= 1){ s += __shfl_xor(s, m); s2 += __shfl_xor(s2, m); }
  __shared__ float rs[4], rq[4];
  if ((tid & 63) == 0){ rs[tid>>6] = s; rq[tid>>6] = s2; }
  __syncthreads();
  s  = rs[0] + rs[1] + rs[2] + rs[3];
  s2 = rq[0] + rq[1] + rq[2] + rq[3];
  const float mu   = s  * (1.f/D_);
  const float var  = s2 * (1.f/D_) - mu*mu;
  const float rstd = rsqrtf(var + EPS_);
  const float4 gg = ((const float4*)g)[tid];
  const float4 bb = ((const float4*)bta)[tid];
  s16x4 o;
  #pragma unroll
  for (int e = 0; e < 4; ++e){
    const float gv = (e==0)?gg.x:(e==1)?gg.y:(e==2)?gg.z:gg.w;
    const float bv = (e==0)?bb.x:(e==1)?bb.y:(e==2)?bb.z:bb.w;
    o[e] = f2bf((v[e] - mu)*rstd*gv + bv);
  }
  ((s16x4*)(out + (size_t)row*D_))[tid] = o;
}

// ---------------- bf16 MFMA GEMM: C(Mr,N) = A(Mr,K) @ Bt(N,K)^T ------------
// 128x128 tile, BK=32, 4 waves of 64x64. global_load_lds staging. XCD swizzle.
// QKVOUT: fused RoPE + scan-tile output {q,k,kT,vT} per (b,h,n)
template<int ACT, int OUTBF, int BIAS, int RES, int QKVOUT>
__global__ __launch_bounds__(256) void gemm_bt(
    const short* __restrict__ A, const short* __restrict__ Bt,
    const float* __restrict__ bias, const float* __restrict__ res,
    float* __restrict__ Cf, short* __restrict__ Cb,
    const float* __restrict__ ct, const float* __restrict__ st,
    int Mr, int N, int K)
{
  __shared__ __align__(16) short As[128*32];
  __shared__ __align__(16) short Bs[128*32];
  const int tid  = threadIdx.x;
  const int lane = tid & 63, wid = tid >> 6;
  // XCD-aware bijective swizzle (nwg always % 8 == 0 here)
  const int nwg = gridDim.x * gridDim.y;
  const int wg  = blockIdx.y * gridDim.x + blockIdx.x;
  const int swz = (wg & 7) * (nwg >> 3) + (wg >> 3);
  const int bx  = swz % gridDim.x, by = swz / gridDim.x;
  const int row0 = by * 128, col0 = bx * 128;
  const int wm = (wid >> 1) * 64, wn = (wid & 1) * 64;
  f32x4 acc[4][4] = {};

  const int sr = tid >> 2, sk = (tid & 3) * 8;
  const short* gA0 = A  + (size_t)(row0 + sr)      * K + sk;
  const short* gA1 = A  + (size_t)(row0 + sr + 64) * K + sk;
  const short* gB0 = Bt + (size_t)(col0 + sr)      * K + sk;
  const short* gB1 = Bt + (size_t)(col0 + sr + 64) * K + sk;
  short* lA0 = As + 8*tid;  short* lA1 = As + 2048 + 8*tid;
  short* lB0 = Bs + 8*tid;  short* lB1 = Bs + 2048 + 8*tid;

  const int fr = lane & 15, fk = (lane >> 4) * 8;
  const int nK = K >> 5;
  for (int kt = 0; kt < nK; ++kt){
    __syncthreads();
    const int ko = kt << 5;
    gl16(gA0 + ko, lA0);
    gl16(gA1 + ko, lA1);
    gl16(gB0 + ko, lB0);
    gl16(gB1 + ko, lB1);
    asm volatile("s_waitcnt vmcnt(0)" ::: "memory");
    __syncthreads();
    bf16x8 af[4], bfv[4];
    #pragma unroll
    for (int f = 0; f < 4; ++f){
      af[f]  = __builtin_bit_cast(bf16x8, *(const s16x8*)(As + (wm + f*16 + fr)*32 + fk));
      bfv[f] = __builtin_bit_cast(bf16x8, *(const s16x8*)(Bs + (wn + f*16 + fr)*32 + fk));
    }
    #pragma unroll
    for (int i = 0; i < 4; ++i)
      #pragma unroll
      for (int j = 0; j < 4; ++j)
        acc[i][j] = __builtin_amdgcn_mfma_f32_16x16x32_bf16(af[i], bfv[j], acc[i][j], 0, 0, 0);
  }
  const int cr = (lane >> 4) * 4, cc = lane & 15;
  if (QKVOUT){
    const int part = col0 >> 10;   // 0=q, 1=k, 2=v (uniform per block)
    #pragma unroll
    for (int i = 0; i < 4; ++i){
      const int gr0 = row0 + wm + i*16 + cr;       // ii = cr + r, same nn for r=0..3
      const int bidx = gr0 >> 11, l0 = gr0 & (L_-1);
      const int nn = l0 >> 4;
      if (part < 2){
        #pragma unroll
        for (int jp = 0; jp < 2; ++jp){
          const int gc = col0 + wn + jp*32 + cc;
          const int hh = (gc & 1023) >> 5;
          short* tile = Cb + ((size_t)(bidx*NH_ + hh)*NM_ + nn)*2048;
          s16x4 r0v, r1v;
          #pragma unroll
          for (int r = 0; r < 4; ++r){
            const int l = l0 + r;
            const float cv = ct[l*16 + cc], sv = st[l*16 + cc];
            const float x0 = acc[i][jp*2][r], x1 = acc[i][jp*2+1][r];
            const short q0 = f2bf(x0*cv - x1*sv);
            const short q1 = f2bf(x1*cv + x0*sv);
            tile[part*512 + (cr + r)*32 + cc]      = q0;
            tile[part*512 + (cr + r)*32 + cc + 16] = q1;
            r0v[r] = q0; r1v[r] = q1;
          }
          if (part == 1){
            *(s16x4*)(tile + 1024 + cc*16 + cr)        = r0v;   // kT rows
            *(s16x4*)(tile + 1024 + (cc+16)*16 + cr)   = r1v;
          }
        }
      } else {
        #pragma unroll
        for (int j = 0; j < 4; ++j){
          const int gc = col0 + wn + j*16 + cc;
          const int hh = (gc & 1023) >> 5, dd = gc & 31;
          short* tile = Cb + ((size_t)(bidx*NH_ + hh)*NM_ + nn)*2048;
          s16x4 p;
          #pragma unroll
          for (int r = 0; r < 4; ++r) p[r] = f2bf(acc[i][j][r]);
          *(s16x4*)(tile + 1536 + dd*16 + cr) = p;              // vT rows
        }
      }
    }
    return;
  }
  #pragma unroll
  for (int i = 0; i < 4; ++i){
    #pragma unroll
    for (int j = 0; j < 4; ++j){
      const int gc = col0 + wn + j*16 + cc;
      float bv = 0.f;
      if (BIAS) bv = bias[gc];
      #pragma unroll
      for (int r = 0; r < 4; ++r){
        const int gr = row0 + wm + i*16 + cr + r;
        float v = acc[i][j][r] + bv;
        if (RES) v += res[(size_t)gr*N + gc];
        if (ACT == 1) v = fmaxf(v, 0.f);
        if (OUTBF) Cb[(size_t)gr*N + gc] = f2bf(v);
        else       Cf[(size_t)gr*N + gc] = v;
      }
    }
  }
}

// ---------------- eta: sigmoid(x . lr_w[h] + lr_b[h]) / HD -----------------
__global__ __launch_bounds__(256) void eta_kernel(
    const short* __restrict__ xb, const short* __restrict__ lrwb,
    const float* __restrict__ lr_b, float* __restrict__ eta)
{
  __shared__ __align__(16) short wl[NH_*D_];   // 64 KB
  __shared__ __align__(16) short xr[D_];
  const int tid = threadIdx.x;
  const int wid = tid >> 6, lane = tid & 63;
  #pragma unroll
  for (int s = 0; s < 16; ++s){
    const int e8 = tid + 256*s;
    ((s16x8*)wl)[e8] = ((const s16x8*)lrwb)[e8];
  }
  for (int tk = 0; tk < 32; ++tk){
    const int token = blockIdx.x*32 + tk;
    __syncthreads();
    if (tid < 128) ((s16x8*)xr)[tid] = ((const s16x8*)(xb + (size_t)token*D_))[tid];
    __syncthreads();
    const s16x8 x0 = ((const s16x8*)xr)[lane*2];
    const s16x8 x1 = ((const s16x8*)xr)[lane*2 + 1];
    #pragma unroll 1
    for (int hh = 0; hh < 8; ++hh){
      const int h = wid*8 + hh;
      const s16x8 w0 = ((const s16x8*)(wl + h*D_))[lane*2];
      const s16x8 w1 = ((const s16x8*)(wl + h*D_))[lane*2 + 1];
      float s = 0.f;
      #pragma unroll
      for (int e = 0; e < 8; ++e)
        s += bf2f(x0[e])*bf2f(w0[e]) + bf2f(x1[e])*bf2f(w1[e]);
      #pragma unroll
      for (int m = 1; m < 64; m <<= 1) s += __shfl_xor(s, m);
      if (lane == 0){
        const float v = 1.f/(1.f + __expf(-(s + lr_b[h]))) * (1.f/32.f);
        const int bidx = token >> 11, l = token & (L_-1), n = l >> 4, im = l & 15;
        eta[(((size_t)bidx*NH_ + h)*NM_ + n)*M_ + im] = v;
      }
    }
  }
}

// ---------------- TTT scan v6: 2 waves/(b,h) producer-consumer --------------
// tile layout per (b,h,n), 2048 shorts: q[16][32] | k[16][32] | kT[32][16] | vT[32][16]
// wave0 = state path (z, grad, W/b update); wave1 = output path (a, P, y, out)
__global__ __launch_bounds__(128) void scan_kernel(
    const short* __restrict__ Q5, const float* __restrict__ eta,
    const float* __restrict__ W1, const float* __restrict__ b1,
    const float* __restrict__ tdelta, const float* __restrict__ lng,
    const float* __restrict__ lnb, short* __restrict__ out)
{
  const int bh = blockIdx.x;
  const int h = bh & 31, b = bh >> 5;
  const int lane = threadIdx.x & 63;
  const int wv = threadIdx.x >> 6;
  const int li = lane & 15, lh = lane >> 4;

  __shared__ __align__(16) unsigned PW[2][64*8];   // Wf publish (2 slots)
  __shared__ __align__(16) unsigned PG[2][64*8];   // gf publish
  __shared__ __align__(16) float    PB[2][64*2];   // bb publish
  __shared__ __align__(16) float AT[16*20];        // attn transpose (wave1)
  __shared__ __align__(16) short QL[16*40];        // q row-major (wave1)

  const short* chain = Q5 + (size_t)bh * (NM_*2048);
  const float* ech   = eta + (size_t)bh * (NM_*16);

  float lw[2], lbv[2];
  #pragma unroll
  for (int hh = 0; hh < 2; ++hh){
    lw[hh]  = lng[h*32 + 16*hh + li];
    lbv[hh] = lnb[h*32 + 16*hh + li];
  }

  if (wv == 0){
    // =================== STATE WAVE ===================
    f32x4 Wq[2][2];
    #pragma unroll
    for (int rb = 0; rb < 2; ++rb)
      #pragma unroll
      for (int cb = 0; cb < 2; ++cb)
        #pragma unroll
        for (int r = 0; r < 4; ++r)
          Wq[rb][cb][r] = W1[h*1024 + (16*rb + 4*lh + r)*32 + 16*cb + li];
    float bb[2];
    bb[0] = b1[h*32 + li];  bb[1] = b1[h*32 + 16 + li];
    const float lef = fmaxf(1.f/16.f + tdelta[15], 0.f);

    const int wa0 = ((lh & 1)*32 + li)*4;
    const int wa1 = wa0 + 64;
    const int ga0 = ((lh*32 + li) & 63)*4;
    const int ga1 = ((lh*32 + 16 + li) & 63)*4;
    const bool rbs = (lh & 2) != 0;

    bf16x8 Wf[2];
    auto mkWf = [&]{
      unsigned wpk[2][2][2];
      #pragma unroll
      for (int rb = 0; rb < 2; ++rb)
        #pragma unroll
        for (int cb = 0; cb < 2; ++cb){
          wpk[rb][cb][0] = cvtpk(Wq[rb][cb][0], Wq[rb][cb][1]);
          wpk[rb][cb][1] = cvtpk(Wq[rb][cb][2], Wq[rb][cb][3]);
        }
      #pragma unroll
      for (int hh = 0; hh < 2; ++hh){
        const int a00 = __builtin_amdgcn_ds_bpermute(wa0, (int)wpk[0][hh][0]);
        const int a10 = __builtin_amdgcn_ds_bpermute(wa0, (int)wpk[1][hh][0]);
        const int a01 = __builtin_amdgcn_ds_bpermute(wa0, (int)wpk[0][hh][1]);
        const int a11 = __builtin_amdgcn_ds_bpermute(wa0, (int)wpk[1][hh][1]);
        const int c00 = __builtin_amdgcn_ds_bpermute(wa1, (int)wpk[0][hh][0]);
        const int c10 = __builtin_amdgcn_ds_bpermute(wa1, (int)wpk[1][hh][0]);
        const int c01 = __builtin_amdgcn_ds_bpermute(wa1, (int)wpk[0][hh][1]);
        const int c11 = __builtin_amdgcn_ds_bpermute(wa1, (int)wpk[1][hh][1]);
        u32x4 wvv;
        wvv[0] = (unsigned)(rbs ? a10 : a00);
        wvv[1] = (unsigned)(rbs ? a11 : a01);
        wvv[2] = (unsigned)(rbs ? c10 : c00);
        wvv[3] = (unsigned)(rbs ? c11 : c01);
        Wf[hh] = __builtin_bit_cast(bf16x8, wvv);
      }
    };
    mkWf();

    struct P0 { s16x8 kA, kTq0, kTq1; s16x4 kTe0, kTe1, vTe0, vTe1;
                f32x4 lr0, lr1, lr2, lr3; };
    auto ld0 = [&](int n) -> P0 {
      const short* t = chain + (size_t)n*2048;
      const float* e = ech + n*16;
      P0 p;
      p.kA   = *(const s16x8*)(t + 512 + li*32 + 8*lh);
      p.kTq0 = *(const s16x8*)(t + 1024 + li*16 + 8*(lh & 1));
      p.kTq1 = *(const s16x8*)(t + 1024 + (16 + li)*16 + 8*(lh & 1));
      p.kTe0 = *(const s16x4*)(t + 1024 + li*16 + 4*lh);
      p.kTe1 = *(const s16x4*)(t + 1024 + (16 + li)*16 + 4*lh);
      p.vTe0 = *(const s16x4*)(t + 1536 + li*16 + 4*lh);
      p.vTe1 = *(const s16x4*)(t + 1536 + (16 + li)*16 + 4*lh);
      p.lr0 = *(const f32x4*)(e);     p.lr1 = *(const f32x4*)(e + 4);
      p.lr2 = *(const f32x4*)(e + 8); p.lr3 = *(const f32x4*)(e + 12);
      return p;
    };

    P0 cur = ld0(0);
    #pragma unroll 1
    for (int n = 0; n < NM_; ++n){
      // publish W_n, b_n
      const int sl = n & 1;
      *(u32x4*)&PW[sl][lane*8]     = __builtin_bit_cast(u32x4, Wf[0]);
      *(u32x4*)&PW[sl][lane*8 + 4] = __builtin_bit_cast(u32x4, Wf[1]);
      PB[sl][lane*2]     = bb[0];
      PB[sl][lane*2 + 1] = bb[1];
      wgbar();   // A

      P0 nxt = ld0(n + 1 < NM_ ? n + 1 : NM_ - 1);
      const bf16x8 kAf = __builtin_bit_cast(bf16x8, cur.kA);

      // Z1 = k@W + b
      f32x4 zac[2];
      #pragma unroll
      for (int hh = 0; hh < 2; ++hh){
        f32x4 c0; c0[0]=bb[hh]; c0[1]=bb[hh]; c0[2]=bb[hh]; c0[3]=bb[hh];
        zac[hh] = __builtin_amdgcn_mfma_f32_16x16x32_bf16(kAf, Wf[hh], c0, 0,0,0);
      }

      // grad = ln_l2_bwd(Z1, v-k)
      float xh[2][4], grad[2][4], rstdv[4];
      #pragma unroll
      for (int r = 0; r < 4; ++r){
        float s  = rsum16d(zac[0][r] + zac[1][r]);
        float q2 = rsum16d(zac[0][r]*zac[0][r] + zac[1][r]*zac[1][r]);
        const float mu  = s * (1.f/32.f);
        const float var = q2 * (1.f/32.f) - mu*mu;
        const float rstd = rsqrtf(var + EPS_);
        rstdv[r] = rstd;
        xh[0][r] = (zac[0][r] - mu) * rstd;
        xh[1][r] = (zac[1][r] - mu) * rstd;
      }
      #pragma unroll
      for (int r = 0; r < 4; ++r){
        const float t0 = bf2f(cur.vTe0[r]) - bf2f(cur.kTe0[r]);
        const float t1 = bf2f(cur.vTe1[r]) - bf2f(cur.kTe1[r]);
        const float g0 = (xh[0][r]*lw[0] + lbv[0] - t0)*lw[0];
        const float g1 = (xh[1][r]*lw[1] + lbv[1] - t1)*lw[1];
        const float sg  = rsum16d(g0 + g1);
        const float sgx = rsum16d(g0*xh[0][r] + g1*xh[1][r]);
        const float f = rstdv[r] * (1.f/32.f);
        grad[0][r] = (32.f*g0 - sg - xh[0][r]*sgx) * f;
        grad[1][r] = (32.f*g1 - sg - xh[1][r]*sgx) * f;
      }

      // gf B-frag via cvt_pk + bpermute; publish
      unsigned gpk[2][2];
      gpk[0][0] = cvtpk(grad[0][0], grad[0][1]);
      gpk[0][1] = cvtpk(grad[0][2], grad[0][3]);
      gpk[1][0] = cvtpk(grad[1][0], grad[1][1]);
      gpk[1][1] = cvtpk(grad[1][2], grad[1][3]);
      bf16x8 gf[2];
      #pragma unroll
      for (int hh = 0; hh < 2; ++hh){
        u32x4 gv;
        gv[0] = (unsigned)__builtin_amdgcn_ds_bpermute(ga0, (int)gpk[hh][0]);
        gv[1] = (unsigned)__builtin_amdgcn_ds_bpermute(ga0, (int)gpk[hh][1]);
        gv[2] = (unsigned)__builtin_amdgcn_ds_bpermute(ga1, (int)gpk[hh][0]);
        gv[3] = (unsigned)__builtin_amdgcn_ds_bpermute(ga1, (int)gpk[hh][1]);
        gf[hh] = __builtin_bit_cast(bf16x8, gv);
        *(u32x4*)&PG[sl][lane*8 + hh*4] = gv;
      }
      wgbar();   // B

      // W update: W -= (lef*lr (.) k)^T @ grad
      const f32x4 plA = (lh & 1) ? cur.lr2 : cur.lr0;
      const f32x4 plB = (lh & 1) ? cur.lr3 : cur.lr1;
      #pragma unroll
      for (int rb = 0; rb < 2; ++rb){
        const s16x8 kq = rb ? cur.kTq1 : cur.kTq0;
        float av8[8];
        #pragma unroll
        for (int jj = 0; jj < 8; ++jj){
          const float lrv = (jj < 4) ? plA[jj] : plB[jj - 4];
          av8[jj] = (lh < 2) ? -lef * lrv * bf2f(kq[jj]) : 0.f;
        }
        u32x4 auv;
        auv[0] = cvtpk(av8[0], av8[1]); auv[1] = cvtpk(av8[2], av8[3]);
        auv[2] = cvtpk(av8[4], av8[5]); auv[3] = cvtpk(av8[6], av8[7]);
        const bf16x8 af = __builtin_bit_cast(bf16x8, auv);
        #pragma unroll
        for (int cb = 0; cb < 2; ++cb)
          Wq[rb][cb] = __builtin_amdgcn_mfma_f32_16x16x32_bf16(af, gf[cb], Wq[rb][cb], 0,0,0);
      }

      // b update
      f32x4 lrq;
      { const f32x4 t0 = (lh & 1) ? cur.lr1 : cur.lr0;
        const f32x4 t1 = (lh & 1) ? cur.lr3 : cur.lr2;
        lrq = (lh & 2) ? t1 : t0; }
      #pragma unroll
      for (int hh = 0; hh < 2; ++hh){
        float t = 0.f;
        #pragma unroll
        for (int r = 0; r < 4; ++r) t += lrq[r]*grad[hh][r];
        t += __shfl_xor(t, 16); t += __shfl_xor(t, 32);
        bb[hh] -= lef * t;
      }

      mkWf();    // W^T for step n+1
      cur = nxt;
    }
  } else {
    // =================== OUTPUT WAVE ===================
    const float tok_i = fmaxf(1.f/(float)(li+1) + tdelta[li], 0.f);
    short* outp = out + (size_t)b*L_*D_ + h*32;

    struct P1 { s16x8 qA, kA; f32x4 lr0, lr1, lr2, lr3; };
    auto ld1 = [&](int n) -> P1 {
      const short* t = chain + (size_t)n*2048;
      const float* e = ech + n*16;
      P1 p;
      p.qA = *(const s16x8*)(t + li*32 + 8*lh);
      p.kA = *(const s16x8*)(t + 512 + li*32 + 8*lh);
      p.lr0 = *(const f32x4*)(e);     p.lr1 = *(const f32x4*)(e + 4);
      p.lr2 = *(const f32x4*)(e + 8); p.lr3 = *(const f32x4*)(e + 12);
      return p;
    };

    P1 cur = ld1(0);
    #pragma unroll 1
    for (int n = 0; n < NM_; ++n){
      const int sl = n & 1;
      const bf16x8 qAf = __builtin_bit_cast(bf16x8, cur.qA);
      const bf16x8 kAf = __builtin_bit_cast(bf16x8, cur.kA);

      // q row-major into LDS for transpose reads at output time
      *(s16x8*)(QL + li*40 + 8*lh) = cur.qA;

      // a = q@kT, transpose via AT
      f32x4 aac = {};
      aac = __builtin_amdgcn_mfma_f32_16x16x32_bf16(qAf, kAf, aac, 0,0,0);
      #pragma unroll
      for (int r = 0; r < 4; ++r)
        AT[(4*lh + r)*20 + li] = aac[r];

      // P fragment: P[i][j] = -tok_i*lr_j*(1+a[i][j])*[j<=i]
      f32x4 arA = {}, arB = {};
      if (lh < 2){
        arA = *(const f32x4*)(AT + li*20 + 8*lh);
        arB = *(const f32x4*)(AT + li*20 + 8*lh + 4);
      }
      const f32x4 plA = (lh & 1) ? cur.lr2 : cur.lr0;
      const f32x4 plB = (lh & 1) ? cur.lr3 : cur.lr1;
      float pv[8];
      #pragma unroll
      for (int jj = 0; jj < 8; ++jj){
        const float av  = (jj < 4) ? arA[jj] : arB[jj - 4];
        const float lrv = (jj < 4) ? plA[jj] : plB[jj - 4];
        const bool ok = (lh < 2) && (8*lh + jj <= li);
        pv[jj] = ok ? -tok_i * lrv * (1.f + av) : 0.f;
      }
      u32x4 ppv;
      ppv[0] = cvtpk(pv[0], pv[1]); ppv[1] = cvtpk(pv[2], pv[3]);
      ppv[2] = cvtpk(pv[4], pv[5]); ppv[3] = cvtpk(pv[6], pv[7]);
      const bf16x8 pAf = __builtin_bit_cast(bf16x8, ppv);

      wgbar();   // A — W_n, b_n available
      const u32x4 w0 = *(const u32x4*)&PW[sl][lane*8];
      const u32x4 w1 = *(const u32x4*)&PW[sl][lane*8 + 4];
      const bf16x8 Wf0 = __builtin_bit_cast(bf16x8, w0);
      const bf16x8 Wf1 = __builtin_bit_cast(bf16x8, w1);
      const float bb0 = PB[sl][lane*2];
      const float bb1 = PB[sl][lane*2 + 1];

      P1 nxt = ld1(n + 1 < NM_ ? n + 1 : NM_ - 1);

      // Y = q@W + b
      f32x4 yac[2];
      { f32x4 c0; c0[0]=bb0; c0[1]=bb0; c0[2]=bb0; c0[3]=bb0;
        yac[0] = __builtin_amdgcn_mfma_f32_16x16x32_bf16(qAf, Wf0, c0, 0,0,0); }
      { f32x4 c0; c0[0]=bb1; c0[1]=bb1; c0[2]=bb1; c0[3]=bb1;
        yac[1] = __builtin_amdgcn_mfma_f32_16x16x32_bf16(qAf, Wf1, c0, 0,0,0); }

      wgbar();   // B — gf available
      const u32x4 g0 = *(const u32x4*)&PG[sl][lane*8];
      const u32x4 g1 = *(const u32x4*)&PG[sl][lane*8 + 4];
      const bf16x8 gf0 = __builtin_bit_cast(bf16x8, g0);
      const bf16x8 gf1 = __builtin_bit_cast(bf16x8, g1);

      // Z1_bar = Y - P@grad
      yac[0] = __builtin_amdgcn_mfma_f32_16x16x32_bf16(pAf, gf0, yac[0], 0,0,0);
      yac[1] = __builtin_amdgcn_mfma_f32_16x16x32_bf16(pAf, gf1, yac[1], 0,0,0);

      // out = q + ln_fwd(Z1_bar)
      #pragma unroll
      for (int r = 0; r < 4; ++r){
        const float s  = rsum16d(yac[0][r] + yac[1][r]);
        const float q2 = rsum16d(yac[0][r]*yac[0][r] + yac[1][r]*yac[1][r]);
        const float mu   = s * (1.f/32.f);
        const float var  = q2 * (1.f/32.f) - mu*mu;
        const float rstd = rsqrtf(var + EPS_);
        const int row = 4*lh + r;
        #pragma unroll
        for (int hh = 0; hh < 2; ++hh){
          const float qv = bf2f(QL[row*40 + 16*hh + li]);
          const float o  = qv + (yac[hh][r] - mu)*rstd*lw[hh] + lbv[hh];
          outp[(size_t)(n*16 + row)*D_ + 16*hh + li] = f2bf(o);
        }
      }
      cur = nxt;
    }
  }
}

// ---------------------------------------------------------------------------
extern "C" void kernel_launch(void* const* d_in, const int* in_sizes, int n_in,
                              void* d_out, int out_size, void* d_ws, size_t ws_size,
                              hipStream_t stream)
{
  const float* enc    = (const float*)d_in[0];
  const float* ln0_g  = (const float*)d_in[1];
  const float* ln0_b  = (const float*)d_in[2];
  const float* Wq     = (const float*)d_in[3];
  const float* Wk     = (const float*)d_in[4];
  const float* Wv     = (const float*)d_in[5];
  const float* Wo     = (const float*)d_in[6];
  const float* W1     = (const float*)d_in[7];
  const float* b1     = (const float*)d_in[8];
  const float* tdelta = (const float*)d_in[9];
  const float* lr_w   = (const float*)d_in[10];
  const float* lr_b   = (const float*)d_in[11];
  const float* ttt_g  = (const float*)d_in[12];
  const float* ttt_b  = (const float*)d_in[13];
  const float* post_g = (const float*)d_in[14];
  const float* post_b = (const float*)d_in[15];
  const float* ffn_g  = (const float*)d_in[16];
  const float* ffn_b  = (const float*)d_in[17];
  const float* fw1    = (const float*)d_in[18];
  const float* fb1    = (const float*)d_in[19];
  const float* fw2    = (const float*)d_in[20];
  const float* fb2    = (const float*)d_in[21];

  char* ws = (char*)d_ws;
  short* Q5    = (short*)(ws + 0);            // 134,217,728 B (scan tiles)
  short* XB    = (short*)(ws + 134217728);    //  33,554,432 B
  short* SCANB = (short*)(ws + 134217728);    //  alias XB (XB dead pre-scan)
  short* WQKVT = (short*)(ws + 167772160);    //   6,291,456 B
  short* WOT   = (short*)(ws + 174063616);    //   2,097,152 B
  short* FW1T  = (short*)(ws + 176160768);    //   4,194,304 B
  short* FW2T  = (short*)(ws + 180355072);    //   4,194,304 B
  short* LRWB  = (short*)(ws + 184549376);    //      65,536 B
  float* CT    = (float*)(ws + 184614912);    //     131,072 B
  float* ST    = (float*)(ws + 184745984);    //     131,072 B
  float* ETA   = (float*)(ws + 184877056);    //   2,097,152 B
  short* YB    = (short*)(ws + 0);            // alias Q5 (post-scan)
  short* HB    = (short*)(ws + 33554432);     // alias Q5
  short* T1    = (short*)(ws + 67108864);     // alias Q5
  float* R2    = (float*)d_out;

  dim3 b256(256);
  TC4 tc;
  tc.s0 = Wq; tc.s1 = Wk; tc.s2 = Wv; tc.s3 = Wo;
  tc.d0 = WQKVT; tc.d1 = WQKVT + 1048576; tc.d2 = WQKVT + 2097152; tc.d3 = WOT;
  transpose_cast4<<<dim3(32,32,4), b256, 0, stream>>>(tc);
  transpose_cast<<<dim3(64,32), b256, 0, stream>>>(fw1, FW1T, D_, DI_);
  transpose_cast<<<dim3(32,64), b256, 0, stream>>>(fw2, FW2T, DI_, D_);
  misc_prep<<<dim3(256), b256, 0, stream>>>(lr_w, LRWB, CT, ST);

  ln_rows<<<BL_, b256, 0, stream>>>(enc, ln0_g, ln0_b, XB);
  gemm_bt<0,0,0,0,1><<<dim3(24,128), b256, 0, stream>>>(XB, WQKVT, nullptr, nullptr,
                                                        nullptr, Q5, CT, ST, BL_, 3072, D_);
  eta_kernel<<<dim3(512), b256, 0, stream>>>(XB, LRWB, lr_b, ETA);
  scan_kernel<<<dim3(256), dim3(128), 0, stream>>>(Q5, ETA, W1, b1, tdelta,
                                                   ttt_g, ttt_b, SCANB);
  ln_rows_bf<<<BL_, b256, 0, stream>>>(SCANB, post_g, post_b, YB);
  gemm_bt<0,0,0,1,0><<<dim3(8,128), b256, 0, stream>>>(YB, WOT, nullptr, enc,
                                                       R2, nullptr, nullptr, nullptr, BL_, D_, D_);
  ln_rows<<<BL_, b256, 0, stream>>>(R2, ffn_g, ffn_b, HB);
  gemm_bt<1,1,1,0,0><<<dim3(16,128), b256, 0, stream>>>(HB, FW1T, fb1, nullptr,
                                                        nullptr, T1, nullptr, nullptr, BL_, DI_, D_);
  gemm_bt<0,0,1,1,0><<<dim3(8,128), b256, 0, stream>>>(T1, FW2T, fb2, R2,
                                                       R2, nullptr, nullptr, nullptr, BL_, D_, DI_);
}

// Round 7
// 808.186 us; speedup vs baseline: 1.3061x; 1.0493x over previous
//
#include <hip/hip_runtime.h>
#include <hip/hip_bf16.h>
#include <stdint.h>

#define B_   8
#define L_   2048
#define D_   1024
#define NH_  32
#define M_   16
#define NM_  128
#define HD_  32
#define DI_  2048
#define BL_  16384
#define EPS_ 1e-6f

typedef __attribute__((ext_vector_type(8))) short  s16x8;
typedef __attribute__((ext_vector_type(4))) short  s16x4;
typedef __attribute__((ext_vector_type(8))) __bf16 bf16x8;
typedef __attribute__((ext_vector_type(4))) float  f32x4;
typedef __attribute__((ext_vector_type(4))) unsigned u32x4;

__device__ __forceinline__ float bf2f(short s){
  unsigned u = ((unsigned)(unsigned short)s) << 16;
  return __builtin_bit_cast(float, u);
}
__device__ __forceinline__ short f2bf(float f){
  unsigned u = __builtin_bit_cast(unsigned, f);
  u = u + 0x7FFFu + ((u >> 16) & 1u);   // RNE
  return (short)(u >> 16);
}
__device__ __forceinline__ unsigned cvtpk(float lo, float hi){
  unsigned r;
  asm("v_cvt_pk_bf16_f32 %0, %1, %2" : "=v"(r) : "v"(lo), "v"(hi));
  return r;
}
template<int N>
__device__ __forceinline__ float ror_add(float v){
  const int y = __builtin_amdgcn_update_dpp(
      0, __builtin_bit_cast(int, v), 0x120 + N, 0xF, 0xF, true);
  return v + __builtin_bit_cast(float, y);
}
__device__ __forceinline__ float rsum16d(float v){
  v = ror_add<1>(v); v = ror_add<2>(v); v = ror_add<4>(v); v = ror_add<8>(v);
  return v;
}
__device__ __forceinline__ void wgbar(){
  asm volatile("s_waitcnt lgkmcnt(0)" ::: "memory");
  __builtin_amdgcn_s_barrier();
  __builtin_amdgcn_sched_barrier(0);
}
__device__ __forceinline__ void gl16(const void* g, void* l){
  __builtin_amdgcn_global_load_lds(
      (const __attribute__((address_space(1))) void*)g,
      (__attribute__((address_space(3))) void*)l, 16, 0, 0);
}

// ---------------- transpose + fp32->bf16 cast: out(Cc,R) = in(R,Cc)^T ------
__global__ __launch_bounds__(256) void transpose_cast(
    const float* __restrict__ in, short* __restrict__ out, int R, int Cc)
{
  __shared__ float t[32][33];
  const int lx = threadIdx.x & 31, ly = threadIdx.x >> 5;
  const int r0 = blockIdx.y * 32, c0 = blockIdx.x * 32;
  #pragma unroll
  for (int s = 0; s < 4; ++s){
    const int r = ly + s*8;
    t[r][lx] = in[(size_t)(r0 + r)*Cc + c0 + lx];
  }
  __syncthreads();
  #pragma unroll
  for (int s = 0; s < 4; ++s){
    const int r = ly + s*8;
    out[(size_t)(c0 + r)*R + r0 + lx] = f2bf(t[lx][r]);
  }
}

struct TC4 { const float *s0,*s1,*s2,*s3; short *d0,*d1,*d2,*d3; };
__global__ __launch_bounds__(256) void transpose_cast4(TC4 p)
{
  __shared__ float t[32][33];
  const int z = blockIdx.z;
  const float* in = (z==0)?p.s0:(z==1)?p.s1:(z==2)?p.s2:p.s3;
  short* out      = (z==0)?p.d0:(z==1)?p.d1:(z==2)?p.d2:p.d3;
  const int lx = threadIdx.x & 31, ly = threadIdx.x >> 5;
  const int r0 = blockIdx.y * 32, c0 = blockIdx.x * 32;
  #pragma unroll
  for (int s = 0; s < 4; ++s){
    const int r = ly + s*8;
    t[r][lx] = in[(size_t)(r0 + r)*1024 + c0 + lx];
  }
  __syncthreads();
  #pragma unroll
  for (int s = 0; s < 4; ++s){
    const int r = ly + s*8;
    out[(size_t)(c0 + r)*1024 + r0 + lx] = f2bf(t[lx][r]);
  }
}

// ---------------- misc prep: lr_w cast + rope tables -----------------------
__global__ __launch_bounds__(256) void misc_prep(
    const float* __restrict__ lr_w, short* __restrict__ lrwb,
    float* __restrict__ ct, float* __restrict__ st)
{
  const int idx = blockIdx.x*256 + threadIdx.x;
  if (idx < NH_*D_){
    lrwb[idx] = f2bf(lr_w[idx]);
  } else {
    const int k = idx - NH_*D_;
    const int l = k >> 4, j = k & 15;
    const float inv = powf(10000.f, -(float)j * (1.f/16.f));
    const float fr  = (float)l * inv;
    ct[k] = cosf(fr);
    st[k] = sinf(fr);
  }
}

// ---------------- row layernorm fp32 -> bf16 (D=1024) ----------------------
__global__ __launch_bounds__(256) void ln_rows(
    const float* __restrict__ in, const float* __restrict__ g,
    const float* __restrict__ bta, short* __restrict__ out)
{
  const int row = blockIdx.x, tid = threadIdx.x;
  const float4 v = ((const float4*)(in + (size_t)row*D_))[tid];
  float s  = v.x + v.y + v.z + v.w;
  float s2 = v.x*v.x + v.y*v.y + v.z*v.z + v.w*v.w;
  #pragma unroll
  for (int m = 1; m < 64; m <<= 1){ s += __shfl_xor(s, m); s2 += __shfl_xor(s2, m); }
  __shared__ float rs[4], rq[4];
  if ((tid & 63) == 0){ rs[tid>>6] = s; rq[tid>>6] = s2; }
  __syncthreads();
  s  = rs[0] + rs[1] + rs[2] + rs[3];
  s2 = rq[0] + rq[1] + rq[2] + rq[3];
  const float mu   = s  * (1.f/D_);
  const float var  = s2 * (1.f/D_) - mu*mu;
  const float rstd = rsqrtf(var + EPS_);
  const float4 gg = ((const float4*)g)[tid];
  const float4 bb = ((const float4*)bta)[tid];
  s16x4 o;
  o[0] = f2bf((v.x - mu)*rstd*gg.x + bb.x);
  o[1] = f2bf((v.y - mu)*rstd*gg.y + bb.y);
  o[2] = f2bf((v.z - mu)*rstd*gg.z + bb.z);
  o[3] = f2bf((v.w - mu)*rstd*gg.w + bb.w);
  ((s16x4*)(out + (size_t)row*D_))[tid] = o;
}

// ---------------- row layernorm bf16 -> bf16 (D=1024) ----------------------
__global__ __launch_bounds__(256) void ln_rows_bf(
    const short* __restrict__ in, const float* __restrict__ g,
    const float* __restrict__ bta, short* __restrict__ out)
{
  const int row = blockIdx.x, tid = threadIdx.x;
  const s16x4 v4 = ((const s16x4*)(in + (size_t)row*D_))[tid];
  float v[4];
  #pragma unroll
  for (int e = 0; e < 4; ++e) v[e] = bf2f(v4[e]);
  float s  = v[0]+v[1]+v[2]+v[3];
  float s2 = v[0]*v[0]+v[1]*v[1]+v[2]*v[2]+v[3]*v[3];
  #pragma unroll
  for (int m = 1; m < 64; m <<= 1){ s += __shfl_xor(s, m); s2 += __shfl_xor(s2, m); }
  __shared__ float rs[4], rq[4];
  if ((tid & 63) == 0){ rs[tid>>6] = s; rq[tid>>6] = s2; }
  __syncthreads();
  s  = rs[0] + rs[1] + rs[2] + rs[3];
  s2 = rq[0] + rq[1] + rq[2] + rq[3];
  const float mu   = s  * (1.f/D_);
  const float var  = s2 * (1.f/D_) - mu*mu;
  const float rstd = rsqrtf(var + EPS_);
  const float4 gg = ((const float4*)g)[tid];
  const float4 bb = ((const float4*)bta)[tid];
  s16x4 o;
  #pragma unroll
  for (int e = 0; e < 4; ++e){
    const float gv = (e==0)?gg.x:(e==1)?gg.y:(e==2)?gg.z:gg.w;
    const float bv = (e==0)?bb.x:(e==1)?bb.y:(e==2)?bb.z:bb.w;
    o[e] = f2bf((v[e] - mu)*rstd*gv + bv);
  }
  ((s16x4*)(out + (size_t)row*D_))[tid] = o;
}

// ---------------- 256x256 8-wave phase-structured bf16 GEMM ----------------
// C(Mr,N) = A(Mr,K) @ Bt(N,K)^T. BK=64, double-buffered LDS, swizzled,
// counted-vmcnt prefetch, setprio MFMA phases. XCD swizzle on blocks.
// QKVOUT: fused RoPE + scan-tile output {q,k,kT,vT} per (b,h,n)
template<int ACT, int OUTBF, int BIAS, int RES, int QKVOUT>
__global__ __launch_bounds__(512, 2) void gemm256(
    const short* __restrict__ A, const short* __restrict__ Bt,
    const float* __restrict__ bias, const float* __restrict__ res,
    float* __restrict__ Cf, short* __restrict__ Cb,
    const float* __restrict__ ct, const float* __restrict__ st,
    int Mr, int N, int K)
{
  // per dbuf: [2 half][128 rows][64 k] shorts; swizzle: elem ^= ((elem>>8)&3)<<3
  __shared__ __align__(16) short As[2][16384];
  __shared__ __align__(16) short Bs[2][16384];
  const int tid  = threadIdx.x;
  const int lane = tid & 63, wid = tid >> 6;
  const int wr = wid >> 2, wc = wid & 3;
  const int nwg = gridDim.x * gridDim.y;
  const int wg  = blockIdx.y * gridDim.x + blockIdx.x;
  const int swz = (wg & 7) * (nwg >> 3) + (wg >> 3);
  const int bx  = swz % gridDim.x, by = swz / gridDim.x;
  const int row0 = by * 256, col0 = bx * 256;

  f32x4 acc[8][4] = {};

  // staging addresses (source pre-swizzled so linear LDS holds swizzled data)
  const int kswz = ((tid & 7) * 8) ^ (((tid >> 5) & 3) << 3);
  const short* gAb = A  + (size_t)(row0 + (tid >> 3)) * K + kswz;
  const short* gBb = Bt + (size_t)(col0 + (tid >> 3)) * K + kswz;
  short* lAb = &As[0][0] + tid*8;
  short* lBb = &Bs[0][0] + tid*8;

  auto stageA = [&](int d, int kt2){
    const size_t kb = (size_t)kt2 * 64;
    gl16(gAb + kb,                   lAb + d*16384);
    gl16(gAb + kb +  64*(size_t)K,   lAb + d*16384 + 4096);
    gl16(gAb + kb + 128*(size_t)K,   lAb + d*16384 + 8192);
    gl16(gAb + kb + 192*(size_t)K,   lAb + d*16384 + 12288);
  };
  auto stageB = [&](int d, int kt2){
    const size_t kb = (size_t)kt2 * 64;
    gl16(gBb + kb,                   lBb + d*16384);
    gl16(gBb + kb +  64*(size_t)K,   lBb + d*16384 + 4096);
    gl16(gBb + kb + 128*(size_t)K,   lBb + d*16384 + 8192);
    gl16(gBb + kb + 192*(size_t)K,   lBb + d*16384 + 12288);
  };

  // fragment read constants
  const int fr  = lane & 15;
  const int fk8 = (lane >> 4) * 8;
  const int kx  = ((lane >> 2) & 3) << 3;     // read-side swizzle XOR
  const int k0  = fk8 ^ kx;                   // kstep0 elem offset
  const short* Ah = &As[0][0] + wr*8192;
  const short* Bh = &Bs[0][0] + (wc >> 1)*8192 + (wc & 1)*4096;

  // prologue: stage K-tile 0 into dbuf 0
  stageA(0, 0); stageB(0, 0);
  asm volatile("s_waitcnt vmcnt(0)" ::: "memory");
  __builtin_amdgcn_s_barrier();

  const int nK = K >> 6;
  bf16x8 bfv[4][2];
  for (int kt = 0; kt < nK; ++kt){
    const int c = kt & 1;
    const bool pf = (kt + 1 < nK);
    const short* Ab = Ah + c*16384;
    const short* Bb = Bh + c*16384;
    #pragma unroll
    for (int q = 0; q < 4; ++q){
      bf16x8 af[2];
      bf16x8 af1[2];
      #pragma unroll
      for (int mm = 0; mm < 2; ++mm){
        const int rh = (2*q + mm)*16 + fr;
        af[mm]  = *(const bf16x8*)(Ab + rh*64 + k0);
        af1[mm] = *(const bf16x8*)(Ab + rh*64 + k0 + 32);
      }
      if (q == 0){
        #pragma unroll
        for (int n = 0; n < 4; ++n){
          const int rh = n*16 + fr;
          bfv[n][0] = *(const bf16x8*)(Bb + rh*64 + k0);
          bfv[n][1] = *(const bf16x8*)(Bb + rh*64 + k0 + 32);
        }
      }
      if (pf){
        if (q == 0)      stageA(c ^ 1, kt + 1);
        else if (q == 1) stageB(c ^ 1, kt + 1);
      }
      __builtin_amdgcn_s_barrier();
      asm volatile("s_waitcnt lgkmcnt(0)" ::: "memory");
      __builtin_amdgcn_sched_barrier(0);
      __builtin_amdgcn_s_setprio(1);
      #pragma unroll
      for (int mm = 0; mm < 2; ++mm)
        #pragma unroll
        for (int n = 0; n < 4; ++n){
          acc[2*q+mm][n] = __builtin_amdgcn_mfma_f32_16x16x32_bf16(af[mm],  bfv[n][0], acc[2*q+mm][n], 0,0,0);
          acc[2*q+mm][n] = __builtin_amdgcn_mfma_f32_16x16x32_bf16(af1[mm], bfv[n][1], acc[2*q+mm][n], 0,0,0);
        }
      __builtin_amdgcn_s_setprio(0);
      if (q < 3) __builtin_amdgcn_s_barrier();
    }
    if (pf) asm volatile("s_waitcnt vmcnt(0)" ::: "memory");
    __builtin_amdgcn_s_barrier();
  }

  const int cr = (lane >> 4) * 4, cc = lane & 15;
  if (QKVOUT){
    const int part = col0 >> 10;   // uniform per block (1024 % 256 == 0)
    #pragma unroll
    for (int m = 0; m < 8; ++m){
      const int gr0 = row0 + wr*128 + m*16 + cr;
      const int bidx = gr0 >> 11, l0 = gr0 & (L_-1);
      const int nn = l0 >> 4;
      if (part < 2){
        #pragma unroll
        for (int np = 0; np < 2; ++np){
          const int gc = col0 + wc*64 + np*32 + cc;
          const int hh = (gc & 1023) >> 5;
          short* tile = Cb + ((size_t)(bidx*NH_ + hh)*NM_ + nn)*2048;
          s16x4 r0v, r1v;
          #pragma unroll
          for (int r = 0; r < 4; ++r){
            const int l = l0 + r;
            const float cv = ct[l*16 + cc], sv = st[l*16 + cc];
            const float x0 = acc[m][np*2][r], x1 = acc[m][np*2+1][r];
            const short q0 = f2bf(x0*cv - x1*sv);
            const short q1 = f2bf(x1*cv + x0*sv);
            tile[part*512 + (cr + r)*32 + cc]      = q0;
            tile[part*512 + (cr + r)*32 + cc + 16] = q1;
            r0v[r] = q0; r1v[r] = q1;
          }
          if (part == 1){
            *(s16x4*)(tile + 1024 + cc*16 + cr)      = r0v;
            *(s16x4*)(tile + 1024 + (cc+16)*16 + cr) = r1v;
          }
        }
      } else {
        #pragma unroll
        for (int n = 0; n < 4; ++n){
          const int gc = col0 + wc*64 + n*16 + cc;
          const int hh = (gc & 1023) >> 5, dd = gc & 31;
          short* tile = Cb + ((size_t)(bidx*NH_ + hh)*NM_ + nn)*2048;
          s16x4 p;
          #pragma unroll
          for (int r = 0; r < 4; ++r) p[r] = f2bf(acc[m][n][r]);
          *(s16x4*)(tile + 1536 + dd*16 + cr) = p;
        }
      }
    }
    return;
  }
  #pragma unroll
  for (int m = 0; m < 8; ++m){
    #pragma unroll
    for (int n = 0; n < 4; ++n){
      const int gc = col0 + wc*64 + n*16 + cc;
      float bv = 0.f;
      if (BIAS) bv = bias[gc];
      #pragma unroll
      for (int r = 0; r < 4; ++r){
        const int gr = row0 + wr*128 + m*16 + cr + r;
        float v = acc[m][n][r] + bv;
        if (RES) v += res[(size_t)gr*N + gc];
        if (ACT == 1) v = fmaxf(v, 0.f);
        if (OUTBF) Cb[(size_t)gr*N + gc] = f2bf(v);
        else       Cf[(size_t)gr*N + gc] = v;
      }
    }
  }
}

// ---------------- eta: sigmoid(x . lr_w[h] + lr_b[h]) / HD -----------------
__global__ __launch_bounds__(256) void eta_kernel(
    const short* __restrict__ xb, const short* __restrict__ lrwb,
    const float* __restrict__ lr_b, float* __restrict__ eta)
{
  __shared__ __align__(16) short wl[NH_*D_];
  __shared__ __align__(16) short xr[D_];
  const int tid = threadIdx.x;
  const int wid = tid >> 6, lane = tid & 63;
  #pragma unroll
  for (int s = 0; s < 16; ++s){
    const int e8 = tid + 256*s;
    ((s16x8*)wl)[e8] = ((const s16x8*)lrwb)[e8];
  }
  for (int tk = 0; tk < 32; ++tk){
    const int token = blockIdx.x*32 + tk;
    __syncthreads();
    if (tid < 128) ((s16x8*)xr)[tid] = ((const s16x8*)(xb + (size_t)token*D_))[tid];
    __syncthreads();
    const s16x8 x0 = ((const s16x8*)xr)[lane*2];
    const s16x8 x1 = ((const s16x8*)xr)[lane*2 + 1];
    #pragma unroll 1
    for (int hh = 0; hh < 8; ++hh){
      const int h = wid*8 + hh;
      const s16x8 w0 = ((const s16x8*)(wl + h*D_))[lane*2];
      const s16x8 w1 = ((const s16x8*)(wl + h*D_))[lane*2 + 1];
      float s = 0.f;
      #pragma unroll
      for (int e = 0; e < 8; ++e)
        s += bf2f(x0[e])*bf2f(w0[e]) + bf2f(x1[e])*bf2f(w1[e]);
      #pragma unroll
      for (int m = 1; m < 64; m <<= 1) s += __shfl_xor(s, m);
      if (lane == 0){
        const float v = 1.f/(1.f + __expf(-(s + lr_b[h]))) * (1.f/32.f);
        const int bidx = token >> 11, l = token & (L_-1), n = l >> 4, im = l & 15;
        eta[(((size_t)bidx*NH_ + h)*NM_ + n)*M_ + im] = v;
      }
    }
  }
}

// ---------------- TTT scan v6: 2 waves/(b,h) producer-consumer --------------
__global__ __launch_bounds__(128) void scan_kernel(
    const short* __restrict__ Q5, const float* __restrict__ eta,
    const float* __restrict__ W1, const float* __restrict__ b1,
    const float* __restrict__ tdelta, const float* __restrict__ lng,
    const float* __restrict__ lnb, short* __restrict__ out)
{
  const int bh = blockIdx.x;
  const int h = bh & 31, b = bh >> 5;
  const int lane = threadIdx.x & 63;
  const int wv = threadIdx.x >> 6;
  const int li = lane & 15, lh = lane >> 4;

  __shared__ __align__(16) unsigned PW[2][64*8];
  __shared__ __align__(16) unsigned PG[2][64*8];
  __shared__ __align__(16) float    PB[2][64*2];
  __shared__ __align__(16) float AT[16*20];
  __shared__ __align__(16) short QL[16*40];

  const short* chain = Q5 + (size_t)bh * (NM_*2048);
  const float* ech   = eta + (size_t)bh * (NM_*16);

  float lw[2], lbv[2];
  #pragma unroll
  for (int hh = 0; hh < 2; ++hh){
    lw[hh]  = lng[h*32 + 16*hh + li];
    lbv[hh] = lnb[h*32 + 16*hh + li];
  }

  if (wv == 0){
    f32x4 Wq[2][2];
    #pragma unroll
    for (int rb = 0; rb < 2; ++rb)
      #pragma unroll
      for (int cb = 0; cb < 2; ++cb)
        #pragma unroll
        for (int r = 0; r < 4; ++r)
          Wq[rb][cb][r] = W1[h*1024 + (16*rb + 4*lh + r)*32 + 16*cb + li];
    float bb[2];
    bb[0] = b1[h*32 + li];  bb[1] = b1[h*32 + 16 + li];
    const float lef = fmaxf(1.f/16.f + tdelta[15], 0.f);

    const int wa0 = ((lh & 1)*32 + li)*4;
    const int wa1 = wa0 + 64;
    const int ga0 = ((lh*32 + li) & 63)*4;
    const int ga1 = ((lh*32 + 16 + li) & 63)*4;
    const bool rbs = (lh & 2) != 0;

    bf16x8 Wf[2];
    auto mkWf = [&]{
      unsigned wpk[2][2][2];
      #pragma unroll
      for (int rb = 0; rb < 2; ++rb)
        #pragma unroll
        for (int cb = 0; cb < 2; ++cb){
          wpk[rb][cb][0] = cvtpk(Wq[rb][cb][0], Wq[rb][cb][1]);
          wpk[rb][cb][1] = cvtpk(Wq[rb][cb][2], Wq[rb][cb][3]);
        }
      #pragma unroll
      for (int hh = 0; hh < 2; ++hh){
        const int a00 = __builtin_amdgcn_ds_bpermute(wa0, (int)wpk[0][hh][0]);
        const int a10 = __builtin_amdgcn_ds_bpermute(wa0, (int)wpk[1][hh][0]);
        const int a01 = __builtin_amdgcn_ds_bpermute(wa0, (int)wpk[0][hh][1]);
        const int a11 = __builtin_amdgcn_ds_bpermute(wa0, (int)wpk[1][hh][1]);
        const int c00 = __builtin_amdgcn_ds_bpermute(wa1, (int)wpk[0][hh][0]);
        const int c10 = __builtin_amdgcn_ds_bpermute(wa1, (int)wpk[1][hh][0]);
        const int c01 = __builtin_amdgcn_ds_bpermute(wa1, (int)wpk[0][hh][1]);
        const int c11 = __builtin_amdgcn_ds_bpermute(wa1, (int)wpk[1][hh][1]);
        u32x4 wvv;
        wvv[0] = (unsigned)(rbs ? a10 : a00);
        wvv[1] = (unsigned)(rbs ? a11 : a01);
        wvv[2] = (unsigned)(rbs ? c10 : c00);
        wvv[3] = (unsigned)(rbs ? c11 : c01);
        Wf[hh] = __builtin_bit_cast(bf16x8, wvv);
      }
    };
    mkWf();

    struct P0 { s16x8 kA, kTq0, kTq1; s16x4 kTe0, kTe1, vTe0, vTe1;
                f32x4 lr0, lr1, lr2, lr3; };
    auto ld0 = [&](int n) -> P0 {
      const short* t = chain + (size_t)n*2048;
      const float* e = ech + n*16;
      P0 p;
      p.kA   = *(const s16x8*)(t + 512 + li*32 + 8*lh);
      p.kTq0 = *(const s16x8*)(t + 1024 + li*16 + 8*(lh & 1));
      p.kTq1 = *(const s16x8*)(t + 1024 + (16 + li)*16 + 8*(lh & 1));
      p.kTe0 = *(const s16x4*)(t + 1024 + li*16 + 4*lh);
      p.kTe1 = *(const s16x4*)(t + 1024 + (16 + li)*16 + 4*lh);
      p.vTe0 = *(const s16x4*)(t + 1536 + li*16 + 4*lh);
      p.vTe1 = *(const s16x4*)(t + 1536 + (16 + li)*16 + 4*lh);
      p.lr0 = *(const f32x4*)(e);     p.lr1 = *(const f32x4*)(e + 4);
      p.lr2 = *(const f32x4*)(e + 8); p.lr3 = *(const f32x4*)(e + 12);
      return p;
    };

    P0 cur = ld0(0);
    #pragma unroll 1
    for (int n = 0; n < NM_; ++n){
      const int sl = n & 1;
      *(u32x4*)&PW[sl][lane*8]     = __builtin_bit_cast(u32x4, Wf[0]);
      *(u32x4*)&PW[sl][lane*8 + 4] = __builtin_bit_cast(u32x4, Wf[1]);
      PB[sl][lane*2]     = bb[0];
      PB[sl][lane*2 + 1] = bb[1];
      wgbar();   // A

      P0 nxt = ld0(n + 1 < NM_ ? n + 1 : NM_ - 1);
      const bf16x8 kAf = __builtin_bit_cast(bf16x8, cur.kA);

      f32x4 zac[2];
      #pragma unroll
      for (int hh = 0; hh < 2; ++hh){
        f32x4 c0; c0[0]=bb[hh]; c0[1]=bb[hh]; c0[2]=bb[hh]; c0[3]=bb[hh];
        zac[hh] = __builtin_amdgcn_mfma_f32_16x16x32_bf16(kAf, Wf[hh], c0, 0,0,0);
      }

      float xh[2][4], grad[2][4], rstdv[4];
      #pragma unroll
      for (int r = 0; r < 4; ++r){
        float s  = rsum16d(zac[0][r] + zac[1][r]);
        float q2 = rsum16d(zac[0][r]*zac[0][r] + zac[1][r]*zac[1][r]);
        const float mu  = s * (1.f/32.f);
        const float var = q2 * (1.f/32.f) - mu*mu;
        const float rstd = rsqrtf(var + EPS_);
        rstdv[r] = rstd;
        xh[0][r] = (zac[0][r] - mu) * rstd;
        xh[1][r] = (zac[1][r] - mu) * rstd;
      }
      #pragma unroll
      for (int r = 0; r < 4; ++r){
        const float t0 = bf2f(cur.vTe0[r]) - bf2f(cur.kTe0[r]);
        const float t1 = bf2f(cur.vTe1[r]) - bf2f(cur.kTe1[r]);
        const float g0 = (xh[0][r]*lw[0] + lbv[0] - t0)*lw[0];
        const float g1 = (xh[1][r]*lw[1] + lbv[1] - t1)*lw[1];
        const float sg  = rsum16d(g0 + g1);
        const float sgx = rsum16d(g0*xh[0][r] + g1*xh[1][r]);
        const float f = rstdv[r] * (1.f/32.f);
        grad[0][r] = (32.f*g0 - sg - xh[0][r]*sgx) * f;
        grad[1][r] = (32.f*g1 - sg - xh[1][r]*sgx) * f;
      }

      unsigned gpk[2][2];
      gpk[0][0] = cvtpk(grad[0][0], grad[0][1]);
      gpk[0][1] = cvtpk(grad[0][2], grad[0][3]);
      gpk[1][0] = cvtpk(grad[1][0], grad[1][1]);
      gpk[1][1] = cvtpk(grad[1][2], grad[1][3]);
      bf16x8 gf[2];
      #pragma unroll
      for (int hh = 0; hh < 2; ++hh){
        u32x4 gv;
        gv[0] = (unsigned)__builtin_amdgcn_ds_bpermute(ga0, (int)gpk[hh][0]);
        gv[1] = (unsigned)__builtin_amdgcn_ds_bpermute(ga0, (int)gpk[hh][1]);
        gv[2] = (unsigned)__builtin_amdgcn_ds_bpermute(ga1, (int)gpk[hh][0]);
        gv[3] = (unsigned)__builtin_amdgcn_ds_bpermute(ga1, (int)gpk[hh][1]);
        gf[hh] = __builtin_bit_cast(bf16x8, gv);
        *(u32x4*)&PG[sl][lane*8 + hh*4] = gv;
      }
      wgbar();   // B

      const f32x4 plA = (lh & 1) ? cur.lr2 : cur.lr0;
      const f32x4 plB = (lh & 1) ? cur.lr3 : cur.lr1;
      #pragma unroll
      for (int rb = 0; rb < 2; ++rb){
        const s16x8 kq = rb ? cur.kTq1 : cur.kTq0;
        float av8[8];
        #pragma unroll
        for (int jj = 0; jj < 8; ++jj){
          const float lrv = (jj < 4) ? plA[jj] : plB[jj - 4];
          av8[jj] = (lh < 2) ? -lef * lrv * bf2f(kq[jj]) : 0.f;
        }
        u32x4 auv;
        auv[0] = cvtpk(av8[0], av8[1]); auv[1] = cvtpk(av8[2], av8[3]);
        auv[2] = cvtpk(av8[4], av8[5]); auv[3] = cvtpk(av8[6], av8[7]);
        const bf16x8 af = __builtin_bit_cast(bf16x8, auv);
        #pragma unroll
        for (int cb = 0; cb < 2; ++cb)
          Wq[rb][cb] = __builtin_amdgcn_mfma_f32_16x16x32_bf16(af, gf[cb], Wq[rb][cb], 0,0,0);
      }

      f32x4 lrq;
      { const f32x4 t0 = (lh & 1) ? cur.lr1 : cur.lr0;
        const f32x4 t1 = (lh & 1) ? cur.lr3 : cur.lr2;
        lrq = (lh & 2) ? t1 : t0; }
      #pragma unroll
      for (int hh = 0; hh < 2; ++hh){
        float t = 0.f;
        #pragma unroll
        for (int r = 0; r < 4; ++r) t += lrq[r]*grad[hh][r];
        t += __shfl_xor(t, 16); t += __shfl_xor(t, 32);
        bb[hh] -= lef * t;
      }

      mkWf();
      cur = nxt;
    }
  } else {
    const float tok_i = fmaxf(1.f/(float)(li+1) + tdelta[li], 0.f);
    short* outp = out + (size_t)b*L_*D_ + h*32;

    struct P1 { s16x8 qA, kA; f32x4 lr0, lr1, lr2, lr3; };
    auto ld1 = [&](int n) -> P1 {
      const short* t = chain + (size_t)n*2048;
      const float* e = ech + n*16;
      P1 p;
      p.qA = *(const s16x8*)(t + li*32 + 8*lh);
      p.kA = *(const s16x8*)(t + 512 + li*32 + 8*lh);
      p.lr0 = *(const f32x4*)(e);     p.lr1 = *(const f32x4*)(e + 4);
      p.lr2 = *(const f32x4*)(e + 8); p.lr3 = *(const f32x4*)(e + 12);
      return p;
    };

    P1 cur = ld1(0);
    #pragma unroll 1
    for (int n = 0; n < NM_; ++n){
      const int sl = n & 1;
      const bf16x8 qAf = __builtin_bit_cast(bf16x8, cur.qA);
      const bf16x8 kAf = __builtin_bit_cast(bf16x8, cur.kA);

      *(s16x8*)(QL + li*40 + 8*lh) = cur.qA;

      f32x4 aac = {};
      aac = __builtin_amdgcn_mfma_f32_16x16x32_bf16(qAf, kAf, aac, 0,0,0);
      #pragma unroll
      for (int r = 0; r < 4; ++r)
        AT[(4*lh + r)*20 + li] = aac[r];

      f32x4 arA = {}, arB = {};
      if (lh < 2){
        arA = *(const f32x4*)(AT + li*20 + 8*lh);
        arB = *(const f32x4*)(AT + li*20 + 8*lh + 4);
      }
      const f32x4 plA = (lh & 1) ? cur.lr2 : cur.lr0;
      const f32x4 plB = (lh & 1) ? cur.lr3 : cur.lr1;
      float pv[8];
      #pragma unroll
      for (int jj = 0; jj < 8; ++jj){
        const float av  = (jj < 4) ? arA[jj] : arB[jj - 4];
        const float lrv = (jj < 4) ? plA[jj] : plB[jj - 4];
        const bool ok = (lh < 2) && (8*lh + jj <= li);
        pv[jj] = ok ? -tok_i * lrv * (1.f + av) : 0.f;
      }
      u32x4 ppv;
      ppv[0] = cvtpk(pv[0], pv[1]); ppv[1] = cvtpk(pv[2], pv[3]);
      ppv[2] = cvtpk(pv[4], pv[5]); ppv[3] = cvtpk(pv[6], pv[7]);
      const bf16x8 pAf = __builtin_bit_cast(bf16x8, ppv);

      wgbar();   // A
      const u32x4 w0 = *(const u32x4*)&PW[sl][lane*8];
      const u32x4 w1 = *(const u32x4*)&PW[sl][lane*8 + 4];
      const bf16x8 Wf0 = __builtin_bit_cast(bf16x8, w0);
      const bf16x8 Wf1 = __builtin_bit_cast(bf16x8, w1);
      const float bb0 = PB[sl][lane*2];
      const float bb1 = PB[sl][lane*2 + 1];

      P1 nxt = ld1(n + 1 < NM_ ? n + 1 : NM_ - 1);

      f32x4 yac[2];
      { f32x4 c0; c0[0]=bb0; c0[1]=bb0; c0[2]=bb0; c0[3]=bb0;
        yac[0] = __builtin_amdgcn_mfma_f32_16x16x32_bf16(qAf, Wf0, c0, 0,0,0); }
      { f32x4 c0; c0[0]=bb1; c0[1]=bb1; c0[2]=bb1; c0[3]=bb1;
        yac[1] = __builtin_amdgcn_mfma_f32_16x16x32_bf16(qAf, Wf1, c0, 0,0,0); }

      wgbar();   // B
      const u32x4 g0 = *(const u32x4*)&PG[sl][lane*8];
      const u32x4 g1 = *(const u32x4*)&PG[sl][lane*8 + 4];
      const bf16x8 gf0 = __builtin_bit_cast(bf16x8, g0);
      const bf16x8 gf1 = __builtin_bit_cast(bf16x8, g1);

      yac[0] = __builtin_amdgcn_mfma_f32_16x16x32_bf16(pAf, gf0, yac[0], 0,0,0);
      yac[1] = __builtin_amdgcn_mfma_f32_16x16x32_bf16(pAf, gf1, yac[1], 0,0,0);

      #pragma unroll
      for (int r = 0; r < 4; ++r){
        const float s  = rsum16d(yac[0][r] + yac[1][r]);
        const float q2 = rsum16d(yac[0][r]*yac[0][r] + yac[1][r]*yac[1][r]);
        const float mu   = s * (1.f/32.f);
        const float var  = q2 * (1.f/32.f) - mu*mu;
        const float rstd = rsqrtf(var + EPS_);
        const int row = 4*lh + r;
        #pragma unroll
        for (int hh = 0; hh < 2; ++hh){
          const float qv = bf2f(QL[row*40 + 16*hh + li]);
          const float o  = qv + (yac[hh][r] - mu)*rstd*lw[hh] + lbv[hh];
          outp[(size_t)(n*16 + row)*D_ + 16*hh + li] = f2bf(o);
        }
      }
      cur = nxt;
    }
  }
}

// ---------------------------------------------------------------------------
extern "C" void kernel_launch(void* const* d_in, const int* in_sizes, int n_in,
                              void* d_out, int out_size, void* d_ws, size_t ws_size,
                              hipStream_t stream)
{
  const float* enc    = (const float*)d_in[0];
  const float* ln0_g  = (const float*)d_in[1];
  const float* ln0_b  = (const float*)d_in[2];
  const float* Wq     = (const float*)d_in[3];
  const float* Wk     = (const float*)d_in[4];
  const float* Wv     = (const float*)d_in[5];
  const float* Wo     = (const float*)d_in[6];
  const float* W1     = (const float*)d_in[7];
  const float* b1     = (const float*)d_in[8];
  const float* tdelta = (const float*)d_in[9];
  const float* lr_w   = (const float*)d_in[10];
  const float* lr_b   = (const float*)d_in[11];
  const float* ttt_g  = (const float*)d_in[12];
  const float* ttt_b  = (const float*)d_in[13];
  const float* post_g = (const float*)d_in[14];
  const float* post_b = (const float*)d_in[15];
  const float* ffn_g  = (const float*)d_in[16];
  const float* ffn_b  = (const float*)d_in[17];
  const float* fw1    = (const float*)d_in[18];
  const float* fb1    = (const float*)d_in[19];
  const float* fw2    = (const float*)d_in[20];
  const float* fb2    = (const float*)d_in[21];

  char* ws = (char*)d_ws;
  short* Q5    = (short*)(ws + 0);            // 134,217,728 B (scan tiles)
  short* XB    = (short*)(ws + 134217728);    //  33,554,432 B
  short* SCANB = (short*)(ws + 134217728);    //  alias XB
  short* WQKVT = (short*)(ws + 167772160);    //   6,291,456 B
  short* WOT   = (short*)(ws + 174063616);    //   2,097,152 B
  short* FW1T  = (short*)(ws + 176160768);    //   4,194,304 B
  short* FW2T  = (short*)(ws + 180355072);    //   4,194,304 B
  short* LRWB  = (short*)(ws + 184549376);    //      65,536 B
  float* CT    = (float*)(ws + 184614912);    //     131,072 B
  float* ST    = (float*)(ws + 184745984);    //     131,072 B
  float* ETA   = (float*)(ws + 184877056);    //   2,097,152 B
  short* YB    = (short*)(ws + 0);            // alias Q5 (post-scan)
  short* HB    = (short*)(ws + 33554432);     // alias Q5
  short* T1    = (short*)(ws + 67108864);     // alias Q5
  float* R2    = (float*)d_out;

  dim3 b256(256), b512(512);
  TC4 tc;
  tc.s0 = Wq; tc.s1 = Wk; tc.s2 = Wv; tc.s3 = Wo;
  tc.d0 = WQKVT; tc.d1 = WQKVT + 1048576; tc.d2 = WQKVT + 2097152; tc.d3 = WOT;
  transpose_cast4<<<dim3(32,32,4), b256, 0, stream>>>(tc);
  transpose_cast<<<dim3(64,32), b256, 0, stream>>>(fw1, FW1T, D_, DI_);
  transpose_cast<<<dim3(32,64), b256, 0, stream>>>(fw2, FW2T, DI_, D_);
  misc_prep<<<dim3(256), b256, 0, stream>>>(lr_w, LRWB, CT, ST);

  ln_rows<<<BL_, b256, 0, stream>>>(enc, ln0_g, ln0_b, XB);
  gemm256<0,0,0,0,1><<<dim3(12,64), b512, 0, stream>>>(XB, WQKVT, nullptr, nullptr,
                                                       nullptr, Q5, CT, ST, BL_, 3072, D_);
  eta_kernel<<<dim3(512), b256, 0, stream>>>(XB, LRWB, lr_b, ETA);
  scan_kernel<<<dim3(256), dim3(128), 0, stream>>>(Q5, ETA, W1, b1, tdelta,
                                                   ttt_g, ttt_b, SCANB);
  ln_rows_bf<<<BL_, b256, 0, stream>>>(SCANB, post_g, post_b, YB);
  gemm256<0,0,0,1,0><<<dim3(4,64), b512, 0, stream>>>(YB, WOT, nullptr, enc,
                                                      R2, nullptr, nullptr, nullptr, BL_, D_, D_);
  ln_rows<<<BL_, b256, 0, stream>>>(R2, ffn_g, ffn_b, HB);
  gemm256<1,1,1,0,0><<<dim3(8,64), b512, 0, stream>>>(HB, FW1T, fb1, nullptr,
                                                      nullptr, T1, nullptr, nullptr, BL_, DI_, D_);
  gemm256<0,0,1,1,0><<<dim3(4,64), b512, 0, stream>>>(T1, FW2T, fb2, R2,
                                                      R2, nullptr, nullptr, nullptr, BL_, D_, DI_);
}

// Round 8
// 738.572 us; speedup vs baseline: 1.4293x; 1.0943x over previous
//
#include <hip/hip_runtime.h>
#include <hip/hip_bf16.h>
#include <stdint.h>

#define B_   8
#define L_   2048
#define D_   1024
#define NH_  32
#define M_   16
#define NM_  128
#define HD_  32
#define DI_  2048
#define BL_  16384
#define EPS_ 1e-6f

typedef __attribute__((ext_vector_type(8))) short  s16x8;
typedef __attribute__((ext_vector_type(4))) short  s16x4;
typedef __attribute__((ext_vector_type(8))) __bf16 bf16x8;
typedef __attribute__((ext_vector_type(4))) float  f32x4;
typedef __attribute__((ext_vector_type(4))) unsigned u32x4;

__device__ __forceinline__ float bf2f(short s){
  unsigned u = ((unsigned)(unsigned short)s) << 16;
  return __builtin_bit_cast(float, u);
}
__device__ __forceinline__ short f2bf(float f){
  unsigned u = __builtin_bit_cast(unsigned, f);
  u = u + 0x7FFFu + ((u >> 16) & 1u);   // RNE
  return (short)(u >> 16);
}
__device__ __forceinline__ unsigned cvtpk(float lo, float hi){
  unsigned r;
  asm("v_cvt_pk_bf16_f32 %0, %1, %2" : "=v"(r) : "v"(lo), "v"(hi));
  return r;
}
template<int N>
__device__ __forceinline__ float ror_add(float v){
  const int y = __builtin_amdgcn_update_dpp(
      0, __builtin_bit_cast(int, v), 0x120 + N, 0xF, 0xF, true);
  return v + __builtin_bit_cast(float, y);
}
__device__ __forceinline__ float rsum16d(float v){
  v = ror_add<1>(v); v = ror_add<2>(v); v = ror_add<4>(v); v = ror_add<8>(v);
  return v;
}
__device__ __forceinline__ void wgbar(){
  asm volatile("s_waitcnt lgkmcnt(0)" ::: "memory");
  __builtin_amdgcn_s_barrier();
  __builtin_amdgcn_sched_barrier(0);
}
__device__ __forceinline__ void gl16(const void* g, void* l){
  __builtin_amdgcn_global_load_lds(
      (const __attribute__((address_space(1))) void*)g,
      (__attribute__((address_space(3))) void*)l, 16, 0, 0);
}

// ---------------- transpose + fp32->bf16 cast: out(Cc,R) = in(R,Cc)^T ------
__global__ __launch_bounds__(256) void transpose_cast(
    const float* __restrict__ in, short* __restrict__ out, int R, int Cc)
{
  __shared__ float t[32][33];
  const int lx = threadIdx.x & 31, ly = threadIdx.x >> 5;
  const int r0 = blockIdx.y * 32, c0 = blockIdx.x * 32;
  #pragma unroll
  for (int s = 0; s < 4; ++s){
    const int r = ly + s*8;
    t[r][lx] = in[(size_t)(r0 + r)*Cc + c0 + lx];
  }
  __syncthreads();
  #pragma unroll
  for (int s = 0; s < 4; ++s){
    const int r = ly + s*8;
    out[(size_t)(c0 + r)*R + r0 + lx] = f2bf(t[lx][r]);
  }
}

struct TC4 { const float *s0,*s1,*s2,*s3; short *d0,*d1,*d2,*d3; };
__global__ __launch_bounds__(256) void transpose_cast4(TC4 p)
{
  __shared__ float t[32][33];
  const int z = blockIdx.z;
  const float* in = (z==0)?p.s0:(z==1)?p.s1:(z==2)?p.s2:p.s3;
  short* out      = (z==0)?p.d0:(z==1)?p.d1:(z==2)?p.d2:p.d3;
  const int lx = threadIdx.x & 31, ly = threadIdx.x >> 5;
  const int r0 = blockIdx.y * 32, c0 = blockIdx.x * 32;
  #pragma unroll
  for (int s = 0; s < 4; ++s){
    const int r = ly + s*8;
    t[r][lx] = in[(size_t)(r0 + r)*1024 + c0 + lx];
  }
  __syncthreads();
  #pragma unroll
  for (int s = 0; s < 4; ++s){
    const int r = ly + s*8;
    out[(size_t)(c0 + r)*1024 + r0 + lx] = f2bf(t[lx][r]);
  }
}

// ---------------- misc prep: lr_w cast + rope tables -----------------------
__global__ __launch_bounds__(256) void misc_prep(
    const float* __restrict__ lr_w, short* __restrict__ lrwb,
    float* __restrict__ ct, float* __restrict__ st)
{
  const int idx = blockIdx.x*256 + threadIdx.x;
  if (idx < NH_*D_){
    lrwb[idx] = f2bf(lr_w[idx]);
  } else {
    const int k = idx - NH_*D_;
    const int l = k >> 4, j = k & 15;
    const float inv = powf(10000.f, -(float)j * (1.f/16.f));
    const float fr  = (float)l * inv;
    ct[k] = cosf(fr);
    st[k] = sinf(fr);
  }
}

// ---------------- row layernorm fp32 -> bf16 (D=1024) ----------------------
__global__ __launch_bounds__(256) void ln_rows(
    const float* __restrict__ in, const float* __restrict__ g,
    const float* __restrict__ bta, short* __restrict__ out)
{
  const int row = blockIdx.x, tid = threadIdx.x;
  const float4 v = ((const float4*)(in + (size_t)row*D_))[tid];
  float s  = v.x + v.y + v.z + v.w;
  float s2 = v.x*v.x + v.y*v.y + v.z*v.z + v.w*v.w;
  #pragma unroll
  for (int m = 1; m < 64; m <<= 1){ s += __shfl_xor(s, m); s2 += __shfl_xor(s2, m); }
  __shared__ float rs[4], rq[4];
  if ((tid & 63) == 0){ rs[tid>>6] = s; rq[tid>>6] = s2; }
  __syncthreads();
  s  = rs[0] + rs[1] + rs[2] + rs[3];
  s2 = rq[0] + rq[1] + rq[2] + rq[3];
  const float mu   = s  * (1.f/D_);
  const float var  = s2 * (1.f/D_) - mu*mu;
  const float rstd = rsqrtf(var + EPS_);
  const float4 gg = ((const float4*)g)[tid];
  const float4 bb = ((const float4*)bta)[tid];
  s16x4 o;
  o[0] = f2bf((v.x - mu)*rstd*gg.x + bb.x);
  o[1] = f2bf((v.y - mu)*rstd*gg.y + bb.y);
  o[2] = f2bf((v.z - mu)*rstd*gg.z + bb.z);
  o[3] = f2bf((v.w - mu)*rstd*gg.w + bb.w);
  ((s16x4*)(out + (size_t)row*D_))[tid] = o;
}

// ---------------- row layernorm bf16 -> bf16 (D=1024) ----------------------
__global__ __launch_bounds__(256) void ln_rows_bf(
    const short* __restrict__ in, const float* __restrict__ g,
    const float* __restrict__ bta, short* __restrict__ out)
{
  const int row = blockIdx.x, tid = threadIdx.x;
  const s16x4 v4 = ((const s16x4*)(in + (size_t)row*D_))[tid];
  float v[4];
  #pragma unroll
  for (int e = 0; e < 4; ++e) v[e] = bf2f(v4[e]);
  float s  = v[0]+v[1]+v[2]+v[3];
  float s2 = v[0]*v[0]+v[1]*v[1]+v[2]*v[2]+v[3]*v[3];
  #pragma unroll
  for (int m = 1; m < 64; m <<= 1){ s += __shfl_xor(s, m); s2 += __shfl_xor(s2, m); }
  __shared__ float rs[4], rq[4];
  if ((tid & 63) == 0){ rs[tid>>6] = s; rq[tid>>6] = s2; }
  __syncthreads();
  s  = rs[0] + rs[1] + rs[2] + rs[3];
  s2 = rq[0] + rq[1] + rq[2] + rq[3];
  const float mu   = s  * (1.f/D_);
  const float var  = s2 * (1.f/D_) - mu*mu;
  const float rstd = rsqrtf(var + EPS_);
  const float4 gg = ((const float4*)g)[tid];
  const float4 bb = ((const float4*)bta)[tid];
  s16x4 o;
  #pragma unroll
  for (int e = 0; e < 4; ++e){
    const float gv = (e==0)?gg.x:(e==1)?gg.y:(e==2)?gg.z:gg.w;
    const float bv = (e==0)?bb.x:(e==1)?bb.y:(e==2)?bb.z:bb.w;
    o[e] = f2bf((v[e] - mu)*rstd*gv + bv);
  }
  ((s16x4*)(out + (size_t)row*D_))[tid] = o;
}

// ---------------- 256x256 8-wave phase-structured bf16 GEMM ----------------
template<int ACT, int OUTBF, int BIAS, int RES, int QKVOUT>
__global__ __launch_bounds__(512, 2) void gemm256(
    const short* __restrict__ A, const short* __restrict__ Bt,
    const float* __restrict__ bias, const float* __restrict__ res,
    float* __restrict__ Cf, short* __restrict__ Cb,
    const float* __restrict__ ct, const float* __restrict__ st,
    int Mr, int N, int K)
{
  __shared__ __align__(16) short As[2][16384];
  __shared__ __align__(16) short Bs[2][16384];
  const int tid  = threadIdx.x;
  const int lane = tid & 63, wid = tid >> 6;
  const int wr = wid >> 2, wc = wid & 3;
  const int nwg = gridDim.x * gridDim.y;
  const int wg  = blockIdx.y * gridDim.x + blockIdx.x;
  const int swz = (wg & 7) * (nwg >> 3) + (wg >> 3);
  const int bx  = swz % gridDim.x, by = swz / gridDim.x;
  const int row0 = by * 256, col0 = bx * 256;

  f32x4 acc[8][4] = {};

  const int kswz = ((tid & 7) * 8) ^ (((tid >> 5) & 3) << 3);
  const short* gAb = A  + (size_t)(row0 + (tid >> 3)) * K + kswz;
  const short* gBb = Bt + (size_t)(col0 + (tid >> 3)) * K + kswz;
  short* lAb = &As[0][0] + tid*8;
  short* lBb = &Bs[0][0] + tid*8;

  auto stageA = [&](int d, int kt2){
    const size_t kb = (size_t)kt2 * 64;
    gl16(gAb + kb,                   lAb + d*16384);
    gl16(gAb + kb +  64*(size_t)K,   lAb + d*16384 + 4096);
    gl16(gAb + kb + 128*(size_t)K,   lAb + d*16384 + 8192);
    gl16(gAb + kb + 192*(size_t)K,   lAb + d*16384 + 12288);
  };
  auto stageB = [&](int d, int kt2){
    const size_t kb = (size_t)kt2 * 64;
    gl16(gBb + kb,                   lBb + d*16384);
    gl16(gBb + kb +  64*(size_t)K,   lBb + d*16384 + 4096);
    gl16(gBb + kb + 128*(size_t)K,   lBb + d*16384 + 8192);
    gl16(gBb + kb + 192*(size_t)K,   lBb + d*16384 + 12288);
  };

  const int fr  = lane & 15;
  const int fk8 = (lane >> 4) * 8;
  const int kx  = ((lane >> 2) & 3) << 3;
  const int k0  = fk8 ^ kx;
  const short* Ah = &As[0][0] + wr*8192;
  const short* Bh = &Bs[0][0] + (wc >> 1)*8192 + (wc & 1)*4096;

  stageA(0, 0); stageB(0, 0);
  asm volatile("s_waitcnt vmcnt(0)" ::: "memory");
  __builtin_amdgcn_s_barrier();

  const int nK = K >> 6;
  bf16x8 bfv[4][2];
  for (int kt = 0; kt < nK; ++kt){
    const int c = kt & 1;
    const bool pf = (kt + 1 < nK);
    const short* Ab = Ah + c*16384;
    const short* Bb = Bh + c*16384;
    #pragma unroll
    for (int q = 0; q < 4; ++q){
      bf16x8 af[2];
      bf16x8 af1[2];
      #pragma unroll
      for (int mm = 0; mm < 2; ++mm){
        const int rh = (2*q + mm)*16 + fr;
        af[mm]  = *(const bf16x8*)(Ab + rh*64 + k0);
        af1[mm] = *(const bf16x8*)(Ab + rh*64 + k0 + 32);
      }
      if (q == 0){
        #pragma unroll
        for (int n = 0; n < 4; ++n){
          const int rh = n*16 + fr;
          bfv[n][0] = *(const bf16x8*)(Bb + rh*64 + k0);
          bfv[n][1] = *(const bf16x8*)(Bb + rh*64 + k0 + 32);
        }
      }
      if (pf){
        if (q == 0)      stageA(c ^ 1, kt + 1);
        else if (q == 1) stageB(c ^ 1, kt + 1);
      }
      __builtin_amdgcn_s_barrier();
      asm volatile("s_waitcnt lgkmcnt(0)" ::: "memory");
      __builtin_amdgcn_sched_barrier(0);
      __builtin_amdgcn_s_setprio(1);
      #pragma unroll
      for (int mm = 0; mm < 2; ++mm)
        #pragma unroll
        for (int n = 0; n < 4; ++n){
          acc[2*q+mm][n] = __builtin_amdgcn_mfma_f32_16x16x32_bf16(af[mm],  bfv[n][0], acc[2*q+mm][n], 0,0,0);
          acc[2*q+mm][n] = __builtin_amdgcn_mfma_f32_16x16x32_bf16(af1[mm], bfv[n][1], acc[2*q+mm][n], 0,0,0);
        }
      __builtin_amdgcn_s_setprio(0);
      if (q < 3) __builtin_amdgcn_s_barrier();
    }
    if (pf) asm volatile("s_waitcnt vmcnt(0)" ::: "memory");
    __builtin_amdgcn_s_barrier();
  }

  const int cr = (lane >> 4) * 4, cc = lane & 15;
  if (QKVOUT){
    const int part = col0 >> 10;
    #pragma unroll
    for (int m = 0; m < 8; ++m){
      const int gr0 = row0 + wr*128 + m*16 + cr;
      const int bidx = gr0 >> 11, l0 = gr0 & (L_-1);
      const int nn = l0 >> 4;
      if (part < 2){
        #pragma unroll
        for (int np = 0; np < 2; ++np){
          const int gc = col0 + wc*64 + np*32 + cc;
          const int hh = (gc & 1023) >> 5;
          short* tile = Cb + ((size_t)(bidx*NH_ + hh)*NM_ + nn)*2048;
          s16x4 r0v, r1v;
          #pragma unroll
          for (int r = 0; r < 4; ++r){
            const int l = l0 + r;
            const float cv = ct[l*16 + cc], sv = st[l*16 + cc];
            const float x0 = acc[m][np*2][r], x1 = acc[m][np*2+1][r];
            const short q0 = f2bf(x0*cv - x1*sv);
            const short q1 = f2bf(x1*cv + x0*sv);
            tile[part*512 + (cr + r)*32 + cc]      = q0;
            tile[part*512 + (cr + r)*32 + cc + 16] = q1;
            r0v[r] = q0; r1v[r] = q1;
          }
          if (part == 1){
            *(s16x4*)(tile + 1024 + cc*16 + cr)      = r0v;
            *(s16x4*)(tile + 1024 + (cc+16)*16 + cr) = r1v;
          }
        }
      } else {
        #pragma unroll
        for (int n = 0; n < 4; ++n){
          const int gc = col0 + wc*64 + n*16 + cc;
          const int hh = (gc & 1023) >> 5, dd = gc & 31;
          short* tile = Cb + ((size_t)(bidx*NH_ + hh)*NM_ + nn)*2048;
          s16x4 p;
          #pragma unroll
          for (int r = 0; r < 4; ++r) p[r] = f2bf(acc[m][n][r]);
          *(s16x4*)(tile + 1536 + dd*16 + cr) = p;
        }
      }
    }
    return;
  }
  #pragma unroll
  for (int m = 0; m < 8; ++m){
    #pragma unroll
    for (int n = 0; n < 4; ++n){
      const int gc = col0 + wc*64 + n*16 + cc;
      float bv = 0.f;
      if (BIAS) bv = bias[gc];
      #pragma unroll
      for (int r = 0; r < 4; ++r){
        const int gr = row0 + wr*128 + m*16 + cr + r;
        float v = acc[m][n][r] + bv;
        if (RES) v += res[(size_t)gr*N + gc];
        if (ACT == 1) v = fmaxf(v, 0.f);
        if (OUTBF) Cb[(size_t)gr*N + gc] = f2bf(v);
        else       Cf[(size_t)gr*N + gc] = v;
      }
    }
  }
}

// ---------------- eta: sigmoid(x . lr_w[h] + lr_b[h]) / HD -----------------
__global__ __launch_bounds__(256) void eta_kernel(
    const short* __restrict__ xb, const short* __restrict__ lrwb,
    const float* __restrict__ lr_b, float* __restrict__ eta)
{
  __shared__ __align__(16) short wl[NH_*D_];
  __shared__ __align__(16) short xr[D_];
  const int tid = threadIdx.x;
  const int wid = tid >> 6, lane = tid & 63;
  #pragma unroll
  for (int s = 0; s < 16; ++s){
    const int e8 = tid + 256*s;
    ((s16x8*)wl)[e8] = ((const s16x8*)lrwb)[e8];
  }
  for (int tk = 0; tk < 32; ++tk){
    const int token = blockIdx.x*32 + tk;
    __syncthreads();
    if (tid < 128) ((s16x8*)xr)[tid] = ((const s16x8*)(xb + (size_t)token*D_))[tid];
    __syncthreads();
    const s16x8 x0 = ((const s16x8*)xr)[lane*2];
    const s16x8 x1 = ((const s16x8*)xr)[lane*2 + 1];
    #pragma unroll 1
    for (int hh = 0; hh < 8; ++hh){
      const int h = wid*8 + hh;
      const s16x8 w0 = ((const s16x8*)(wl + h*D_))[lane*2];
      const s16x8 w1 = ((const s16x8*)(wl + h*D_))[lane*2 + 1];
      float s = 0.f;
      #pragma unroll
      for (int e = 0; e < 8; ++e)
        s += bf2f(x0[e])*bf2f(w0[e]) + bf2f(x1[e])*bf2f(w1[e]);
      #pragma unroll
      for (int m = 1; m < 64; m <<= 1) s += __shfl_xor(s, m);
      if (lane == 0){
        const float v = 1.f/(1.f + __expf(-(s + lr_b[h]))) * (1.f/32.f);
        const int bidx = token >> 11, l = token & (L_-1), n = l >> 4, im = l & 15;
        eta[(((size_t)bidx*NH_ + h)*NM_ + n)*M_ + im] = v;
      }
    }
  }
}

// ---------------- TTT scan v7: 2 waves, 1 barrier/step, LDS transposes -----
// wave0 = state (z, grad, W/b update); wave1 = output, pipelined 1 step back
__global__ __launch_bounds__(128) void scan_kernel(
    const short* __restrict__ Q5, const float* __restrict__ eta,
    const float* __restrict__ W1, const float* __restrict__ b1,
    const float* __restrict__ tdelta, const float* __restrict__ lng,
    const float* __restrict__ lnb, short* __restrict__ out)
{
  const int bh = blockIdx.x;
  const int h = bh & 31, b = bh >> 5;
  const int lane = threadIdx.x & 63;
  const int wv = threadIdx.x >> 6;
  const int li = lane & 15, lh = lane >> 4;

  __shared__ __align__(16) short WTl[2][32*40];   // W^T bf16 (slot = n&1)
  __shared__ __align__(16) short GTl[2][32*24];   // grad^T bf16 (slot = n&1)
  __shared__ float BBl[2][2][16];                 // b publish
  __shared__ __align__(16) float AT[16*20];       // attn transpose (wave1)
  __shared__ __align__(16) short QLl[2][16*40];   // q row-major (wave1)

  const short* chain = Q5 + (size_t)bh * (NM_*2048);
  const float* ech   = eta + (size_t)bh * (NM_*16);

  float lw[2], lbv[2];
  #pragma unroll
  for (int hh = 0; hh < 2; ++hh){
    lw[hh]  = lng[h*32 + 16*hh + li];
    lbv[hh] = lnb[h*32 + 16*hh + li];
  }

  if (wv == 0){
    // =================== STATE WAVE ===================
    f32x4 Wq[2][2];
    #pragma unroll
    for (int rb = 0; rb < 2; ++rb)
      #pragma unroll
      for (int cb = 0; cb < 2; ++cb)
        #pragma unroll
        for (int r = 0; r < 4; ++r)
          Wq[rb][cb][r] = W1[h*1024 + (16*rb + 4*lh + r)*32 + 16*cb + li];
    float bb[2];
    bb[0] = b1[h*32 + li];  bb[1] = b1[h*32 + 16 + li];
    const float lef = fmaxf(1.f/16.f + tdelta[15], 0.f);

    // write W^T (bf16) into WTl[sl]: per lane 4 b64 writes, conflict-light
    auto writeWT = [&](int sl){
      #pragma unroll
      for (int cb = 0; cb < 2; ++cb)
        #pragma unroll
        for (int rb = 0; rb < 2; ++rb){
          const unsigned p0 = cvtpk(Wq[rb][cb][0], Wq[rb][cb][1]);
          const unsigned p1 = cvtpk(Wq[rb][cb][2], Wq[rb][cb][3]);
          *(uint64_t*)(&WTl[sl][0] + (16*cb + li)*40 + 16*rb + 4*lh) =
              ((uint64_t)p1 << 32) | p0;
        }
    };
    auto readWf = [&](int sl, bf16x8* Wf){
      Wf[0] = *(const bf16x8*)(&WTl[sl][0] + li*40 + 8*lh);
      Wf[1] = *(const bf16x8*)(&WTl[sl][0] + (16 + li)*40 + 8*lh);
    };

    writeWT(0);
    if (lh == 0){ BBl[0][0][li] = bb[0]; BBl[0][1][li] = bb[1]; }
    bf16x8 Wf[2];
    readWf(0, Wf);   // in-order LDS within wave: read-after-write OK

    struct P0 { s16x8 kA, kTq0, kTq1; s16x4 kTe0, kTe1, vTe0, vTe1;
                f32x4 lr0, lr1, lr2, lr3; };
    auto ld0 = [&](int n) -> P0 {
      const short* t = chain + (size_t)n*2048;
      const float* e = ech + n*16;
      P0 p;
      p.kA   = *(const s16x8*)(t + 512 + li*32 + 8*lh);
      p.kTq0 = *(const s16x8*)(t + 1024 + li*16 + 8*(lh & 1));
      p.kTq1 = *(const s16x8*)(t + 1024 + (16 + li)*16 + 8*(lh & 1));
      p.kTe0 = *(const s16x4*)(t + 1024 + li*16 + 4*lh);
      p.kTe1 = *(const s16x4*)(t + 1024 + (16 + li)*16 + 4*lh);
      p.vTe0 = *(const s16x4*)(t + 1536 + li*16 + 4*lh);
      p.vTe1 = *(const s16x4*)(t + 1536 + (16 + li)*16 + 4*lh);
      p.lr0 = *(const f32x4*)(e);     p.lr1 = *(const f32x4*)(e + 4);
      p.lr2 = *(const f32x4*)(e + 8); p.lr3 = *(const f32x4*)(e + 12);
      return p;
    };

    P0 cur = ld0(0);
    wgbar();   // barrier 0: WT[0], BB[0] visible

    const int gcol = (8*lh) & 15;   // in-bounds col for gf reads (lh>=2 unused)
    #pragma unroll 1
    for (int n = 0; n < NM_; ++n){
      const int sl = n & 1;
      P0 nxt = ld0(n + 1 < NM_ ? n + 1 : NM_ - 1);
      const bf16x8 kAf = __builtin_bit_cast(bf16x8, cur.kA);

      // Z1 = k@W + b
      f32x4 zac[2];
      #pragma unroll
      for (int hh = 0; hh < 2; ++hh){
        f32x4 c0; c0[0]=bb[hh]; c0[1]=bb[hh]; c0[2]=bb[hh]; c0[3]=bb[hh];
        zac[hh] = __builtin_amdgcn_mfma_f32_16x16x32_bf16(kAf, Wf[hh], c0, 0,0,0);
      }

      // grad = ln_l2_bwd(Z1, v-k)
      float xh[2][4], grad[2][4], rstdv[4];
      #pragma unroll
      for (int r = 0; r < 4; ++r){
        float s  = rsum16d(zac[0][r] + zac[1][r]);
        float q2 = rsum16d(zac[0][r]*zac[0][r] + zac[1][r]*zac[1][r]);
        const float mu  = s * (1.f/32.f);
        const float var = q2 * (1.f/32.f) - mu*mu;
        const float rstd = rsqrtf(var + EPS_);
        rstdv[r] = rstd;
        xh[0][r] = (zac[0][r] - mu) * rstd;
        xh[1][r] = (zac[1][r] - mu) * rstd;
      }
      #pragma unroll
      for (int r = 0; r < 4; ++r){
        const float t0 = bf2f(cur.vTe0[r]) - bf2f(cur.kTe0[r]);
        const float t1 = bf2f(cur.vTe1[r]) - bf2f(cur.kTe1[r]);
        const float g0 = (xh[0][r]*lw[0] + lbv[0] - t0)*lw[0];
        const float g1 = (xh[1][r]*lw[1] + lbv[1] - t1)*lw[1];
        const float sg  = rsum16d(g0 + g1);
        const float sgx = rsum16d(g0*xh[0][r] + g1*xh[1][r]);
        const float f = rstdv[r] * (1.f/32.f);
        grad[0][r] = (32.f*g0 - sg - xh[0][r]*sgx) * f;
        grad[1][r] = (32.f*g1 - sg - xh[1][r]*sgx) * f;
      }

      // grad^T -> GTl[sl] (2 b64 writes), then read back gf A-frags
      #pragma unroll
      for (int hh = 0; hh < 2; ++hh){
        const unsigned p0 = cvtpk(grad[hh][0], grad[hh][1]);
        const unsigned p1 = cvtpk(grad[hh][2], grad[hh][3]);
        *(uint64_t*)(&GTl[sl][0] + (16*hh + li)*24 + 4*lh) =
            ((uint64_t)p1 << 32) | p0;
      }
      bf16x8 gf[2];
      gf[0] = *(const bf16x8*)(&GTl[sl][0] + li*24 + gcol);
      gf[1] = *(const bf16x8*)(&GTl[sl][0] + (16 + li)*24 + gcol);

      // W update: W -= (lef*lr (.) k)^T @ grad
      const f32x4 plA = (lh & 1) ? cur.lr2 : cur.lr0;
      const f32x4 plB = (lh & 1) ? cur.lr3 : cur.lr1;
      #pragma unroll
      for (int rb = 0; rb < 2; ++rb){
        const s16x8 kq = rb ? cur.kTq1 : cur.kTq0;
        float av8[8];
        #pragma unroll
        for (int jj = 0; jj < 8; ++jj){
          const float lrv = (jj < 4) ? plA[jj] : plB[jj - 4];
          av8[jj] = (lh < 2) ? -lef * lrv * bf2f(kq[jj]) : 0.f;
        }
        u32x4 auv;
        auv[0] = cvtpk(av8[0], av8[1]); auv[1] = cvtpk(av8[2], av8[3]);
        auv[2] = cvtpk(av8[4], av8[5]); auv[3] = cvtpk(av8[6], av8[7]);
        const bf16x8 af = __builtin_bit_cast(bf16x8, auv);
        #pragma unroll
        for (int cb = 0; cb < 2; ++cb)
          Wq[rb][cb] = __builtin_amdgcn_mfma_f32_16x16x32_bf16(af, gf[cb], Wq[rb][cb], 0,0,0);
      }

      // b update
      f32x4 lrq;
      { const f32x4 t0 = (lh & 1) ? cur.lr1 : cur.lr0;
        const f32x4 t1 = (lh & 1) ? cur.lr3 : cur.lr2;
        lrq = (lh & 2) ? t1 : t0; }
      #pragma unroll
      for (int hh = 0; hh < 2; ++hh){
        float t = 0.f;
        #pragma unroll
        for (int r = 0; r < 4; ++r) t += lrq[r]*grad[hh][r];
        t += __shfl_xor(t, 16); t += __shfl_xor(t, 32);
        bb[hh] -= lef * t;
      }

      // publish W(n+1), b(n+1); read own Wf for next step
      writeWT(sl ^ 1);
      if (lh == 0){ BBl[sl ^ 1][0][li] = bb[0]; BBl[sl ^ 1][1][li] = bb[1]; }
      readWf(sl ^ 1, Wf);
      cur = nxt;
      wgbar();
    }
  } else {
    // =================== OUTPUT WAVE (pipelined one step back) ===============
    const float tok_i = fmaxf(1.f/(float)(li+1) + tdelta[li], 0.f);
    short* outp = out + (size_t)b*L_*D_ + h*32;
    const int gcol = (8*lh) & 15;

    struct P1 { s16x8 qA, kA; f32x4 lr0, lr1, lr2, lr3; };
    auto ld1 = [&](int n) -> P1 {
      const short* t = chain + (size_t)n*2048;
      const float* e = ech + n*16;
      P1 p;
      p.qA = *(const s16x8*)(t + li*32 + 8*lh);
      p.kA = *(const s16x8*)(t + 512 + li*32 + 8*lh);
      p.lr0 = *(const f32x4*)(e);     p.lr1 = *(const f32x4*)(e + 4);
      p.lr2 = *(const f32x4*)(e + 8); p.lr3 = *(const f32x4*)(e + 12);
      return p;
    };

    auto outln = [&](int n, const f32x4* yac){
      #pragma unroll
      for (int r = 0; r < 4; ++r){
        const float s  = rsum16d(yac[0][r] + yac[1][r]);
        const float q2 = rsum16d(yac[0][r]*yac[0][r] + yac[1][r]*yac[1][r]);
        const float mu   = s * (1.f/32.f);
        const float var  = q2 * (1.f/32.f) - mu*mu;
        const float rstd = rsqrtf(var + EPS_);
        const int row = 4*lh + r;
        #pragma unroll
        for (int hh = 0; hh < 2; ++hh){
          const float qv = bf2f(QLl[n & 1][row*40 + 16*hh + li]);
          const float o  = qv + (yac[hh][r] - mu)*rstd*lw[hh] + lbv[hh];
          outp[(size_t)(n*16 + row)*D_ + 16*hh + li] = f2bf(o);
        }
      }
    };

    P1 cur = ld1(0);
    wgbar();   // barrier 0

    f32x4 yprev[2] = {};
    bf16x8 pPrev = {};
    #pragma unroll 1
    for (int n = 0; n < NM_; ++n){
      const int sl = n & 1;
      // W(n), b(n) now visible
      bf16x8 Wf0 = *(const bf16x8*)(&WTl[sl][0] + li*40 + 8*lh);
      bf16x8 Wf1 = *(const bf16x8*)(&WTl[sl][0] + (16 + li)*40 + 8*lh);
      const float bb0 = BBl[sl][0][li];
      const float bb1 = BBl[sl][1][li];

      // finish step n-1: Z1_bar = y - P@grad, out-LN, stores
      if (n > 0){
        bf16x8 gf0 = *(const bf16x8*)(&GTl[sl ^ 1][0] + li*24 + gcol);
        bf16x8 gf1 = *(const bf16x8*)(&GTl[sl ^ 1][0] + (16 + li)*24 + gcol);
        yprev[0] = __builtin_amdgcn_mfma_f32_16x16x32_bf16(pPrev, gf0, yprev[0], 0,0,0);
        yprev[1] = __builtin_amdgcn_mfma_f32_16x16x32_bf16(pPrev, gf1, yprev[1], 0,0,0);
        outln(n - 1, yprev);
      }

      P1 nxt = ld1(n + 1 < NM_ ? n + 1 : NM_ - 1);
      const bf16x8 qAf = __builtin_bit_cast(bf16x8, cur.qA);
      const bf16x8 kAf = __builtin_bit_cast(bf16x8, cur.kA);

      *(s16x8*)(&QLl[sl][0] + li*40 + 8*lh) = cur.qA;

      // a = q@kT; transpose via AT
      f32x4 aac = {};
      aac = __builtin_amdgcn_mfma_f32_16x16x32_bf16(qAf, kAf, aac, 0,0,0);
      #pragma unroll
      for (int r = 0; r < 4; ++r)
        AT[(4*lh + r)*20 + li] = aac[r];

      f32x4 arA = {}, arB = {};
      if (lh < 2){
        arA = *(const f32x4*)(AT + li*20 + 8*lh);
        arB = *(const f32x4*)(AT + li*20 + 8*lh + 4);
      }
      const f32x4 plA = (lh & 1) ? cur.lr2 : cur.lr0;
      const f32x4 plB = (lh & 1) ? cur.lr3 : cur.lr1;
      float pv[8];
      #pragma unroll
      for (int jj = 0; jj < 8; ++jj){
        const float av  = (jj < 4) ? arA[jj] : arB[jj - 4];
        const float lrv = (jj < 4) ? plA[jj] : plB[jj - 4];
        const bool ok = (lh < 2) && (8*lh + jj <= li);
        pv[jj] = ok ? -tok_i * lrv * (1.f + av) : 0.f;
      }
      u32x4 ppv;
      ppv[0] = cvtpk(pv[0], pv[1]); ppv[1] = cvtpk(pv[2], pv[3]);
      ppv[2] = cvtpk(pv[4], pv[5]); ppv[3] = cvtpk(pv[6], pv[7]);
      pPrev = __builtin_bit_cast(bf16x8, ppv);

      // y = q@W + b
      { f32x4 c0; c0[0]=bb0; c0[1]=bb0; c0[2]=bb0; c0[3]=bb0;
        yprev[0] = __builtin_amdgcn_mfma_f32_16x16x32_bf16(qAf, Wf0, c0, 0,0,0); }
      { f32x4 c0; c0[0]=bb1; c0[1]=bb1; c0[2]=bb1; c0[3]=bb1;
        yprev[1] = __builtin_amdgcn_mfma_f32_16x16x32_bf16(qAf, Wf1, c0, 0,0,0); }

      cur = nxt;
      wgbar();
    }
    // epilogue: finish n = NM-1 (GT[(NM-1)&1] written before final barrier)
    {
      const int sl = (NM_ - 1) & 1;
      bf16x8 gf0 = *(const bf16x8*)(&GTl[sl][0] + li*24 + gcol);
      bf16x8 gf1 = *(const bf16x8*)(&GTl[sl][0] + (16 + li)*24 + gcol);
      yprev[0] = __builtin_amdgcn_mfma_f32_16x16x32_bf16(pPrev, gf0, yprev[0], 0,0,0);
      yprev[1] = __builtin_amdgcn_mfma_f32_16x16x32_bf16(pPrev, gf1, yprev[1], 0,0,0);
      outln(NM_ - 1, yprev);
    }
  }
}

// ---------------------------------------------------------------------------
extern "C" void kernel_launch(void* const* d_in, const int* in_sizes, int n_in,
                              void* d_out, int out_size, void* d_ws, size_t ws_size,
                              hipStream_t stream)
{
  const float* enc    = (const float*)d_in[0];
  const float* ln0_g  = (const float*)d_in[1];
  const float* ln0_b  = (const float*)d_in[2];
  const float* Wq     = (const float*)d_in[3];
  const float* Wk     = (const float*)d_in[4];
  const float* Wv     = (const float*)d_in[5];
  const float* Wo     = (const float*)d_in[6];
  const float* W1     = (const float*)d_in[7];
  const float* b1     = (const float*)d_in[8];
  const float* tdelta = (const float*)d_in[9];
  const float* lr_w   = (const float*)d_in[10];
  const float* lr_b   = (const float*)d_in[11];
  const float* ttt_g  = (const float*)d_in[12];
  const float* ttt_b  = (const float*)d_in[13];
  const float* post_g = (const float*)d_in[14];
  const float* post_b = (const float*)d_in[15];
  const float* ffn_g  = (const float*)d_in[16];
  const float* ffn_b  = (const float*)d_in[17];
  const float* fw1    = (const float*)d_in[18];
  const float* fb1    = (const float*)d_in[19];
  const float* fw2    = (const float*)d_in[20];
  const float* fb2    = (const float*)d_in[21];

  char* ws = (char*)d_ws;
  short* Q5    = (short*)(ws + 0);            // 134,217,728 B (scan tiles)
  short* XB    = (short*)(ws + 134217728);    //  33,554,432 B
  short* SCANB = (short*)(ws + 134217728);    //  alias XB
  short* WQKVT = (short*)(ws + 167772160);    //   6,291,456 B
  short* WOT   = (short*)(ws + 174063616);    //   2,097,152 B
  short* FW1T  = (short*)(ws + 176160768);    //   4,194,304 B
  short* FW2T  = (short*)(ws + 180355072);    //   4,194,304 B
  short* LRWB  = (short*)(ws + 184549376);    //      65,536 B
  float* CT    = (float*)(ws + 184614912);    //     131,072 B
  float* ST    = (float*)(ws + 184745984);    //     131,072 B
  float* ETA   = (float*)(ws + 184877056);    //   2,097,152 B
  short* YB    = (short*)(ws + 0);            // alias Q5 (post-scan)
  short* HB    = (short*)(ws + 33554432);     // alias Q5
  short* T1    = (short*)(ws + 67108864);     // alias Q5
  float* R2    = (float*)d_out;

  dim3 b256(256), b512(512);
  TC4 tc;
  tc.s0 = Wq; tc.s1 = Wk; tc.s2 = Wv; tc.s3 = Wo;
  tc.d0 = WQKVT; tc.d1 = WQKVT + 1048576; tc.d2 = WQKVT + 2097152; tc.d3 = WOT;
  transpose_cast4<<<dim3(32,32,4), b256, 0, stream>>>(tc);
  transpose_cast<<<dim3(64,32), b256, 0, stream>>>(fw1, FW1T, D_, DI_);
  transpose_cast<<<dim3(32,64), b256, 0, stream>>>(fw2, FW2T, DI_, D_);
  misc_prep<<<dim3(256), b256, 0, stream>>>(lr_w, LRWB, CT, ST);

  ln_rows<<<BL_, b256, 0, stream>>>(enc, ln0_g, ln0_b, XB);
  gemm256<0,0,0,0,1><<<dim3(12,64), b512, 0, stream>>>(XB, WQKVT, nullptr, nullptr,
                                                       nullptr, Q5, CT, ST, BL_, 3072, D_);
  eta_kernel<<<dim3(512), b256, 0, stream>>>(XB, LRWB, lr_b, ETA);
  scan_kernel<<<dim3(256), dim3(128), 0, stream>>>(Q5, ETA, W1, b1, tdelta,
                                                   ttt_g, ttt_b, SCANB);
  ln_rows_bf<<<BL_, b256, 0, stream>>>(SCANB, post_g, post_b, YB);
  gemm256<0,0,0,1,0><<<dim3(4,64), b512, 0, stream>>>(YB, WOT, nullptr, enc,
                                                      R2, nullptr, nullptr, nullptr, BL_, D_, D_);
  ln_rows<<<BL_, b256, 0, stream>>>(R2, ffn_g, ffn_b, HB);
  gemm256<1,1,1,0,0><<<dim3(8,64), b512, 0, stream>>>(HB, FW1T, fb1, nullptr,
                                                      nullptr, T1, nullptr, nullptr, BL_, DI_, D_);
  gemm256<0,0,1,1,0><<<dim3(4,64), b512, 0, stream>>>(T1, FW2T, fb2, R2,
                                                      R2, nullptr, nullptr, nullptr, BL_, D_, DI_);
}

// Round 9
// 696.314 us; speedup vs baseline: 1.5160x; 1.0607x over previous
//
#include <hip/hip_runtime.h>
#include <hip/hip_bf16.h>
#include <stdint.h>

#define B_   8
#define L_   2048
#define D_   1024
#define NH_  32
#define M_   16
#define NM_  128
#define HD_  32
#define DI_  2048
#define BL_  16384
#define EPS_ 1e-6f

typedef __attribute__((ext_vector_type(8))) short  s16x8;
typedef __attribute__((ext_vector_type(4))) short  s16x4;
typedef __attribute__((ext_vector_type(8))) __bf16 bf16x8;
typedef __attribute__((ext_vector_type(4))) float  f32x4;
typedef __attribute__((ext_vector_type(4))) unsigned u32x4;

__device__ __forceinline__ float bf2f(short s){
  unsigned u = ((unsigned)(unsigned short)s) << 16;
  return __builtin_bit_cast(float, u);
}
__device__ __forceinline__ short f2bf(float f){
  unsigned u = __builtin_bit_cast(unsigned, f);
  u = u + 0x7FFFu + ((u >> 16) & 1u);   // RNE
  return (short)(u >> 16);
}
__device__ __forceinline__ unsigned cvtpk(float lo, float hi){
  unsigned r;
  asm("v_cvt_pk_bf16_f32 %0, %1, %2" : "=v"(r) : "v"(lo), "v"(hi));
  return r;
}
template<int N>
__device__ __forceinline__ float ror_add(float v){
  const int y = __builtin_amdgcn_update_dpp(
      0, __builtin_bit_cast(int, v), 0x120 + N, 0xF, 0xF, true);
  return v + __builtin_bit_cast(float, y);
}
__device__ __forceinline__ float rsum16d(float v){
  v = ror_add<1>(v); v = ror_add<2>(v); v = ror_add<4>(v); v = ror_add<8>(v);
  return v;
}
__device__ __forceinline__ void wgbar(){
  asm volatile("s_waitcnt lgkmcnt(0)" ::: "memory");
  __builtin_amdgcn_s_barrier();
  __builtin_amdgcn_sched_barrier(0);
}
__device__ __forceinline__ void gl16(const void* g, void* l){
  __builtin_amdgcn_global_load_lds(
      (const __attribute__((address_space(1))) void*)g,
      (__attribute__((address_space(3))) void*)l, 16, 0, 0);
}

// ---------------- transpose + fp32->bf16 cast: out(Cc,R) = in(R,Cc)^T ------
__global__ __launch_bounds__(256) void transpose_cast(
    const float* __restrict__ in, short* __restrict__ out, int R, int Cc)
{
  __shared__ float t[32][33];
  const int lx = threadIdx.x & 31, ly = threadIdx.x >> 5;
  const int r0 = blockIdx.y * 32, c0 = blockIdx.x * 32;
  #pragma unroll
  for (int s = 0; s < 4; ++s){
    const int r = ly + s*8;
    t[r][lx] = in[(size_t)(r0 + r)*Cc + c0 + lx];
  }
  __syncthreads();
  #pragma unroll
  for (int s = 0; s < 4; ++s){
    const int r = ly + s*8;
    out[(size_t)(c0 + r)*R + r0 + lx] = f2bf(t[lx][r]);
  }
}

struct TC4 { const float *s0,*s1,*s2,*s3; short *d0,*d1,*d2,*d3; };
__global__ __launch_bounds__(256) void transpose_cast4(TC4 p)
{
  __shared__ float t[32][33];
  const int z = blockIdx.z;
  const float* in = (z==0)?p.s0:(z==1)?p.s1:(z==2)?p.s2:p.s3;
  short* out      = (z==0)?p.d0:(z==1)?p.d1:(z==2)?p.d2:p.d3;
  const int lx = threadIdx.x & 31, ly = threadIdx.x >> 5;
  const int r0 = blockIdx.y * 32, c0 = blockIdx.x * 32;
  #pragma unroll
  for (int s = 0; s < 4; ++s){
    const int r = ly + s*8;
    t[r][lx] = in[(size_t)(r0 + r)*1024 + c0 + lx];
  }
  __syncthreads();
  #pragma unroll
  for (int s = 0; s < 4; ++s){
    const int r = ly + s*8;
    out[(size_t)(c0 + r)*1024 + r0 + lx] = f2bf(t[lx][r]);
  }
}

// ---------------- misc prep: lr_w cast + rope tables -----------------------
__global__ __launch_bounds__(256) void misc_prep(
    const float* __restrict__ lr_w, short* __restrict__ lrwb,
    float* __restrict__ ct, float* __restrict__ st)
{
  const int idx = blockIdx.x*256 + threadIdx.x;
  if (idx < NH_*D_){
    lrwb[idx] = f2bf(lr_w[idx]);
  } else {
    const int k = idx - NH_*D_;
    const int l = k >> 4, j = k & 15;
    const float inv = powf(10000.f, -(float)j * (1.f/16.f));
    const float fr  = (float)l * inv;
    ct[k] = cosf(fr);
    st[k] = sinf(fr);
  }
}

// ---------------- row layernorm fp32 -> bf16 (D=1024) ----------------------
__global__ __launch_bounds__(256) void ln_rows(
    const float* __restrict__ in, const float* __restrict__ g,
    const float* __restrict__ bta, short* __restrict__ out)
{
  const int row = blockIdx.x, tid = threadIdx.x;
  const float4 v = ((const float4*)(in + (size_t)row*D_))[tid];
  float s  = v.x + v.y + v.z + v.w;
  float s2 = v.x*v.x + v.y*v.y + v.z*v.z + v.w*v.w;
  #pragma unroll
  for (int m = 1; m < 64; m <<= 1){ s += __shfl_xor(s, m); s2 += __shfl_xor(s2, m); }
  __shared__ float rs[4], rq[4];
  if ((tid & 63) == 0){ rs[tid>>6] = s; rq[tid>>6] = s2; }
  __syncthreads();
  s  = rs[0] + rs[1] + rs[2] + rs[3];
  s2 = rq[0] + rq[1] + rq[2] + rq[3];
  const float mu   = s  * (1.f/D_);
  const float var  = s2 * (1.f/D_) - mu*mu;
  const float rstd = rsqrtf(var + EPS_);
  const float4 gg = ((const float4*)g)[tid];
  const float4 bb = ((const float4*)bta)[tid];
  s16x4 o;
  o[0] = f2bf((v.x - mu)*rstd*gg.x + bb.x);
  o[1] = f2bf((v.y - mu)*rstd*gg.y + bb.y);
  o[2] = f2bf((v.z - mu)*rstd*gg.z + bb.z);
  o[3] = f2bf((v.w - mu)*rstd*gg.w + bb.w);
  ((s16x4*)(out + (size_t)row*D_))[tid] = o;
}

// ---------------- row layernorm bf16 -> bf16 (D=1024) ----------------------
__global__ __launch_bounds__(256) void ln_rows_bf(
    const short* __restrict__ in, const float* __restrict__ g,
    const float* __restrict__ bta, short* __restrict__ out)
{
  const int row = blockIdx.x, tid = threadIdx.x;
  const s16x4 v4 = ((const s16x4*)(in + (size_t)row*D_))[tid];
  float v[4];
  #pragma unroll
  for (int e = 0; e < 4; ++e) v[e] = bf2f(v4[e]);
  float s  = v[0]+v[1]+v[2]+v[3];
  float s2 = v[0]*v[0]+v[1]*v[1]+v[2]*v[2]+v[3]*v[3];
  #pragma unroll
  for (int m = 1; m < 64; m <<= 1){ s += __shfl_xor(s, m); s2 += __shfl_xor(s2, m); }
  __shared__ float rs[4], rq[4];
  if ((tid & 63) == 0){ rs[tid>>6] = s; rq[tid>>6] = s2; }
  __syncthreads();
  s  = rs[0] + rs[1] + rs[2] + rs[3];
  s2 = rq[0] + rq[1] + rq[2] + rq[3];
  const float mu   = s  * (1.f/D_);
  const float var  = s2 * (1.f/D_) - mu*mu;
  const float rstd = rsqrtf(var + EPS_);
  const float4 gg = ((const float4*)g)[tid];
  const float4 bb = ((const float4*)bta)[tid];
  s16x4 o;
  #pragma unroll
  for (int e = 0; e < 4; ++e){
    const float gv = (e==0)?gg.x:(e==1)?gg.y:(e==2)?gg.z:gg.w;
    const float bv = (e==0)?bb.x:(e==1)?bb.y:(e==2)?bb.z:bb.w;
    o[e] = f2bf((v[e] - mu)*rstd*gv + bv);
  }
  ((s16x4*)(out + (size_t)row*D_))[tid] = o;
}

// ---------------- 256x256 8-wave phase-structured bf16 GEMM ----------------
// LDS swizzle: col' = col ^ ((row&7)<<3)  (8-elem granularity, full 128B row)
template<int ACT, int OUTBF, int BIAS, int RES, int QKVOUT>
__global__ __launch_bounds__(512, 2) void gemm256(
    const short* __restrict__ A, const short* __restrict__ Bt,
    const float* __restrict__ bias, const float* __restrict__ res,
    float* __restrict__ Cf, short* __restrict__ Cb,
    const float* __restrict__ ct, const float* __restrict__ st,
    int Mr, int N, int K)
{
  __shared__ __align__(16) short As[2][16384];
  __shared__ __align__(16) short Bs[2][16384];
  const int tid  = threadIdx.x;
  const int lane = tid & 63, wid = tid >> 6;
  const int wr = wid >> 2, wc = wid & 3;
  const int nwg = gridDim.x * gridDim.y;
  const int wg  = blockIdx.y * gridDim.x + blockIdx.x;
  const int swz = (wg & 7) * (nwg >> 3) + (wg >> 3);
  const int bx  = swz % gridDim.x, by = swz / gridDim.x;
  const int row0 = by * 256, col0 = bx * 256;

  f32x4 acc[8][4] = {};

  // source pre-swizzled so linear LDS holds swizzled data (row = tid>>3)
  const int kswz = ((tid & 7) * 8) ^ (((tid >> 3) & 7) << 3);
  const short* gAb = A  + (size_t)(row0 + (tid >> 3)) * K + kswz;
  const short* gBb = Bt + (size_t)(col0 + (tid >> 3)) * K + kswz;
  short* lAb = &As[0][0] + tid*8;
  short* lBb = &Bs[0][0] + tid*8;

  auto stageA = [&](int d, int kt2){
    const size_t kb = (size_t)kt2 * 64;
    gl16(gAb + kb,                   lAb + d*16384);
    gl16(gAb + kb +  64*(size_t)K,   lAb + d*16384 + 4096);
    gl16(gAb + kb + 128*(size_t)K,   lAb + d*16384 + 8192);
    gl16(gAb + kb + 192*(size_t)K,   lAb + d*16384 + 12288);
  };
  auto stageB = [&](int d, int kt2){
    const size_t kb = (size_t)kt2 * 64;
    gl16(gBb + kb,                   lBb + d*16384);
    gl16(gBb + kb +  64*(size_t)K,   lBb + d*16384 + 4096);
    gl16(gBb + kb + 128*(size_t)K,   lBb + d*16384 + 8192);
    gl16(gBb + kb + 192*(size_t)K,   lBb + d*16384 + 12288);
  };

  const int fr  = lane & 15;
  const int fk8 = (lane >> 4) * 8;
  const int k0  = fk8 ^ ((lane & 7) << 3);   // read-side swizzle (row&7 = lane&7)
  const short* Ah = &As[0][0] + wr*8192;
  const short* Bh = &Bs[0][0] + (wc >> 1)*8192 + (wc & 1)*4096;

  stageA(0, 0); stageB(0, 0);
  asm volatile("s_waitcnt vmcnt(0)" ::: "memory");
  __builtin_amdgcn_s_barrier();

  const int nK = K >> 6;
  bf16x8 bfv[4][2];
  for (int kt = 0; kt < nK; ++kt){
    const int c = kt & 1;
    const bool pf = (kt + 1 < nK);
    const short* Ab = Ah + c*16384;
    const short* Bb = Bh + c*16384;
    #pragma unroll
    for (int q = 0; q < 4; ++q){
      bf16x8 af[2];
      bf16x8 af1[2];
      #pragma unroll
      for (int mm = 0; mm < 2; ++mm){
        const int rh = (2*q + mm)*16 + fr;
        af[mm]  = *(const bf16x8*)(Ab + rh*64 + k0);
        af1[mm] = *(const bf16x8*)(Ab + rh*64 + (k0 ^ 32));
      }
      if (q == 0){
        #pragma unroll
        for (int n = 0; n < 4; ++n){
          const int rh = n*16 + fr;
          bfv[n][0] = *(const bf16x8*)(Bb + rh*64 + k0);
          bfv[n][1] = *(const bf16x8*)(Bb + rh*64 + (k0 ^ 32));
        }
      }
      if (pf){
        if (q == 0)      stageA(c ^ 1, kt + 1);
        else if (q == 1) stageB(c ^ 1, kt + 1);
      }
      __builtin_amdgcn_s_barrier();
      asm volatile("s_waitcnt lgkmcnt(0)" ::: "memory");
      __builtin_amdgcn_sched_barrier(0);
      __builtin_amdgcn_s_setprio(1);
      #pragma unroll
      for (int mm = 0; mm < 2; ++mm)
        #pragma unroll
        for (int n = 0; n < 4; ++n){
          acc[2*q+mm][n] = __builtin_amdgcn_mfma_f32_16x16x32_bf16(af[mm],  bfv[n][0], acc[2*q+mm][n], 0,0,0);
          acc[2*q+mm][n] = __builtin_amdgcn_mfma_f32_16x16x32_bf16(af1[mm], bfv[n][1], acc[2*q+mm][n], 0,0,0);
        }
      __builtin_amdgcn_s_setprio(0);
      if (q < 3) __builtin_amdgcn_s_barrier();
    }
    if (pf) asm volatile("s_waitcnt vmcnt(0)" ::: "memory");
    __builtin_amdgcn_s_barrier();
  }

  const int cr = (lane >> 4) * 4, cc = lane & 15;
  if (QKVOUT){
    const int part = col0 >> 10;
    #pragma unroll
    for (int m = 0; m < 8; ++m){
      const int gr0 = row0 + wr*128 + m*16 + cr;
      const int bidx = gr0 >> 11, l0 = gr0 & (L_-1);
      const int nn = l0 >> 4;
      if (part < 2){
        #pragma unroll
        for (int np = 0; np < 2; ++np){
          const int gc = col0 + wc*64 + np*32 + cc;
          const int hh = (gc & 1023) >> 5;
          short* tile = Cb + ((size_t)(bidx*NH_ + hh)*NM_ + nn)*2048;
          s16x4 r0v, r1v;
          #pragma unroll
          for (int r = 0; r < 4; ++r){
            const int l = l0 + r;
            const float cv = ct[l*16 + cc], sv = st[l*16 + cc];
            const float x0 = acc[m][np*2][r], x1 = acc[m][np*2+1][r];
            const short q0 = f2bf(x0*cv - x1*sv);
            const short q1 = f2bf(x1*cv + x0*sv);
            tile[part*512 + (cr + r)*32 + cc]      = q0;
            tile[part*512 + (cr + r)*32 + cc + 16] = q1;
            r0v[r] = q0; r1v[r] = q1;
          }
          if (part == 1){
            *(s16x4*)(tile + 1024 + cc*16 + cr)      = r0v;
            *(s16x4*)(tile + 1024 + (cc+16)*16 + cr) = r1v;
          }
        }
      } else {
        #pragma unroll
        for (int n = 0; n < 4; ++n){
          const int gc = col0 + wc*64 + n*16 + cc;
          const int hh = (gc & 1023) >> 5, dd = gc & 31;
          short* tile = Cb + ((size_t)(bidx*NH_ + hh)*NM_ + nn)*2048;
          s16x4 p;
          #pragma unroll
          for (int r = 0; r < 4; ++r) p[r] = f2bf(acc[m][n][r]);
          *(s16x4*)(tile + 1536 + dd*16 + cr) = p;
        }
      }
    }
    return;
  }
  #pragma unroll
  for (int m = 0; m < 8; ++m){
    #pragma unroll
    for (int n = 0; n < 4; ++n){
      const int gc = col0 + wc*64 + n*16 + cc;
      float bv = 0.f;
      if (BIAS) bv = bias[gc];
      #pragma unroll
      for (int r = 0; r < 4; ++r){
        const int gr = row0 + wr*128 + m*16 + cr + r;
        float v = acc[m][n][r] + bv;
        if (RES) v += res[(size_t)gr*N + gc];
        if (ACT == 1) v = fmaxf(v, 0.f);
        if (OUTBF) Cb[(size_t)gr*N + gc] = f2bf(v);
        else       Cf[(size_t)gr*N + gc] = v;
      }
    }
  }
}

// ---------------- eta: sigmoid(x . lr_w[h] + lr_b[h]) / HD -----------------
__global__ __launch_bounds__(256) void eta_kernel(
    const short* __restrict__ xb, const short* __restrict__ lrwb,
    const float* __restrict__ lr_b, float* __restrict__ eta)
{
  __shared__ __align__(16) short wl[NH_*D_];
  __shared__ __align__(16) short xr[D_];
  const int tid = threadIdx.x;
  const int wid = tid >> 6, lane = tid & 63;
  #pragma unroll
  for (int s = 0; s < 16; ++s){
    const int e8 = tid + 256*s;
    ((s16x8*)wl)[e8] = ((const s16x8*)lrwb)[e8];
  }
  for (int tk = 0; tk < 32; ++tk){
    const int token = blockIdx.x*32 + tk;
    __syncthreads();
    if (tid < 128) ((s16x8*)xr)[tid] = ((const s16x8*)(xb + (size_t)token*D_))[tid];
    __syncthreads();
    const s16x8 x0 = ((const s16x8*)xr)[lane*2];
    const s16x8 x1 = ((const s16x8*)xr)[lane*2 + 1];
    #pragma unroll 1
    for (int hh = 0; hh < 8; ++hh){
      const int h = wid*8 + hh;
      const s16x8 w0 = ((const s16x8*)(wl + h*D_))[lane*2];
      const s16x8 w1 = ((const s16x8*)(wl + h*D_))[lane*2 + 1];
      float s = 0.f;
      #pragma unroll
      for (int e = 0; e < 8; ++e)
        s += bf2f(x0[e])*bf2f(w0[e]) + bf2f(x1[e])*bf2f(w1[e]);
      #pragma unroll
      for (int m = 1; m < 64; m <<= 1) s += __shfl_xor(s, m);
      if (lane == 0){
        const float v = 1.f/(1.f + __expf(-(s + lr_b[h]))) * (1.f/32.f);
        const int bidx = token >> 11, l = token & (L_-1), n = l >> 4, im = l & 15;
        eta[(((size_t)bidx*NH_ + h)*NM_ + n)*M_ + im] = v;
      }
    }
  }
}

// ---------------- TTT scan v7: 2 waves, 1 barrier/step, LDS transposes -----
__global__ __launch_bounds__(128) void scan_kernel(
    const short* __restrict__ Q5, const float* __restrict__ eta,
    const float* __restrict__ W1, const float* __restrict__ b1,
    const float* __restrict__ tdelta, const float* __restrict__ lng,
    const float* __restrict__ lnb, short* __restrict__ out)
{
  const int bh = blockIdx.x;
  const int h = bh & 31, b = bh >> 5;
  const int lane = threadIdx.x & 63;
  const int wv = threadIdx.x >> 6;
  const int li = lane & 15, lh = lane >> 4;

  __shared__ __align__(16) short WTl[2][32*40];
  __shared__ __align__(16) short GTl[2][32*24];
  __shared__ float BBl[2][2][16];
  __shared__ __align__(16) float AT[16*20];
  __shared__ __align__(16) short QLl[2][16*40];

  const short* chain = Q5 + (size_t)bh * (NM_*2048);
  const float* ech   = eta + (size_t)bh * (NM_*16);

  float lw[2], lbv[2];
  #pragma unroll
  for (int hh = 0; hh < 2; ++hh){
    lw[hh]  = lng[h*32 + 16*hh + li];
    lbv[hh] = lnb[h*32 + 16*hh + li];
  }

  if (wv == 0){
    f32x4 Wq[2][2];
    #pragma unroll
    for (int rb = 0; rb < 2; ++rb)
      #pragma unroll
      for (int cb = 0; cb < 2; ++cb)
        #pragma unroll
        for (int r = 0; r < 4; ++r)
          Wq[rb][cb][r] = W1[h*1024 + (16*rb + 4*lh + r)*32 + 16*cb + li];
    float bb[2];
    bb[0] = b1[h*32 + li];  bb[1] = b1[h*32 + 16 + li];
    const float lef = fmaxf(1.f/16.f + tdelta[15], 0.f);

    auto writeWT = [&](int sl){
      #pragma unroll
      for (int cb = 0; cb < 2; ++cb)
        #pragma unroll
        for (int rb = 0; rb < 2; ++rb){
          const unsigned p0 = cvtpk(Wq[rb][cb][0], Wq[rb][cb][1]);
          const unsigned p1 = cvtpk(Wq[rb][cb][2], Wq[rb][cb][3]);
          *(uint64_t*)(&WTl[sl][0] + (16*cb + li)*40 + 16*rb + 4*lh) =
              ((uint64_t)p1 << 32) | p0;
        }
    };
    auto readWf = [&](int sl, bf16x8* Wf){
      Wf[0] = *(const bf16x8*)(&WTl[sl][0] + li*40 + 8*lh);
      Wf[1] = *(const bf16x8*)(&WTl[sl][0] + (16 + li)*40 + 8*lh);
    };

    writeWT(0);
    if (lh == 0){ BBl[0][0][li] = bb[0]; BBl[0][1][li] = bb[1]; }
    bf16x8 Wf[2];
    readWf(0, Wf);

    struct P0 { s16x8 kA, kTq0, kTq1; s16x4 kTe0, kTe1, vTe0, vTe1;
                f32x4 lr0, lr1, lr2, lr3; };
    auto ld0 = [&](int n) -> P0 {
      const short* t = chain + (size_t)n*2048;
      const float* e = ech + n*16;
      P0 p;
      p.kA   = *(const s16x8*)(t + 512 + li*32 + 8*lh);
      p.kTq0 = *(const s16x8*)(t + 1024 + li*16 + 8*(lh & 1));
      p.kTq1 = *(const s16x8*)(t + 1024 + (16 + li)*16 + 8*(lh & 1));
      p.kTe0 = *(const s16x4*)(t + 1024 + li*16 + 4*lh);
      p.kTe1 = *(const s16x4*)(t + 1024 + (16 + li)*16 + 4*lh);
      p.vTe0 = *(const s16x4*)(t + 1536 + li*16 + 4*lh);
      p.vTe1 = *(const s16x4*)(t + 1536 + (16 + li)*16 + 4*lh);
      p.lr0 = *(const f32x4*)(e);     p.lr1 = *(const f32x4*)(e + 4);
      p.lr2 = *(const f32x4*)(e + 8); p.lr3 = *(const f32x4*)(e + 12);
      return p;
    };

    P0 cur = ld0(0);
    wgbar();

    const int gcol = (8*lh) & 15;
    #pragma unroll 1
    for (int n = 0; n < NM_; ++n){
      const int sl = n & 1;
      P0 nxt = ld0(n + 1 < NM_ ? n + 1 : NM_ - 1);
      const bf16x8 kAf = __builtin_bit_cast(bf16x8, cur.kA);

      f32x4 zac[2];
      #pragma unroll
      for (int hh = 0; hh < 2; ++hh){
        f32x4 c0; c0[0]=bb[hh]; c0[1]=bb[hh]; c0[2]=bb[hh]; c0[3]=bb[hh];
        zac[hh] = __builtin_amdgcn_mfma_f32_16x16x32_bf16(kAf, Wf[hh], c0, 0,0,0);
      }

      float xh[2][4], grad[2][4], rstdv[4];
      #pragma unroll
      for (int r = 0; r < 4; ++r){
        float s  = rsum16d(zac[0][r] + zac[1][r]);
        float q2 = rsum16d(zac[0][r]*zac[0][r] + zac[1][r]*zac[1][r]);
        const float mu  = s * (1.f/32.f);
        const float var = q2 * (1.f/32.f) - mu*mu;
        const float rstd = rsqrtf(var + EPS_);
        rstdv[r] = rstd;
        xh[0][r] = (zac[0][r] - mu) * rstd;
        xh[1][r] = (zac[1][r] - mu) * rstd;
      }
      #pragma unroll
      for (int r = 0; r < 4; ++r){
        const float t0 = bf2f(cur.vTe0[r]) - bf2f(cur.kTe0[r]);
        const float t1 = bf2f(cur.vTe1[r]) - bf2f(cur.kTe1[r]);
        const float g0 = (xh[0][r]*lw[0] + lbv[0] - t0)*lw[0];
        const float g1 = (xh[1][r]*lw[1] + lbv[1] - t1)*lw[1];
        const float sg  = rsum16d(g0 + g1);
        const float sgx = rsum16d(g0*xh[0][r] + g1*xh[1][r]);
        const float f = rstdv[r] * (1.f/32.f);
        grad[0][r] = (32.f*g0 - sg - xh[0][r]*sgx) * f;
        grad[1][r] = (32.f*g1 - sg - xh[1][r]*sgx) * f;
      }

      #pragma unroll
      for (int hh = 0; hh < 2; ++hh){
        const unsigned p0 = cvtpk(grad[hh][0], grad[hh][1]);
        const unsigned p1 = cvtpk(grad[hh][2], grad[hh][3]);
        *(uint64_t*)(&GTl[sl][0] + (16*hh + li)*24 + 4*lh) =
            ((uint64_t)p1 << 32) | p0;
      }
      bf16x8 gf[2];
      gf[0] = *(const bf16x8*)(&GTl[sl][0] + li*24 + gcol);
      gf[1] = *(const bf16x8*)(&GTl[sl][0] + (16 + li)*24 + gcol);

      const f32x4 plA = (lh & 1) ? cur.lr2 : cur.lr0;
      const f32x4 plB = (lh & 1) ? cur.lr3 : cur.lr1;
      #pragma unroll
      for (int rb = 0; rb < 2; ++rb){
        const s16x8 kq = rb ? cur.kTq1 : cur.kTq0;
        float av8[8];
        #pragma unroll
        for (int jj = 0; jj < 8; ++jj){
          const float lrv = (jj < 4) ? plA[jj] : plB[jj - 4];
          av8[jj] = (lh < 2) ? -lef * lrv * bf2f(kq[jj]) : 0.f;
        }
        u32x4 auv;
        auv[0] = cvtpk(av8[0], av8[1]); auv[1] = cvtpk(av8[2], av8[3]);
        auv[2] = cvtpk(av8[4], av8[5]); auv[3] = cvtpk(av8[6], av8[7]);
        const bf16x8 af = __builtin_bit_cast(bf16x8, auv);
        #pragma unroll
        for (int cb = 0; cb < 2; ++cb)
          Wq[rb][cb] = __builtin_amdgcn_mfma_f32_16x16x32_bf16(af, gf[cb], Wq[rb][cb], 0,0,0);
      }

      f32x4 lrq;
      { const f32x4 t0 = (lh & 1) ? cur.lr1 : cur.lr0;
        const f32x4 t1 = (lh & 1) ? cur.lr3 : cur.lr2;
        lrq = (lh & 2) ? t1 : t0; }
      #pragma unroll
      for (int hh = 0; hh < 2; ++hh){
        float t = 0.f;
        #pragma unroll
        for (int r = 0; r < 4; ++r) t += lrq[r]*grad[hh][r];
        t += __shfl_xor(t, 16); t += __shfl_xor(t, 32);
        bb[hh] -= lef * t;
      }

      writeWT(sl ^ 1);
      if (lh == 0){ BBl[sl ^ 1][0][li] = bb[0]; BBl[sl ^ 1][1][li] = bb[1]; }
      readWf(sl ^ 1, Wf);
      cur = nxt;
      wgbar();
    }
  } else {
    const float tok_i = fmaxf(1.f/(float)(li+1) + tdelta[li], 0.f);
    short* outp = out + (size_t)b*L_*D_ + h*32;
    const int gcol = (8*lh) & 15;

    struct P1 { s16x8 qA, kA; f32x4 lr0, lr1, lr2, lr3; };
    auto ld1 = [&](int n) -> P1 {
      const short* t = chain + (size_t)n*2048;
      const float* e = ech + n*16;
      P1 p;
      p.qA = *(const s16x8*)(t + li*32 + 8*lh);
      p.kA = *(const s16x8*)(t + 512 + li*32 + 8*lh);
      p.lr0 = *(const f32x4*)(e);     p.lr1 = *(const f32x4*)(e + 4);
      p.lr2 = *(const f32x4*)(e + 8); p.lr3 = *(const f32x4*)(e + 12);
      return p;
    };

    auto outln = [&](int n, const f32x4* yac){
      #pragma unroll
      for (int r = 0; r < 4; ++r){
        const float s  = rsum16d(yac[0][r] + yac[1][r]);
        const float q2 = rsum16d(yac[0][r]*yac[0][r] + yac[1][r]*yac[1][r]);
        const float mu   = s * (1.f/32.f);
        const float var  = q2 * (1.f/32.f) - mu*mu;
        const float rstd = rsqrtf(var + EPS_);
        const int row = 4*lh + r;
        #pragma unroll
        for (int hh = 0; hh < 2; ++hh){
          const float qv = bf2f(QLl[n & 1][row*40 + 16*hh + li]);
          const float o  = qv + (yac[hh][r] - mu)*rstd*lw[hh] + lbv[hh];
          outp[(size_t)(n*16 + row)*D_ + 16*hh + li] = f2bf(o);
        }
      }
    };

    P1 cur = ld1(0);
    wgbar();

    f32x4 yprev[2] = {};
    bf16x8 pPrev = {};
    #pragma unroll 1
    for (int n = 0; n < NM_; ++n){
      const int sl = n & 1;
      bf16x8 Wf0 = *(const bf16x8*)(&WTl[sl][0] + li*40 + 8*lh);
      bf16x8 Wf1 = *(const bf16x8*)(&WTl[sl][0] + (16 + li)*40 + 8*lh);
      const float bb0 = BBl[sl][0][li];
      const float bb1 = BBl[sl][1][li];

      if (n > 0){
        bf16x8 gf0 = *(const bf16x8*)(&GTl[sl ^ 1][0] + li*24 + gcol);
        bf16x8 gf1 = *(const bf16x8*)(&GTl[sl ^ 1][0] + (16 + li)*24 + gcol);
        yprev[0] = __builtin_amdgcn_mfma_f32_16x16x32_bf16(pPrev, gf0, yprev[0], 0,0,0);
        yprev[1] = __builtin_amdgcn_mfma_f32_16x16x32_bf16(pPrev, gf1, yprev[1], 0,0,0);
        outln(n - 1, yprev);
      }

      P1 nxt = ld1(n + 1 < NM_ ? n + 1 : NM_ - 1);
      const bf16x8 qAf = __builtin_bit_cast(bf16x8, cur.qA);
      const bf16x8 kAf = __builtin_bit_cast(bf16x8, cur.kA);

      *(s16x8*)(&QLl[sl][0] + li*40 + 8*lh) = cur.qA;

      f32x4 aac = {};
      aac = __builtin_amdgcn_mfma_f32_16x16x32_bf16(qAf, kAf, aac, 0,0,0);
      #pragma unroll
      for (int r = 0; r < 4; ++r)
        AT[(4*lh + r)*20 + li] = aac[r];

      f32x4 arA = {}, arB = {};
      if (lh < 2){
        arA = *(const f32x4*)(AT + li*20 + 8*lh);
        arB = *(const f32x4*)(AT + li*20 + 8*lh + 4);
      }
      const f32x4 plA = (lh & 1) ? cur.lr2 : cur.lr0;
      const f32x4 plB = (lh & 1) ? cur.lr3 : cur.lr1;
      float pv[8];
      #pragma unroll
      for (int jj = 0; jj < 8; ++jj){
        const float av  = (jj < 4) ? arA[jj] : arB[jj - 4];
        const float lrv = (jj < 4) ? plA[jj] : plB[jj - 4];
        const bool ok = (lh < 2) && (8*lh + jj <= li);
        pv[jj] = ok ? -tok_i * lrv * (1.f + av) : 0.f;
      }
      u32x4 ppv;
      ppv[0] = cvtpk(pv[0], pv[1]); ppv[1] = cvtpk(pv[2], pv[3]);
      ppv[2] = cvtpk(pv[4], pv[5]); ppv[3] = cvtpk(pv[6], pv[7]);
      pPrev = __builtin_bit_cast(bf16x8, ppv);

      { f32x4 c0; c0[0]=bb0; c0[1]=bb0; c0[2]=bb0; c0[3]=bb0;
        yprev[0] = __builtin_amdgcn_mfma_f32_16x16x32_bf16(qAf, Wf0, c0, 0,0,0); }
      { f32x4 c0; c0[0]=bb1; c0[1]=bb1; c0[2]=bb1; c0[3]=bb1;
        yprev[1] = __builtin_amdgcn_mfma_f32_16x16x32_bf16(qAf, Wf1, c0, 0,0,0); }

      cur = nxt;
      wgbar();
    }
    {
      const int sl = (NM_ - 1) & 1;
      bf16x8 gf0 = *(const bf16x8*)(&GTl[sl][0] + li*24 + gcol);
      bf16x8 gf1 = *(const bf16x8*)(&GTl[sl][0] + (16 + li)*24 + gcol);
      yprev[0] = __builtin_amdgcn_mfma_f32_16x16x32_bf16(pPrev, gf0, yprev[0], 0,0,0);
      yprev[1] = __builtin_amdgcn_mfma_f32_16x16x32_bf16(pPrev, gf1, yprev[1], 0,0,0);
      outln(NM_ - 1, yprev);
    }
  }
}

// ---------------------------------------------------------------------------
extern "C" void kernel_launch(void* const* d_in, const int* in_sizes, int n_in,
                              void* d_out, int out_size, void* d_ws, size_t ws_size,
                              hipStream_t stream)
{
  const float* enc    = (const float*)d_in[0];
  const float* ln0_g  = (const float*)d_in[1];
  const float* ln0_b  = (const float*)d_in[2];
  const float* Wq     = (const float*)d_in[3];
  const float* Wk     = (const float*)d_in[4];
  const float* Wv     = (const float*)d_in[5];
  const float* Wo     = (const float*)d_in[6];
  const float* W1     = (const float*)d_in[7];
  const float* b1     = (const float*)d_in[8];
  const float* tdelta = (const float*)d_in[9];
  const float* lr_w   = (const float*)d_in[10];
  const float* lr_b   = (const float*)d_in[11];
  const float* ttt_g  = (const float*)d_in[12];
  const float* ttt_b  = (const float*)d_in[13];
  const float* post_g = (const float*)d_in[14];
  const float* post_b = (const float*)d_in[15];
  const float* ffn_g  = (const float*)d_in[16];
  const float* ffn_b  = (const float*)d_in[17];
  const float* fw1    = (const float*)d_in[18];
  const float* fb1    = (const float*)d_in[19];
  const float* fw2    = (const float*)d_in[20];
  const float* fb2    = (const float*)d_in[21];

  char* ws = (char*)d_ws;
  short* Q5    = (short*)(ws + 0);            // 134,217,728 B (scan tiles)
  short* XB    = (short*)(ws + 134217728);    //  33,554,432 B
  short* SCANB = (short*)(ws + 134217728);    //  alias XB
  short* WQKVT = (short*)(ws + 167772160);    //   6,291,456 B
  short* WOT   = (short*)(ws + 174063616);    //   2,097,152 B
  short* FW1T  = (short*)(ws + 176160768);    //   4,194,304 B
  short* FW2T  = (short*)(ws + 180355072);    //   4,194,304 B
  short* LRWB  = (short*)(ws + 184549376);    //      65,536 B
  float* CT    = (float*)(ws + 184614912);    //     131,072 B
  float* ST    = (float*)(ws + 184745984);    //     131,072 B
  float* ETA   = (float*)(ws + 184877056);    //   2,097,152 B
  short* YB    = (short*)(ws + 0);            // alias Q5 (post-scan)
  short* HB    = (short*)(ws + 33554432);     // alias Q5
  short* T1    = (short*)(ws + 67108864);     // alias Q5
  float* R2    = (float*)d_out;

  dim3 b256(256), b512(512);
  TC4 tc;
  tc.s0 = Wq; tc.s1 = Wk; tc.s2 = Wv; tc.s3 = Wo;
  tc.d0 = WQKVT; tc.d1 = WQKVT + 1048576; tc.d2 = WQKVT + 2097152; tc.d3 = WOT;
  transpose_cast4<<<dim3(32,32,4), b256, 0, stream>>>(tc);
  transpose_cast<<<dim3(64,32), b256, 0, stream>>>(fw1, FW1T, D_, DI_);
  transpose_cast<<<dim3(32,64), b256, 0, stream>>>(fw2, FW2T, DI_, D_);
  misc_prep<<<dim3(256), b256, 0, stream>>>(lr_w, LRWB, CT, ST);

  ln_rows<<<BL_, b256, 0, stream>>>(enc, ln0_g, ln0_b, XB);
  gemm256<0,0,0,0,1><<<dim3(12,64), b512, 0, stream>>>(XB, WQKVT, nullptr, nullptr,
                                                       nullptr, Q5, CT, ST, BL_, 3072, D_);
  eta_kernel<<<dim3(512), b256, 0, stream>>>(XB, LRWB, lr_b, ETA);
  scan_kernel<<<dim3(256), dim3(128), 0, stream>>>(Q5, ETA, W1, b1, tdelta,
                                                   ttt_g, ttt_b, SCANB);
  ln_rows_bf<<<BL_, b256, 0, stream>>>(SCANB, post_g, post_b, YB);
  gemm256<0,0,0,1,0><<<dim3(4,64), b512, 0, stream>>>(YB, WOT, nullptr, enc,
                                                      R2, nullptr, nullptr, nullptr, BL_, D_, D_);
  ln_rows<<<BL_, b256, 0, stream>>>(R2, ffn_g, ffn_b, HB);
  gemm256<1,1,1,0,0><<<dim3(8,64), b512, 0, stream>>>(HB, FW1T, fb1, nullptr,
                                                      nullptr, T1, nullptr, nullptr, BL_, DI_, D_);
  gemm256<0,0,1,1,0><<<dim3(4,64), b512, 0, stream>>>(T1, FW2T, fb2, R2,
                                                      R2, nullptr, nullptr, nullptr, BL_, D_, DI_);
}

// Round 10
// 679.577 us; speedup vs baseline: 1.5533x; 1.0246x over previous
//
#include <hip/hip_runtime.h>
#include <hip/hip_bf16.h>
#include <stdint.h>

#define B_   8
#define L_   2048
#define D_   1024
#define NH_  32
#define M_   16
#define NM_  128
#define HD_  32
#define DI_  2048
#define BL_  16384
#define EPS_ 1e-6f

typedef __attribute__((ext_vector_type(8))) short  s16x8;
typedef __attribute__((ext_vector_type(4))) short  s16x4;
typedef __attribute__((ext_vector_type(8))) __bf16 bf16x8;
typedef __attribute__((ext_vector_type(4))) float  f32x4;
typedef __attribute__((ext_vector_type(4))) unsigned u32x4;

__device__ __forceinline__ float bf2f(short s){
  unsigned u = ((unsigned)(unsigned short)s) << 16;
  return __builtin_bit_cast(float, u);
}
__device__ __forceinline__ short f2bf(float f){
  unsigned u = __builtin_bit_cast(unsigned, f);
  u = u + 0x7FFFu + ((u >> 16) & 1u);   // RNE
  return (short)(u >> 16);
}
__device__ __forceinline__ unsigned cvtpk(float lo, float hi){
  unsigned r;
  asm("v_cvt_pk_bf16_f32 %0, %1, %2" : "=v"(r) : "v"(lo), "v"(hi));
  return r;
}
template<int N>
__device__ __forceinline__ float ror_add(float v){
  const int y = __builtin_amdgcn_update_dpp(
      0, __builtin_bit_cast(int, v), 0x120 + N, 0xF, 0xF, true);
  return v + __builtin_bit_cast(float, y);
}
__device__ __forceinline__ float rsum16d(float v){
  v = ror_add<1>(v); v = ror_add<2>(v); v = ror_add<4>(v); v = ror_add<8>(v);
  return v;
}
__device__ __forceinline__ void wgbar(){
  asm volatile("s_waitcnt lgkmcnt(0)" ::: "memory");
  __builtin_amdgcn_s_barrier();
  __builtin_amdgcn_sched_barrier(0);
}
__device__ __forceinline__ void gl16(const void* g, void* l){
  __builtin_amdgcn_global_load_lds(
      (const __attribute__((address_space(1))) void*)g,
      (__attribute__((address_space(3))) void*)l, 16, 0, 0);
}

// ---------------- transpose + fp32->bf16 cast: out(Cc,R) = in(R,Cc)^T ------
__global__ __launch_bounds__(256) void transpose_cast(
    const float* __restrict__ in, short* __restrict__ out, int R, int Cc)
{
  __shared__ float t[32][33];
  const int lx = threadIdx.x & 31, ly = threadIdx.x >> 5;
  const int r0 = blockIdx.y * 32, c0 = blockIdx.x * 32;
  #pragma unroll
  for (int s = 0; s < 4; ++s){
    const int r = ly + s*8;
    t[r][lx] = in[(size_t)(r0 + r)*Cc + c0 + lx];
  }
  __syncthreads();
  #pragma unroll
  for (int s = 0; s < 4; ++s){
    const int r = ly + s*8;
    out[(size_t)(c0 + r)*R + r0 + lx] = f2bf(t[lx][r]);
  }
}

struct TC4 { const float *s0,*s1,*s2,*s3; short *d0,*d1,*d2,*d3; };
__global__ __launch_bounds__(256) void transpose_cast4(TC4 p)
{
  __shared__ float t[32][33];
  const int z = blockIdx.z;
  const float* in = (z==0)?p.s0:(z==1)?p.s1:(z==2)?p.s2:p.s3;
  short* out      = (z==0)?p.d0:(z==1)?p.d1:(z==2)?p.d2:p.d3;
  const int lx = threadIdx.x & 31, ly = threadIdx.x >> 5;
  const int r0 = blockIdx.y * 32, c0 = blockIdx.x * 32;
  #pragma unroll
  for (int s = 0; s < 4; ++s){
    const int r = ly + s*8;
    t[r][lx] = in[(size_t)(r0 + r)*1024 + c0 + lx];
  }
  __syncthreads();
  #pragma unroll
  for (int s = 0; s < 4; ++s){
    const int r = ly + s*8;
    out[(size_t)(c0 + r)*1024 + r0 + lx] = f2bf(t[lx][r]);
  }
}

// ---------------- misc prep: lr_w cast + rope tables -----------------------
__global__ __launch_bounds__(256) void misc_prep(
    const float* __restrict__ lr_w, short* __restrict__ lrwb,
    float* __restrict__ ct, float* __restrict__ st)
{
  const int idx = blockIdx.x*256 + threadIdx.x;
  if (idx < NH_*D_){
    lrwb[idx] = f2bf(lr_w[idx]);
  } else {
    const int k = idx - NH_*D_;
    const int l = k >> 4, j = k & 15;
    const float inv = powf(10000.f, -(float)j * (1.f/16.f));
    const float fr  = (float)l * inv;
    ct[k] = cosf(fr);
    st[k] = sinf(fr);
  }
}

// ---------------- row layernorm fp32 -> bf16 (D=1024) ----------------------
__global__ __launch_bounds__(256) void ln_rows(
    const float* __restrict__ in, const float* __restrict__ g,
    const float* __restrict__ bta, short* __restrict__ out)
{
  const int row = blockIdx.x, tid = threadIdx.x;
  const float4 v = ((const float4*)(in + (size_t)row*D_))[tid];
  float s  = v.x + v.y + v.z + v.w;
  float s2 = v.x*v.x + v.y*v.y + v.z*v.z + v.w*v.w;
  #pragma unroll
  for (int m = 1; m < 64; m <<= 1){ s += __shfl_xor(s, m); s2 += __shfl_xor(s2, m); }
  __shared__ float rs[4], rq[4];
  if ((tid & 63) == 0){ rs[tid>>6] = s; rq[tid>>6] = s2; }
  __syncthreads();
  s  = rs[0] + rs[1] + rs[2] + rs[3];
  s2 = rq[0] + rq[1] + rq[2] + rq[3];
  const float mu   = s  * (1.f/D_);
  const float var  = s2 * (1.f/D_) - mu*mu;
  const float rstd = rsqrtf(var + EPS_);
  const float4 gg = ((const float4*)g)[tid];
  const float4 bb = ((const float4*)bta)[tid];
  s16x4 o;
  o[0] = f2bf((v.x - mu)*rstd*gg.x + bb.x);
  o[1] = f2bf((v.y - mu)*rstd*gg.y + bb.y);
  o[2] = f2bf((v.z - mu)*rstd*gg.z + bb.z);
  o[3] = f2bf((v.w - mu)*rstd*gg.w + bb.w);
  ((s16x4*)(out + (size_t)row*D_))[tid] = o;
}

// ---------------- row layernorm bf16 -> bf16 (D=1024) ----------------------
__global__ __launch_bounds__(256) void ln_rows_bf(
    const short* __restrict__ in, const float* __restrict__ g,
    const float* __restrict__ bta, short* __restrict__ out)
{
  const int row = blockIdx.x, tid = threadIdx.x;
  const s16x4 v4 = ((const s16x4*)(in + (size_t)row*D_))[tid];
  float v[4];
  #pragma unroll
  for (int e = 0; e < 4; ++e) v[e] = bf2f(v4[e]);
  float s  = v[0]+v[1]+v[2]+v[3];
  float s2 = v[0]*v[0]+v[1]*v[1]+v[2]*v[2]+v[3]*v[3];
  #pragma unroll
  for (int m = 1; m < 64; m <<= 1){ s += __shfl_xor(s, m); s2 += __shfl_xor(s2, m); }
  __shared__ float rs[4], rq[4];
  if ((tid & 63) == 0){ rs[tid>>6] = s; rq[tid>>6] = s2; }
  __syncthreads();
  s  = rs[0] + rs[1] + rs[2] + rs[3];
  s2 = rq[0] + rq[1] + rq[2] + rq[3];
  const float mu   = s  * (1.f/D_);
  const float var  = s2 * (1.f/D_) - mu*mu;
  const float rstd = rsqrtf(var + EPS_);
  const float4 gg = ((const float4*)g)[tid];
  const float4 bb = ((const float4*)bta)[tid];
  s16x4 o;
  #pragma unroll
  for (int e = 0; e < 4; ++e){
    const float gv = (e==0)?gg.x:(e==1)?gg.y:(e==2)?gg.z:gg.w;
    const float bv = (e==0)?bb.x:(e==1)?bb.y:(e==2)?bb.z:bb.w;
    o[e] = f2bf((v[e] - mu)*rstd*gv + bv);
  }
  ((s16x4*)(out + (size_t)row*D_))[tid] = o;
}

// ---------------- 256x256 8-wave bf16 GEMM, BK=32, 4-deep pipeline ---------
// 4 K-tile buffers; stage tile t+3 at tile t; boundary vmcnt(8) never blocks.
// LDS swizzle: chunk' = chunk ^ (row&3) (16B granularity within 64B row).
template<int ACT, int OUTBF, int BIAS, int RES, int RESB, int QKVOUT>
__global__ __launch_bounds__(512, 2) void gemm256(
    const short* __restrict__ A, const short* __restrict__ Bt,
    const float* __restrict__ bias, const float* __restrict__ res,
    const short* __restrict__ resb,
    float* __restrict__ Cf, short* __restrict__ Cb,
    const float* __restrict__ ct, const float* __restrict__ st,
    int Mr, int N, int K)
{
  __shared__ __align__(16) short As[4][8192];
  __shared__ __align__(16) short Bs[4][8192];
  const int tid  = threadIdx.x;
  const int lane = tid & 63, wid = tid >> 6;
  const int wr = wid >> 2, wc = wid & 3;
  const int nwg = gridDim.x * gridDim.y;
  const int wg  = blockIdx.y * gridDim.x + blockIdx.x;
  const int swz = (wg & 7) * (nwg >> 3) + (wg >> 3);
  const int bx  = swz % gridDim.x, by = swz / gridDim.x;
  const int row0 = by * 256, col0 = bx * 256;

  f32x4 acc[8][4] = {};

  // staging: thread stages rows (tid>>2) and (tid>>2)+128, chunk tid&3
  // source pre-swizzled: chunk_src = (tid&3) ^ ((tid>>2)&3)
  const int kswz = (((tid & 3) ^ ((tid >> 2) & 3)) << 3);
  const short* gAb = A  + (size_t)(row0 + (tid >> 2)) * K + kswz;
  const short* gBb = Bt + (size_t)(col0 + (tid >> 2)) * K + kswz;
  short* lAb = &As[0][0] + tid*8;
  short* lBb = &Bs[0][0] + tid*8;

  auto stage = [&](int bt2, int t2){
    const size_t kb = (size_t)t2 * 32;
    gl16(gAb + kb,                   lAb + bt2*8192);
    gl16(gAb + kb + 128*(size_t)K,   lAb + bt2*8192 + 4096);
    gl16(gBb + kb,                   lBb + bt2*8192);
    gl16(gBb + kb + 128*(size_t)K,   lBb + bt2*8192 + 4096);
  };

  const int fr = lane & 15;
  const int k0 = (((lane >> 4) ^ (lane & 3)) << 3);   // read-side swizzle

  const int nK = K >> 5;
  // prologue: stage tiles 0,1,2 (12 loads); wait tile0 (<=8 outstanding)
  stage(0, 0); stage(1, 1); stage(2, 2);
  asm volatile("s_waitcnt vmcnt(8)" ::: "memory");
  __builtin_amdgcn_s_barrier();

  for (int kt = 0; kt < nK; ++kt){
    const int bt = kt & 3;
    const short* Ab = &As[0][0] + bt*8192 + wr*4096;
    const short* Bb = &Bs[0][0] + bt*8192 + (wc >> 1)*4096 + (wc & 1)*2048;
    bf16x8 af[4], bfv[4];
    #pragma unroll
    for (int m = 0; m < 4; ++m)
      af[m] = *(const bf16x8*)(Ab + (m*16 + fr)*32 + k0);
    #pragma unroll
    for (int n = 0; n < 4; ++n)
      bfv[n] = *(const bf16x8*)(Bb + (n*16 + fr)*32 + k0);
    if (kt + 3 < nK) stage((kt + 3) & 3, kt + 3);
    __builtin_amdgcn_s_barrier();
    asm volatile("s_waitcnt lgkmcnt(0)" ::: "memory");
    __builtin_amdgcn_sched_barrier(0);
    __builtin_amdgcn_s_setprio(1);
    #pragma unroll
    for (int m = 0; m < 4; ++m)
      #pragma unroll
      for (int n = 0; n < 4; ++n)
        acc[m][n] = __builtin_amdgcn_mfma_f32_16x16x32_bf16(af[m], bfv[n], acc[m][n], 0,0,0);
    __builtin_amdgcn_s_setprio(0);
    __builtin_amdgcn_s_barrier();
    // phase 2: rows 64..127 of the wave's half
    #pragma unroll
    for (int m = 0; m < 4; ++m)
      af[m] = *(const bf16x8*)(Ab + ((m + 4)*16 + fr)*32 + k0);
    __builtin_amdgcn_s_barrier();
    asm volatile("s_waitcnt lgkmcnt(0)" ::: "memory");
    __builtin_amdgcn_sched_barrier(0);
    __builtin_amdgcn_s_setprio(1);
    #pragma unroll
    for (int m = 0; m < 4; ++m)
      #pragma unroll
      for (int n = 0; n < 4; ++n)
        acc[m + 4][n] = __builtin_amdgcn_mfma_f32_16x16x32_bf16(af[m], bfv[n], acc[m + 4][n], 0,0,0);
    __builtin_amdgcn_s_setprio(0);
    if (kt < nK - 1){
      if (kt + 3 < nK)      asm volatile("s_waitcnt vmcnt(8)" ::: "memory");
      else if (kt + 2 < nK) asm volatile("s_waitcnt vmcnt(4)" ::: "memory");
      else                  asm volatile("s_waitcnt vmcnt(0)" ::: "memory");
    }
    __builtin_amdgcn_s_barrier();
  }

  const int cr = (lane >> 4) * 4, cc = lane & 15;
  if (QKVOUT){
    const int part = col0 >> 10;
    #pragma unroll
    for (int m = 0; m < 8; ++m){
      const int gr0 = row0 + wr*128 + m*16 + cr;
      const int bidx = gr0 >> 11, l0 = gr0 & (L_-1);
      const int nn = l0 >> 4;
      if (part < 2){
        #pragma unroll
        for (int np = 0; np < 2; ++np){
          const int gc = col0 + wc*64 + np*32 + cc;
          const int hh = (gc & 1023) >> 5;
          short* tile = Cb + ((size_t)(bidx*NH_ + hh)*NM_ + nn)*2048;
          s16x4 r0v, r1v;
          #pragma unroll
          for (int r = 0; r < 4; ++r){
            const int l = l0 + r;
            const float cv = ct[l*16 + cc], sv = st[l*16 + cc];
            const float x0 = acc[m][np*2][r], x1 = acc[m][np*2+1][r];
            const short q0 = f2bf(x0*cv - x1*sv);
            const short q1 = f2bf(x1*cv + x0*sv);
            tile[part*512 + (cr + r)*32 + cc]      = q0;
            tile[part*512 + (cr + r)*32 + cc + 16] = q1;
            r0v[r] = q0; r1v[r] = q1;
          }
          if (part == 1){
            *(s16x4*)(tile + 1024 + cc*16 + cr)      = r0v;
            *(s16x4*)(tile + 1024 + (cc+16)*16 + cr) = r1v;
          }
        }
      } else {
        #pragma unroll
        for (int n = 0; n < 4; ++n){
          const int gc = col0 + wc*64 + n*16 + cc;
          const int hh = (gc & 1023) >> 5, dd = gc & 31;
          short* tile = Cb + ((size_t)(bidx*NH_ + hh)*NM_ + nn)*2048;
          s16x4 p;
          #pragma unroll
          for (int r = 0; r < 4; ++r) p[r] = f2bf(acc[m][n][r]);
          *(s16x4*)(tile + 1536 + dd*16 + cr) = p;
        }
      }
    }
    return;
  }
  #pragma unroll
  for (int m = 0; m < 8; ++m){
    #pragma unroll
    for (int n = 0; n < 4; ++n){
      const int gc = col0 + wc*64 + n*16 + cc;
      float bv = 0.f;
      if (BIAS) bv = bias[gc];
      #pragma unroll
      for (int r = 0; r < 4; ++r){
        const int gr = row0 + wr*128 + m*16 + cr + r;
        float v = acc[m][n][r] + bv;
        if (RES)  v += res[(size_t)gr*N + gc];
        if (RESB) v += bf2f(resb[(size_t)gr*N + gc]);
        if (ACT == 1) v = fmaxf(v, 0.f);
        if (OUTBF) Cb[(size_t)gr*N + gc] = f2bf(v);
        else       Cf[(size_t)gr*N + gc] = v;
      }
    }
  }
}

// ---------------- eta: sigmoid(x . lr_w[h] + lr_b[h]) / HD -----------------
__global__ __launch_bounds__(256) void eta_kernel(
    const short* __restrict__ xb, const short* __restrict__ lrwb,
    const float* __restrict__ lr_b, float* __restrict__ eta)
{
  __shared__ __align__(16) short wl[NH_*D_];
  __shared__ __align__(16) short xr[D_];
  const int tid = threadIdx.x;
  const int wid = tid >> 6, lane = tid & 63;
  #pragma unroll
  for (int s = 0; s < 16; ++s){
    const int e8 = tid + 256*s;
    ((s16x8*)wl)[e8] = ((const s16x8*)lrwb)[e8];
  }
  for (int tk = 0; tk < 32; ++tk){
    const int token = blockIdx.x*32 + tk;
    __syncthreads();
    if (tid < 128) ((s16x8*)xr)[tid] = ((const s16x8*)(xb + (size_t)token*D_))[tid];
    __syncthreads();
    const s16x8 x0 = ((const s16x8*)xr)[lane*2];
    const s16x8 x1 = ((const s16x8*)xr)[lane*2 + 1];
    #pragma unroll 1
    for (int hh = 0; hh < 8; ++hh){
      const int h = wid*8 + hh;
      const s16x8 w0 = ((const s16x8*)(wl + h*D_))[lane*2];
      const s16x8 w1 = ((const s16x8*)(wl + h*D_))[lane*2 + 1];
      float s = 0.f;
      #pragma unroll
      for (int e = 0; e < 8; ++e)
        s += bf2f(x0[e])*bf2f(w0[e]) + bf2f(x1[e])*bf2f(w1[e]);
      #pragma unroll
      for (int m = 1; m < 64; m <<= 1) s += __shfl_xor(s, m);
      if (lane == 0){
        const float v = 1.f/(1.f + __expf(-(s + lr_b[h]))) * (1.f/32.f);
        const int bidx = token >> 11, l = token & (L_-1), n = l >> 4, im = l & 15;
        eta[(((size_t)bidx*NH_ + h)*NM_ + n)*M_ + im] = v;
      }
    }
  }
}

// ---------------- TTT scan v7b: 2 waves, 1 barrier/step --------------------
__global__ __launch_bounds__(128) void scan_kernel(
    const short* __restrict__ Q5, const float* __restrict__ eta,
    const float* __restrict__ W1, const float* __restrict__ b1,
    const float* __restrict__ tdelta, const float* __restrict__ lng,
    const float* __restrict__ lnb, short* __restrict__ out)
{
  const int bh = blockIdx.x;
  const int h = bh & 31, b = bh >> 5;
  const int lane = threadIdx.x & 63;
  const int wv = threadIdx.x >> 6;
  const int li = lane & 15, lh = lane >> 4;

  __shared__ __align__(16) short WTl[2][32*40];
  __shared__ __align__(16) short GTl[2][32*24];
  __shared__ float BBl[2][2][16];
  __shared__ __align__(16) float AT[16*20];
  __shared__ __align__(16) short QLl[2][16*40];

  const short* chain = Q5 + (size_t)bh * (NM_*2048);
  const float* ech   = eta + (size_t)bh * (NM_*16);

  float lw[2], lbv[2];
  #pragma unroll
  for (int hh = 0; hh < 2; ++hh){
    lw[hh]  = lng[h*32 + 16*hh + li];
    lbv[hh] = lnb[h*32 + 16*hh + li];
  }

  if (wv == 0){
    f32x4 Wq[2][2];
    #pragma unroll
    for (int rb = 0; rb < 2; ++rb)
      #pragma unroll
      for (int cb = 0; cb < 2; ++cb)
        #pragma unroll
        for (int r = 0; r < 4; ++r)
          Wq[rb][cb][r] = W1[h*1024 + (16*rb + 4*lh + r)*32 + 16*cb + li];
    float bb[2];
    bb[0] = b1[h*32 + li];  bb[1] = b1[h*32 + 16 + li];
    const float lef = fmaxf(1.f/16.f + tdelta[15], 0.f);

    auto writeWT = [&](int sl){
      #pragma unroll
      for (int cb = 0; cb < 2; ++cb)
        #pragma unroll
        for (int rb = 0; rb < 2; ++rb){
          const unsigned p0 = cvtpk(Wq[rb][cb][0], Wq[rb][cb][1]);
          const unsigned p1 = cvtpk(Wq[rb][cb][2], Wq[rb][cb][3]);
          *(uint64_t*)(&WTl[sl][0] + (16*cb + li)*40 + 16*rb + 4*lh) =
              ((uint64_t)p1 << 32) | p0;
        }
    };
    auto readWf = [&](int sl, bf16x8* Wf){
      Wf[0] = *(const bf16x8*)(&WTl[sl][0] + li*40 + 8*lh);
      Wf[1] = *(const bf16x8*)(&WTl[sl][0] + (16 + li)*40 + 8*lh);
    };

    writeWT(0);
    if (lh == 0){ BBl[0][0][li] = bb[0]; BBl[0][1][li] = bb[1]; }
    bf16x8 Wf[2];
    readWf(0, Wf);

    struct P0 { s16x8 kA, kTq0, kTq1; s16x4 kTe0, kTe1, vTe0, vTe1;
                f32x4 lr0, lr1, lr2, lr3; };
    auto ld0 = [&](int n) -> P0 {
      const short* t = chain + (size_t)n*2048;
      const float* e = ech + n*16;
      P0 p;
      p.kA   = *(const s16x8*)(t + 512 + li*32 + 8*lh);
      p.kTq0 = *(const s16x8*)(t + 1024 + li*16 + 8*(lh & 1));
      p.kTq1 = *(const s16x8*)(t + 1024 + (16 + li)*16 + 8*(lh & 1));
      p.kTe0 = *(const s16x4*)(t + 1024 + li*16 + 4*lh);
      p.kTe1 = *(const s16x4*)(t + 1024 + (16 + li)*16 + 4*lh);
      p.vTe0 = *(const s16x4*)(t + 1536 + li*16 + 4*lh);
      p.vTe1 = *(const s16x4*)(t + 1536 + (16 + li)*16 + 4*lh);
      p.lr0 = *(const f32x4*)(e);     p.lr1 = *(const f32x4*)(e + 4);
      p.lr2 = *(const f32x4*)(e + 8); p.lr3 = *(const f32x4*)(e + 12);
      return p;
    };

    P0 cur = ld0(0);
    wgbar();

    const int gcol = (8*lh) & 15;
    #pragma unroll 1
    for (int n = 0; n < NM_; ++n){
      const int sl = n & 1;
      P0 nxt = ld0(n + 1 < NM_ ? n + 1 : NM_ - 1);
      const bf16x8 kAf = __builtin_bit_cast(bf16x8, cur.kA);

      f32x4 zac[2];
      #pragma unroll
      for (int hh = 0; hh < 2; ++hh){
        f32x4 c0; c0[0]=bb[hh]; c0[1]=bb[hh]; c0[2]=bb[hh]; c0[3]=bb[hh];
        zac[hh] = __builtin_amdgcn_mfma_f32_16x16x32_bf16(kAf, Wf[hh], c0, 0,0,0);
      }

      float xh[2][4], grad[2][4], rstdv[4];
      #pragma unroll
      for (int r = 0; r < 4; ++r){
        float s  = rsum16d(zac[0][r] + zac[1][r]);
        float q2 = rsum16d(zac[0][r]*zac[0][r] + zac[1][r]*zac[1][r]);
        const float mu  = s * (1.f/32.f);
        const float var = q2 * (1.f/32.f) - mu*mu;
        const float rstd = rsqrtf(var + EPS_);
        rstdv[r] = rstd;
        xh[0][r] = (zac[0][r] - mu) * rstd;
        xh[1][r] = (zac[1][r] - mu) * rstd;
      }
      #pragma unroll
      for (int r = 0; r < 4; ++r){
        const float t0 = bf2f(cur.vTe0[r]) - bf2f(cur.kTe0[r]);
        const float t1 = bf2f(cur.vTe1[r]) - bf2f(cur.kTe1[r]);
        const float g0 = (xh[0][r]*lw[0] + lbv[0] - t0)*lw[0];
        const float g1 = (xh[1][r]*lw[1] + lbv[1] - t1)*lw[1];
        const float sg  = rsum16d(g0 + g1);
        const float sgx = rsum16d(g0*xh[0][r] + g1*xh[1][r]);
        const float f = rstdv[r] * (1.f/32.f);
        grad[0][r] = (32.f*g0 - sg - xh[0][r]*sgx) * f;
        grad[1][r] = (32.f*g1 - sg - xh[1][r]*sgx) * f;
      }

      #pragma unroll
      for (int hh = 0; hh < 2; ++hh){
        const unsigned p0 = cvtpk(grad[hh][0], grad[hh][1]);
        const unsigned p1 = cvtpk(grad[hh][2], grad[hh][3]);
        *(uint64_t*)(&GTl[sl][0] + (16*hh + li)*24 + 4*lh) =
            ((uint64_t)p1 << 32) | p0;
      }
      bf16x8 gf[2];
      gf[0] = *(const bf16x8*)(&GTl[sl][0] + li*24 + gcol);
      gf[1] = *(const bf16x8*)(&GTl[sl][0] + (16 + li)*24 + gcol);

      const f32x4 plA = (lh & 1) ? cur.lr2 : cur.lr0;
      const f32x4 plB = (lh & 1) ? cur.lr3 : cur.lr1;
      #pragma unroll
      for (int rb = 0; rb < 2; ++rb){
        const s16x8 kq = rb ? cur.kTq1 : cur.kTq0;
        float av8[8];
        #pragma unroll
        for (int jj = 0; jj < 8; ++jj){
          const float lrv = (jj < 4) ? plA[jj] : plB[jj - 4];
          av8[jj] = (lh < 2) ? -lef * lrv * bf2f(kq[jj]) : 0.f;
        }
        u32x4 auv;
        auv[0] = cvtpk(av8[0], av8[1]); auv[1] = cvtpk(av8[2], av8[3]);
        auv[2] = cvtpk(av8[4], av8[5]); auv[3] = cvtpk(av8[6], av8[7]);
        const bf16x8 af = __builtin_bit_cast(bf16x8, auv);
        #pragma unroll
        for (int cb = 0; cb < 2; ++cb)
          Wq[rb][cb] = __builtin_amdgcn_mfma_f32_16x16x32_bf16(af, gf[cb], Wq[rb][cb], 0,0,0);
      }

      // publish W(n+1) immediately (shortens W -> next-z chain)
      writeWT(sl ^ 1);

      f32x4 lrq;
      { const f32x4 t0 = (lh & 1) ? cur.lr1 : cur.lr0;
        const f32x4 t1 = (lh & 1) ? cur.lr3 : cur.lr2;
        lrq = (lh & 2) ? t1 : t0; }
      #pragma unroll
      for (int hh = 0; hh < 2; ++hh){
        float t = 0.f;
        #pragma unroll
        for (int r = 0; r < 4; ++r) t += lrq[r]*grad[hh][r];
        t += __shfl_xor(t, 16); t += __shfl_xor(t, 32);
        bb[hh] -= lef * t;
      }
      if (lh == 0){ BBl[sl ^ 1][0][li] = bb[0]; BBl[sl ^ 1][1][li] = bb[1]; }
      readWf(sl ^ 1, Wf);
      cur = nxt;
      wgbar();
    }
  } else {
    const float tok_i = fmaxf(1.f/(float)(li+1) + tdelta[li], 0.f);
    short* outp = out + (size_t)b*L_*D_ + h*32;
    const int gcol = (8*lh) & 15;

    struct P1 { s16x8 qA, kA; f32x4 lr0, lr1, lr2, lr3; };
    auto ld1 = [&](int n) -> P1 {
      const short* t = chain + (size_t)n*2048;
      const float* e = ech + n*16;
      P1 p;
      p.qA = *(const s16x8*)(t + li*32 + 8*lh);
      p.kA = *(const s16x8*)(t + 512 + li*32 + 8*lh);
      p.lr0 = *(const f32x4*)(e);     p.lr1 = *(const f32x4*)(e + 4);
      p.lr2 = *(const f32x4*)(e + 8); p.lr3 = *(const f32x4*)(e + 12);
      return p;
    };

    auto outln = [&](int n, const f32x4* yac){
      #pragma unroll
      for (int r = 0; r < 4; ++r){
        const float s  = rsum16d(yac[0][r] + yac[1][r]);
        const float q2 = rsum16d(yac[0][r]*yac[0][r] + yac[1][r]*yac[1][r]);
        const float mu   = s * (1.f/32.f);
        const float var  = q2 * (1.f/32.f) - mu*mu;
        const float rstd = rsqrtf(var + EPS_);
        const int row = 4*lh + r;
        #pragma unroll
        for (int hh = 0; hh < 2; ++hh){
          const float qv = bf2f(QLl[n & 1][row*40 + 16*hh + li]);
          const float o  = qv + (yac[hh][r] - mu)*rstd*lw[hh] + lbv[hh];
          outp[(size_t)(n*16 + row)*D_ + 16*hh + li] = f2bf(o);
        }
      }
    };

    P1 cur = ld1(0);
    wgbar();

    f32x4 yprev[2] = {};
    bf16x8 pPrev = {};
    #pragma unroll 1
    for (int n = 0; n < NM_; ++n){
      const int sl = n & 1;
      bf16x8 Wf0 = *(const bf16x8*)(&WTl[sl][0] + li*40 + 8*lh);
      bf16x8 Wf1 = *(const bf16x8*)(&WTl[sl][0] + (16 + li)*40 + 8*lh);
      const float bb0 = BBl[sl][0][li];
      const float bb1 = BBl[sl][1][li];

      if (n > 0){
        bf16x8 gf0 = *(const bf16x8*)(&GTl[sl ^ 1][0] + li*24 + gcol);
        bf16x8 gf1 = *(const bf16x8*)(&GTl[sl ^ 1][0] + (16 + li)*24 + gcol);
        yprev[0] = __builtin_amdgcn_mfma_f32_16x16x32_bf16(pPrev, gf0, yprev[0], 0,0,0);
        yprev[1] = __builtin_amdgcn_mfma_f32_16x16x32_bf16(pPrev, gf1, yprev[1], 0,0,0);
        outln(n - 1, yprev);
      }

      P1 nxt = ld1(n + 1 < NM_ ? n + 1 : NM_ - 1);
      const bf16x8 qAf = __builtin_bit_cast(bf16x8, cur.qA);
      const bf16x8 kAf = __builtin_bit_cast(bf16x8, cur.kA);

      *(s16x8*)(&QLl[sl][0] + li*40 + 8*lh) = cur.qA;

      f32x4 aac = {};
      aac = __builtin_amdgcn_mfma_f32_16x16x32_bf16(qAf, kAf, aac, 0,0,0);
      #pragma unroll
      for (int r = 0; r < 4; ++r)
        AT[(4*lh + r)*20 + li] = aac[r];

      f32x4 arA = {}, arB = {};
      if (lh < 2){
        arA = *(const f32x4*)(AT + li*20 + 8*lh);
        arB = *(const f32x4*)(AT + li*20 + 8*lh + 4);
      }
      const f32x4 plA = (lh & 1) ? cur.lr2 : cur.lr0;
      const f32x4 plB = (lh & 1) ? cur.lr3 : cur.lr1;
      float pv[8];
      #pragma unroll
      for (int jj = 0; jj < 8; ++jj){
        const float av  = (jj < 4) ? arA[jj] : arB[jj - 4];
        const float lrv = (jj < 4) ? plA[jj] : plB[jj - 4];
        const bool ok = (lh < 2) && (8*lh + jj <= li);
        pv[jj] = ok ? -tok_i * lrv * (1.f + av) : 0.f;
      }
      u32x4 ppv;
      ppv[0] = cvtpk(pv[0], pv[1]); ppv[1] = cvtpk(pv[2], pv[3]);
      ppv[2] = cvtpk(pv[4], pv[5]); ppv[3] = cvtpk(pv[6], pv[7]);
      pPrev = __builtin_bit_cast(bf16x8, ppv);

      { f32x4 c0; c0[0]=bb0; c0[1]=bb0; c0[2]=bb0; c0[3]=bb0;
        yprev[0] = __builtin_amdgcn_mfma_f32_16x16x32_bf16(qAf, Wf0, c0, 0,0,0); }
      { f32x4 c0; c0[0]=bb1; c0[1]=bb1; c0[2]=bb1; c0[3]=bb1;
        yprev[1] = __builtin_amdgcn_mfma_f32_16x16x32_bf16(qAf, Wf1, c0, 0,0,0); }

      cur = nxt;
      wgbar();
    }
    {
      const int sl = (NM_ - 1) & 1;
      bf16x8 gf0 = *(const bf16x8*)(&GTl[sl][0] + li*24 + gcol);
      bf16x8 gf1 = *(const bf16x8*)(&GTl[sl][0] + (16 + li)*24 + gcol);
      yprev[0] = __builtin_amdgcn_mfma_f32_16x16x32_bf16(pPrev, gf0, yprev[0], 0,0,0);
      yprev[1] = __builtin_amdgcn_mfma_f32_16x16x32_bf16(pPrev, gf1, yprev[1], 0,0,0);
      outln(NM_ - 1, yprev);
    }
  }
}

// ---------------------------------------------------------------------------
extern "C" void kernel_launch(void* const* d_in, const int* in_sizes, int n_in,
                              void* d_out, int out_size, void* d_ws, size_t ws_size,
                              hipStream_t stream)
{
  const float* enc    = (const float*)d_in[0];
  const float* ln0_g  = (const float*)d_in[1];
  const float* ln0_b  = (const float*)d_in[2];
  const float* Wq     = (const float*)d_in[3];
  const float* Wk     = (const float*)d_in[4];
  const float* Wv     = (const float*)d_in[5];
  const float* Wo     = (const float*)d_in[6];
  const float* W1     = (const float*)d_in[7];
  const float* b1     = (const float*)d_in[8];
  const float* tdelta = (const float*)d_in[9];
  const float* lr_w   = (const float*)d_in[10];
  const float* lr_b   = (const float*)d_in[11];
  const float* ttt_g  = (const float*)d_in[12];
  const float* ttt_b  = (const float*)d_in[13];
  const float* post_g = (const float*)d_in[14];
  const float* post_b = (const float*)d_in[15];
  const float* ffn_g  = (const float*)d_in[16];
  const float* ffn_b  = (const float*)d_in[17];
  const float* fw1    = (const float*)d_in[18];
  const float* fb1    = (const float*)d_in[19];
  const float* fw2    = (const float*)d_in[20];
  const float* fb2    = (const float*)d_in[21];

  char* ws = (char*)d_ws;
  short* Q5    = (short*)(ws + 0);            // 134,217,728 B (scan tiles)
  short* XB    = (short*)(ws + 134217728);    //  33,554,432 B
  short* SCANB = (short*)(ws + 134217728);    //  alias XB
  short* WQKVT = (short*)(ws + 167772160);    //   6,291,456 B
  short* WOT   = (short*)(ws + 174063616);    //   2,097,152 B
  short* FW1T  = (short*)(ws + 176160768);    //   4,194,304 B
  short* FW2T  = (short*)(ws + 180355072);    //   4,194,304 B
  short* LRWB  = (short*)(ws + 184549376);    //      65,536 B
  float* CT    = (float*)(ws + 184614912);    //     131,072 B
  float* ST    = (float*)(ws + 184745984);    //     131,072 B
  float* ETA   = (float*)(ws + 184877056);    //   2,097,152 B
  short* YB    = (short*)(ws + 0);            // alias Q5 (post-scan)
  short* HB    = (short*)(ws + 33554432);     // alias Q5
  short* T1    = (short*)(ws + 67108864);     // alias Q5 (64 MB, ends 134M)
  short* R2B   = (short*)(ws + 134217728);    // alias SCANB (dead post-LN)
  float* R2    = (float*)d_out;

  dim3 b256(256), b512(512);
  TC4 tc;
  tc.s0 = Wq; tc.s1 = Wk; tc.s2 = Wv; tc.s3 = Wo;
  tc.d0 = WQKVT; tc.d1 = WQKVT + 1048576; tc.d2 = WQKVT + 2097152; tc.d3 = WOT;
  transpose_cast4<<<dim3(32,32,4), b256, 0, stream>>>(tc);
  transpose_cast<<<dim3(64,32), b256, 0, stream>>>(fw1, FW1T, D_, DI_);
  transpose_cast<<<dim3(32,64), b256, 0, stream>>>(fw2, FW2T, DI_, D_);
  misc_prep<<<dim3(256), b256, 0, stream>>>(lr_w, LRWB, CT, ST);

  ln_rows<<<BL_, b256, 0, stream>>>(enc, ln0_g, ln0_b, XB);
  gemm256<0,0,0,0,0,1><<<dim3(12,64), b512, 0, stream>>>(XB, WQKVT, nullptr, nullptr, nullptr,
                                                         nullptr, Q5, CT, ST, BL_, 3072, D_);
  eta_kernel<<<dim3(512), b256, 0, stream>>>(XB, LRWB, lr_b, ETA);
  scan_kernel<<<dim3(256), dim3(128), 0, stream>>>(Q5, ETA, W1, b1, tdelta,
                                                   ttt_g, ttt_b, SCANB);
  ln_rows_bf<<<BL_, b256, 0, stream>>>(SCANB, post_g, post_b, YB);
  // Wo + residual(enc) -> R2B (bf16)
  gemm256<0,1,0,1,0,0><<<dim3(4,64), b512, 0, stream>>>(YB, WOT, nullptr, enc, nullptr,
                                                        nullptr, R2B, nullptr, nullptr, BL_, D_, D_);
  ln_rows_bf<<<BL_, b256, 0, stream>>>(R2B, ffn_g, ffn_b, HB);
  gemm256<1,1,1,0,0,0><<<dim3(8,64), b512, 0, stream>>>(HB, FW1T, fb1, nullptr, nullptr,
                                                        nullptr, T1, nullptr, nullptr, BL_, DI_, D_);
  // FFN2 + residual(R2B) -> d_out (f32)
  gemm256<0,0,1,0,1,0><<<dim3(4,64), b512, 0, stream>>>(T1, FW2T, fb2, nullptr, R2B,
                                                        R2, nullptr, nullptr, nullptr, BL_, D_, DI_);
}

// Round 11
// 556.331 us; speedup vs baseline: 1.8974x; 1.2215x over previous
//
#include <hip/hip_runtime.h>
#include <hip/hip_bf16.h>
#include <stdint.h>

#define B_   8
#define L_   2048
#define D_   1024
#define NH_  32
#define M_   16
#define NM_  128
#define HD_  32
#define DI_  2048
#define BL_  16384
#define EPS_ 1e-6f

typedef __attribute__((ext_vector_type(8))) short  s16x8;
typedef __attribute__((ext_vector_type(4))) short  s16x4;
typedef __attribute__((ext_vector_type(8))) __bf16 bf16x8;
typedef __attribute__((ext_vector_type(4))) float  f32x4;
typedef __attribute__((ext_vector_type(4))) unsigned u32x4;

__device__ __forceinline__ float bf2f(short s){
  unsigned u = ((unsigned)(unsigned short)s) << 16;
  return __builtin_bit_cast(float, u);
}
__device__ __forceinline__ short f2bf(float f){
  unsigned u = __builtin_bit_cast(unsigned, f);
  u = u + 0x7FFFu + ((u >> 16) & 1u);   // RNE
  return (short)(u >> 16);
}
__device__ __forceinline__ unsigned cvtpk(float lo, float hi){
  unsigned r;
  asm("v_cvt_pk_bf16_f32 %0, %1, %2" : "=v"(r) : "v"(lo), "v"(hi));
  return r;
}
template<int N>
__device__ __forceinline__ float ror_add(float v){
  const int y = __builtin_amdgcn_update_dpp(
      0, __builtin_bit_cast(int, v), 0x120 + N, 0xF, 0xF, true);
  return v + __builtin_bit_cast(float, y);
}
__device__ __forceinline__ float rsum16d(float v){
  v = ror_add<1>(v); v = ror_add<2>(v); v = ror_add<4>(v); v = ror_add<8>(v);
  return v;
}
__device__ __forceinline__ void wgbar(){
  asm volatile("s_waitcnt lgkmcnt(0)" ::: "memory");
  __builtin_amdgcn_s_barrier();
  __builtin_amdgcn_sched_barrier(0);
}
__device__ __forceinline__ void gl16(const void* g, void* l){
  __builtin_amdgcn_global_load_lds(
      (const __attribute__((address_space(1))) void*)g,
      (__attribute__((address_space(3))) void*)l, 16, 0, 0);
}

// ---------------- transpose + fp32->bf16 cast: out(Cc,R) = in(R,Cc)^T ------
__global__ __launch_bounds__(256) void transpose_cast(
    const float* __restrict__ in, short* __restrict__ out, int R, int Cc)
{
  __shared__ float t[32][33];
  const int lx = threadIdx.x & 31, ly = threadIdx.x >> 5;
  const int r0 = blockIdx.y * 32, c0 = blockIdx.x * 32;
  #pragma unroll
  for (int s = 0; s < 4; ++s){
    const int r = ly + s*8;
    t[r][lx] = in[(size_t)(r0 + r)*Cc + c0 + lx];
  }
  __syncthreads();
  #pragma unroll
  for (int s = 0; s < 4; ++s){
    const int r = ly + s*8;
    out[(size_t)(c0 + r)*R + r0 + lx] = f2bf(t[lx][r]);
  }
}

struct TC4 { const float *s0,*s1,*s2,*s3; short *d0,*d1,*d2,*d3; };
__global__ __launch_bounds__(256) void transpose_cast4(TC4 p)
{
  __shared__ float t[32][33];
  const int z = blockIdx.z;
  const float* in = (z==0)?p.s0:(z==1)?p.s1:(z==2)?p.s2:p.s3;
  short* out      = (z==0)?p.d0:(z==1)?p.d1:(z==2)?p.d2:p.d3;
  const int lx = threadIdx.x & 31, ly = threadIdx.x >> 5;
  const int r0 = blockIdx.y * 32, c0 = blockIdx.x * 32;
  #pragma unroll
  for (int s = 0; s < 4; ++s){
    const int r = ly + s*8;
    t[r][lx] = in[(size_t)(r0 + r)*1024 + c0 + lx];
  }
  __syncthreads();
  #pragma unroll
  for (int s = 0; s < 4; ++s){
    const int r = ly + s*8;
    out[(size_t)(c0 + r)*1024 + r0 + lx] = f2bf(t[lx][r]);
  }
}

// ---------------- misc prep: lr_w cast + rope tables -----------------------
__global__ __launch_bounds__(256) void misc_prep(
    const float* __restrict__ lr_w, short* __restrict__ lrwb,
    float* __restrict__ ct, float* __restrict__ st)
{
  const int idx = blockIdx.x*256 + threadIdx.x;
  if (idx < NH_*D_){
    lrwb[idx] = f2bf(lr_w[idx]);
  } else {
    const int k = idx - NH_*D_;
    const int l = k >> 4, j = k & 15;
    const float inv = powf(10000.f, -(float)j * (1.f/16.f));
    const float fr  = (float)l * inv;
    ct[k] = cosf(fr);
    st[k] = sinf(fr);
  }
}

// ---------------- row layernorm fp32 -> bf16 (D=1024) ----------------------
__global__ __launch_bounds__(256) void ln_rows(
    const float* __restrict__ in, const float* __restrict__ g,
    const float* __restrict__ bta, short* __restrict__ out)
{
  const int row = blockIdx.x, tid = threadIdx.x;
  const float4 v = ((const float4*)(in + (size_t)row*D_))[tid];
  float s  = v.x + v.y + v.z + v.w;
  float s2 = v.x*v.x + v.y*v.y + v.z*v.z + v.w*v.w;
  #pragma unroll
  for (int m = 1; m < 64; m <<= 1){ s += __shfl_xor(s, m); s2 += __shfl_xor(s2, m); }
  __shared__ float rs[4], rq[4];
  if ((tid & 63) == 0){ rs[tid>>6] = s; rq[tid>>6] = s2; }
  __syncthreads();
  s  = rs[0] + rs[1] + rs[2] + rs[3];
  s2 = rq[0] + rq[1] + rq[2] + rq[3];
  const float mu   = s  * (1.f/D_);
  const float var  = s2 * (1.f/D_) - mu*mu;
  const float rstd = rsqrtf(var + EPS_);
  const float4 gg = ((const float4*)g)[tid];
  const float4 bb = ((const float4*)bta)[tid];
  s16x4 o;
  o[0] = f2bf((v.x - mu)*rstd*gg.x + bb.x);
  o[1] = f2bf((v.y - mu)*rstd*gg.y + bb.y);
  o[2] = f2bf((v.z - mu)*rstd*gg.z + bb.z);
  o[3] = f2bf((v.w - mu)*rstd*gg.w + bb.w);
  ((s16x4*)(out + (size_t)row*D_))[tid] = o;
}

// ---------------- row layernorm bf16 -> bf16 (D=1024) ----------------------
__global__ __launch_bounds__(256) void ln_rows_bf(
    const short* __restrict__ in, const float* __restrict__ g,
    const float* __restrict__ bta, short* __restrict__ out)
{
  const int row = blockIdx.x, tid = threadIdx.x;
  const s16x4 v4 = ((const s16x4*)(in + (size_t)row*D_))[tid];
  float v[4];
  #pragma unroll
  for (int e = 0; e < 4; ++e) v[e] = bf2f(v4[e]);
  float s  = v[0]+v[1]+v[2]+v[3];
  float s2 = v[0]*v[0]+v[1]*v[1]+v[2]*v[2]+v[3]*v[3];
  #pragma unroll
  for (int m = 1; m < 64; m <<= 1){ s += __shfl_xor(s, m); s2 += __shfl_xor(s2, m); }
  __shared__ float rs[4], rq[4];
  if ((tid & 63) == 0){ rs[tid>>6] = s; rq[tid>>6] = s2; }
  __syncthreads();
  s  = rs[0] + rs[1] + rs[2] + rs[3];
  s2 = rq[0] + rq[1] + rq[2] + rq[3];
  const float mu   = s  * (1.f/D_);
  const float var  = s2 * (1.f/D_) - mu*mu;
  const float rstd = rsqrtf(var + EPS_);
  const float4 gg = ((const float4*)g)[tid];
  const float4 bb = ((const float4*)bta)[tid];
  s16x4 o;
  #pragma unroll
  for (int e = 0; e < 4; ++e){
    const float gv = (e==0)?gg.x:(e==1)?gg.y:(e==2)?gg.z:gg.w;
    const float bv = (e==0)?bb.x:(e==1)?bb.y:(e==2)?bb.z:bb.w;
    o[e] = f2bf((v[e] - mu)*rstd*gv + bv);
  }
  ((s16x4*)(out + (size_t)row*D_))[tid] = o;
}

// ---------------- 256x256 8-wave bf16 GEMM, BK=32, 4-deep pipeline ---------
// LDS swizzle v2: chunk' = chunk ^ ((row>>1)&3) — conflict-free per quad.
template<int ACT, int OUTBF, int BIAS, int RES, int RESB, int QKVOUT>
__global__ __launch_bounds__(512, 2) void gemm256(
    const short* __restrict__ A, const short* __restrict__ Bt,
    const float* __restrict__ bias, const float* __restrict__ res,
    const short* __restrict__ resb,
    float* __restrict__ Cf, short* __restrict__ Cb,
    const float* __restrict__ ct, const float* __restrict__ st,
    int Mr, int N, int K)
{
  __shared__ __align__(16) short As[4][8192];
  __shared__ __align__(16) short Bs[4][8192];
  const int tid  = threadIdx.x;
  const int lane = tid & 63, wid = tid >> 6;
  const int wr = wid >> 2, wc = wid & 3;
  const int nwg = gridDim.x * gridDim.y;
  const int wg  = blockIdx.y * gridDim.x + blockIdx.x;
  const int swz = (wg & 7) * (nwg >> 3) + (wg >> 3);
  const int bx  = swz % gridDim.x, by = swz / gridDim.x;
  const int row0 = by * 256, col0 = bx * 256;

  f32x4 acc[8][4] = {};

  // staging: thread stages rows (tid>>2) and (tid>>2)+128, chunk tid&3
  // source pre-swizzled: chunk_src = (tid&3) ^ ((row>>1)&3), row = tid>>2
  const int kswz = (((tid & 3) ^ ((tid >> 3) & 3)) << 3);
  const short* gAb = A  + (size_t)(row0 + (tid >> 2)) * K + kswz;
  const short* gBb = Bt + (size_t)(col0 + (tid >> 2)) * K + kswz;
  short* lAb = &As[0][0] + tid*8;
  short* lBb = &Bs[0][0] + tid*8;

  auto stage = [&](int bt2, int t2){
    const size_t kb = (size_t)t2 * 32;
    gl16(gAb + kb,                   lAb + bt2*8192);
    gl16(gAb + kb + 128*(size_t)K,   lAb + bt2*8192 + 4096);
    gl16(gBb + kb,                   lBb + bt2*8192);
    gl16(gBb + kb + 128*(size_t)K,   lBb + bt2*8192 + 4096);
  };

  const int fr = lane & 15;
  const int k0 = (((lane >> 4) ^ ((lane >> 1) & 3)) << 3);   // read-side swizzle v2

  const int nK = K >> 5;
  stage(0, 0); stage(1, 1); stage(2, 2);
  asm volatile("s_waitcnt vmcnt(8)" ::: "memory");
  __builtin_amdgcn_s_barrier();

  for (int kt = 0; kt < nK; ++kt){
    const int bt = kt & 3;
    const short* Ab = &As[0][0] + bt*8192 + wr*4096;
    const short* Bb = &Bs[0][0] + bt*8192 + (wc >> 1)*4096 + (wc & 1)*2048;
    bf16x8 af[4], bfv[4];
    #pragma unroll
    for (int m = 0; m < 4; ++m)
      af[m] = *(const bf16x8*)(Ab + (m*16 + fr)*32 + k0);
    #pragma unroll
    for (int n = 0; n < 4; ++n)
      bfv[n] = *(const bf16x8*)(Bb + (n*16 + fr)*32 + k0);
    if (kt + 3 < nK) stage((kt + 3) & 3, kt + 3);
    __builtin_amdgcn_s_barrier();
    asm volatile("s_waitcnt lgkmcnt(0)" ::: "memory");
    __builtin_amdgcn_sched_barrier(0);
    __builtin_amdgcn_s_setprio(1);
    #pragma unroll
    for (int m = 0; m < 4; ++m)
      #pragma unroll
      for (int n = 0; n < 4; ++n)
        acc[m][n] = __builtin_amdgcn_mfma_f32_16x16x32_bf16(af[m], bfv[n], acc[m][n], 0,0,0);
    __builtin_amdgcn_s_setprio(0);
    __builtin_amdgcn_s_barrier();
    // phase 2: rows 64..127 of the wave's half
    #pragma unroll
    for (int m = 0; m < 4; ++m)
      af[m] = *(const bf16x8*)(Ab + ((m + 4)*16 + fr)*32 + k0);
    __builtin_amdgcn_s_barrier();
    asm volatile("s_waitcnt lgkmcnt(0)" ::: "memory");
    __builtin_amdgcn_sched_barrier(0);
    __builtin_amdgcn_s_setprio(1);
    #pragma unroll
    for (int m = 0; m < 4; ++m)
      #pragma unroll
      for (int n = 0; n < 4; ++n)
        acc[m + 4][n] = __builtin_amdgcn_mfma_f32_16x16x32_bf16(af[m], bfv[n], acc[m + 4][n], 0,0,0);
    __builtin_amdgcn_s_setprio(0);
    if (kt < nK - 1){
      if (kt + 3 < nK)      asm volatile("s_waitcnt vmcnt(8)" ::: "memory");
      else if (kt + 2 < nK) asm volatile("s_waitcnt vmcnt(4)" ::: "memory");
      else                  asm volatile("s_waitcnt vmcnt(0)" ::: "memory");
    }
    __builtin_amdgcn_s_barrier();
  }

  const int cr = (lane >> 4) * 4, cc = lane & 15;
  if (QKVOUT){
    const int part = col0 >> 10;
    #pragma unroll
    for (int m = 0; m < 8; ++m){
      const int gr0 = row0 + wr*128 + m*16 + cr;
      const int bidx = gr0 >> 11, l0 = gr0 & (L_-1);
      const int nn = l0 >> 4;
      if (part < 2){
        #pragma unroll
        for (int np = 0; np < 2; ++np){
          const int gc = col0 + wc*64 + np*32 + cc;
          const int hh = (gc & 1023) >> 5;
          short* tile = Cb + ((size_t)(bidx*NH_ + hh)*NM_ + nn)*2048;
          s16x4 r0v, r1v;
          #pragma unroll
          for (int r = 0; r < 4; ++r){
            const int l = l0 + r;
            const float cv = ct[l*16 + cc], sv = st[l*16 + cc];
            const float x0 = acc[m][np*2][r], x1 = acc[m][np*2+1][r];
            const short q0 = f2bf(x0*cv - x1*sv);
            const short q1 = f2bf(x1*cv + x0*sv);
            tile[part*512 + (cr + r)*32 + cc]      = q0;
            tile[part*512 + (cr + r)*32 + cc + 16] = q1;
            r0v[r] = q0; r1v[r] = q1;
          }
          if (part == 1){
            *(s16x4*)(tile + 1024 + cc*16 + cr)      = r0v;
            *(s16x4*)(tile + 1024 + (cc+16)*16 + cr) = r1v;
          }
        }
      } else {
        #pragma unroll
        for (int n = 0; n < 4; ++n){
          const int gc = col0 + wc*64 + n*16 + cc;
          const int hh = (gc & 1023) >> 5, dd = gc & 31;
          short* tile = Cb + ((size_t)(bidx*NH_ + hh)*NM_ + nn)*2048;
          s16x4 p;
          #pragma unroll
          for (int r = 0; r < 4; ++r) p[r] = f2bf(acc[m][n][r]);
          *(s16x4*)(tile + 1536 + dd*16 + cr) = p;
        }
      }
    }
    return;
  }
  #pragma unroll
  for (int m = 0; m < 8; ++m){
    #pragma unroll
    for (int n = 0; n < 4; ++n){
      const int gc = col0 + wc*64 + n*16 + cc;
      float bv = 0.f;
      if (BIAS) bv = bias[gc];
      #pragma unroll
      for (int r = 0; r < 4; ++r){
        const int gr = row0 + wr*128 + m*16 + cr + r;
        float v = acc[m][n][r] + bv;
        if (RES)  v += res[(size_t)gr*N + gc];
        if (RESB) v += bf2f(resb[(size_t)gr*N + gc]);
        if (ACT == 1) v = fmaxf(v, 0.f);
        if (OUTBF) Cb[(size_t)gr*N + gc] = f2bf(v);
        else       Cf[(size_t)gr*N + gc] = v;
      }
    }
  }
}

// ---------------- eta v2: MFMA GEMM sigmoid(X @ lr_w^T + b)/32 -------------
// grid 256 blocks x 4 waves; wave = 16 tokens; lr_w in LDS pitch 1032
__global__ __launch_bounds__(256) void eta_kernel(
    const short* __restrict__ xb, const short* __restrict__ lrwb,
    const float* __restrict__ lr_b, float* __restrict__ eta)
{
  __shared__ __align__(16) short wl[NH_*1032];   // 66 KB, padded rows
  const int tid = threadIdx.x;
  const int lane = tid & 63, wv = tid >> 6;
  const int li = lane & 15, lh = lane >> 4;
  // stage lr_w [32][1024] -> wl [32][1032]
  #pragma unroll
  for (int s = 0; s < 16; ++s){
    const int e = tid + 256*s;              // chunk-of-8 index, 4096 total
    const int hrow = e >> 7, c = (e & 127) * 8;
    *(s16x8*)(wl + hrow*1032 + c) = ((const s16x8*)lrwb)[e];
  }
  __syncthreads();

  const int t0 = (blockIdx.x*4 + wv) * 16;
  const short* xrow = xb + (size_t)(t0 + li)*1024 + 8*lh;
  const short* w0p = wl + li*1032 + 8*lh;
  const short* w1p = wl + (16 + li)*1032 + 8*lh;
  f32x4 acc0 = {}, acc1 = {};
  #pragma unroll 4
  for (int s = 0; s < 32; ++s){
    const bf16x8 a  = *(const bf16x8*)(xrow + s*32);
    const bf16x8 b0 = *(const bf16x8*)(w0p + s*32);
    const bf16x8 b1 = *(const bf16x8*)(w1p + s*32);
    acc0 = __builtin_amdgcn_mfma_f32_16x16x32_bf16(a, b0, acc0, 0,0,0);
    acc1 = __builtin_amdgcn_mfma_f32_16x16x32_bf16(a, b1, acc1, 0,0,0);
  }
  // C-layout: token = t0 + 4*lh + r, head = li (+16)
  const int t = t0 + 4*lh;
  const int bidx = t >> 11, l = t & (L_-1), n = l >> 4, im = l & 15;
  float* e0 = eta + ((size_t)(bidx*NH_ + li)*NM_ + n)*M_ + im;
  float* e1 = eta + ((size_t)(bidx*NH_ + 16 + li)*NM_ + n)*M_ + im;
  const float lb0 = lr_b[li], lb1 = lr_b[16 + li];
  #pragma unroll
  for (int r = 0; r < 4; ++r){
    e0[r] = 1.f/(1.f + __expf(-(acc0[r] + lb0))) * (1.f/32.f);
    e1[r] = 1.f/(1.f + __expf(-(acc1[r] + lb1))) * (1.f/32.f);
  }
}

// ---------------- TTT scan v7b: 2 waves, 1 barrier/step --------------------
__global__ __launch_bounds__(128) void scan_kernel(
    const short* __restrict__ Q5, const float* __restrict__ eta,
    const float* __restrict__ W1, const float* __restrict__ b1,
    const float* __restrict__ tdelta, const float* __restrict__ lng,
    const float* __restrict__ lnb, short* __restrict__ out)
{
  const int bh = blockIdx.x;
  const int h = bh & 31, b = bh >> 5;
  const int lane = threadIdx.x & 63;
  const int wv = threadIdx.x >> 6;
  const int li = lane & 15, lh = lane >> 4;

  __shared__ __align__(16) short WTl[2][32*40];
  __shared__ __align__(16) short GTl[2][32*24];
  __shared__ float BBl[2][2][16];
  __shared__ __align__(16) float AT[16*20];
  __shared__ __align__(16) short QLl[2][16*40];

  const short* chain = Q5 + (size_t)bh * (NM_*2048);
  const float* ech   = eta + (size_t)bh * (NM_*16);

  float lw[2], lbv[2];
  #pragma unroll
  for (int hh = 0; hh < 2; ++hh){
    lw[hh]  = lng[h*32 + 16*hh + li];
    lbv[hh] = lnb[h*32 + 16*hh + li];
  }

  if (wv == 0){
    f32x4 Wq[2][2];
    #pragma unroll
    for (int rb = 0; rb < 2; ++rb)
      #pragma unroll
      for (int cb = 0; cb < 2; ++cb)
        #pragma unroll
        for (int r = 0; r < 4; ++r)
          Wq[rb][cb][r] = W1[h*1024 + (16*rb + 4*lh + r)*32 + 16*cb + li];
    float bb[2];
    bb[0] = b1[h*32 + li];  bb[1] = b1[h*32 + 16 + li];
    const float lef = fmaxf(1.f/16.f + tdelta[15], 0.f);

    auto writeWT = [&](int sl){
      #pragma unroll
      for (int cb = 0; cb < 2; ++cb)
        #pragma unroll
        for (int rb = 0; rb < 2; ++rb){
          const unsigned p0 = cvtpk(Wq[rb][cb][0], Wq[rb][cb][1]);
          const unsigned p1 = cvtpk(Wq[rb][cb][2], Wq[rb][cb][3]);
          *(uint64_t*)(&WTl[sl][0] + (16*cb + li)*40 + 16*rb + 4*lh) =
              ((uint64_t)p1 << 32) | p0;
        }
    };
    auto readWf = [&](int sl, bf16x8* Wf){
      Wf[0] = *(const bf16x8*)(&WTl[sl][0] + li*40 + 8*lh);
      Wf[1] = *(const bf16x8*)(&WTl[sl][0] + (16 + li)*40 + 8*lh);
    };

    writeWT(0);
    if (lh == 0){ BBl[0][0][li] = bb[0]; BBl[0][1][li] = bb[1]; }
    bf16x8 Wf[2];
    readWf(0, Wf);

    struct P0 { s16x8 kA, kTq0, kTq1; s16x4 kTe0, kTe1, vTe0, vTe1;
                f32x4 lr0, lr1, lr2, lr3; };
    auto ld0 = [&](int n) -> P0 {
      const short* t = chain + (size_t)n*2048;
      const float* e = ech + n*16;
      P0 p;
      p.kA   = *(const s16x8*)(t + 512 + li*32 + 8*lh);
      p.kTq0 = *(const s16x8*)(t + 1024 + li*16 + 8*(lh & 1));
      p.kTq1 = *(const s16x8*)(t + 1024 + (16 + li)*16 + 8*(lh & 1));
      p.kTe0 = *(const s16x4*)(t + 1024 + li*16 + 4*lh);
      p.kTe1 = *(const s16x4*)(t + 1024 + (16 + li)*16 + 4*lh);
      p.vTe0 = *(const s16x4*)(t + 1536 + li*16 + 4*lh);
      p.vTe1 = *(const s16x4*)(t + 1536 + (16 + li)*16 + 4*lh);
      p.lr0 = *(const f32x4*)(e);     p.lr1 = *(const f32x4*)(e + 4);
      p.lr2 = *(const f32x4*)(e + 8); p.lr3 = *(const f32x4*)(e + 12);
      return p;
    };

    P0 cur = ld0(0);
    wgbar();

    const int gcol = (8*lh) & 15;
    #pragma unroll 1
    for (int n = 0; n < NM_; ++n){
      const int sl = n & 1;
      P0 nxt = ld0(n + 1 < NM_ ? n + 1 : NM_ - 1);
      const bf16x8 kAf = __builtin_bit_cast(bf16x8, cur.kA);

      f32x4 zac[2];
      #pragma unroll
      for (int hh = 0; hh < 2; ++hh){
        f32x4 c0; c0[0]=bb[hh]; c0[1]=bb[hh]; c0[2]=bb[hh]; c0[3]=bb[hh];
        zac[hh] = __builtin_amdgcn_mfma_f32_16x16x32_bf16(kAf, Wf[hh], c0, 0,0,0);
      }

      float xh[2][4], grad[2][4], rstdv[4];
      #pragma unroll
      for (int r = 0; r < 4; ++r){
        float s  = rsum16d(zac[0][r] + zac[1][r]);
        float q2 = rsum16d(zac[0][r]*zac[0][r] + zac[1][r]*zac[1][r]);
        const float mu  = s * (1.f/32.f);
        const float var = q2 * (1.f/32.f) - mu*mu;
        const float rstd = rsqrtf(var + EPS_);
        rstdv[r] = rstd;
        xh[0][r] = (zac[0][r] - mu) * rstd;
        xh[1][r] = (zac[1][r] - mu) * rstd;
      }
      #pragma unroll
      for (int r = 0; r < 4; ++r){
        const float t0 = bf2f(cur.vTe0[r]) - bf2f(cur.kTe0[r]);
        const float t1 = bf2f(cur.vTe1[r]) - bf2f(cur.kTe1[r]);
        const float g0 = (xh[0][r]*lw[0] + lbv[0] - t0)*lw[0];
        const float g1 = (xh[1][r]*lw[1] + lbv[1] - t1)*lw[1];
        const float sg  = rsum16d(g0 + g1);
        const float sgx = rsum16d(g0*xh[0][r] + g1*xh[1][r]);
        const float f = rstdv[r] * (1.f/32.f);
        grad[0][r] = (32.f*g0 - sg - xh[0][r]*sgx) * f;
        grad[1][r] = (32.f*g1 - sg - xh[1][r]*sgx) * f;
      }

      #pragma unroll
      for (int hh = 0; hh < 2; ++hh){
        const unsigned p0 = cvtpk(grad[hh][0], grad[hh][1]);
        const unsigned p1 = cvtpk(grad[hh][2], grad[hh][3]);
        *(uint64_t*)(&GTl[sl][0] + (16*hh + li)*24 + 4*lh) =
            ((uint64_t)p1 << 32) | p0;
      }
      bf16x8 gf[2];
      gf[0] = *(const bf16x8*)(&GTl[sl][0] + li*24 + gcol);
      gf[1] = *(const bf16x8*)(&GTl[sl][0] + (16 + li)*24 + gcol);

      const f32x4 plA = (lh & 1) ? cur.lr2 : cur.lr0;
      const f32x4 plB = (lh & 1) ? cur.lr3 : cur.lr1;
      #pragma unroll
      for (int rb = 0; rb < 2; ++rb){
        const s16x8 kq = rb ? cur.kTq1 : cur.kTq0;
        float av8[8];
        #pragma unroll
        for (int jj = 0; jj < 8; ++jj){
          const float lrv = (jj < 4) ? plA[jj] : plB[jj - 4];
          av8[jj] = (lh < 2) ? -lef * lrv * bf2f(kq[jj]) : 0.f;
        }
        u32x4 auv;
        auv[0] = cvtpk(av8[0], av8[1]); auv[1] = cvtpk(av8[2], av8[3]);
        auv[2] = cvtpk(av8[4], av8[5]); auv[3] = cvtpk(av8[6], av8[7]);
        const bf16x8 af = __builtin_bit_cast(bf16x8, auv);
        #pragma unroll
        for (int cb = 0; cb < 2; ++cb)
          Wq[rb][cb] = __builtin_amdgcn_mfma_f32_16x16x32_bf16(af, gf[cb], Wq[rb][cb], 0,0,0);
      }

      // publish W(n+1) immediately (shortens W -> next-z chain)
      writeWT(sl ^ 1);

      f32x4 lrq;
      { const f32x4 t0 = (lh & 1) ? cur.lr1 : cur.lr0;
        const f32x4 t1 = (lh & 1) ? cur.lr3 : cur.lr2;
        lrq = (lh & 2) ? t1 : t0; }
      #pragma unroll
      for (int hh = 0; hh < 2; ++hh){
        float t = 0.f;
        #pragma unroll
        for (int r = 0; r < 4; ++r) t += lrq[r]*grad[hh][r];
        t += __shfl_xor(t, 16); t += __shfl_xor(t, 32);
        bb[hh] -= lef * t;
      }
      if (lh == 0){ BBl[sl ^ 1][0][li] = bb[0]; BBl[sl ^ 1][1][li] = bb[1]; }
      readWf(sl ^ 1, Wf);
      cur = nxt;
      wgbar();
    }
  } else {
    const float tok_i = fmaxf(1.f/(float)(li+1) + tdelta[li], 0.f);
    short* outp = out + (size_t)b*L_*D_ + h*32;
    const int gcol = (8*lh) & 15;

    struct P1 { s16x8 qA, kA; f32x4 lr0, lr1, lr2, lr3; };
    auto ld1 = [&](int n) -> P1 {
      const short* t = chain + (size_t)n*2048;
      const float* e = ech + n*16;
      P1 p;
      p.qA = *(const s16x8*)(t + li*32 + 8*lh);
      p.kA = *(const s16x8*)(t + 512 + li*32 + 8*lh);
      p.lr0 = *(const f32x4*)(e);     p.lr1 = *(const f32x4*)(e + 4);
      p.lr2 = *(const f32x4*)(e + 8); p.lr3 = *(const f32x4*)(e + 12);
      return p;
    };

    auto outln = [&](int n, const f32x4* yac){
      #pragma unroll
      for (int r = 0; r < 4; ++r){
        const float s  = rsum16d(yac[0][r] + yac[1][r]);
        const float q2 = rsum16d(yac[0][r]*yac[0][r] + yac[1][r]*yac[1][r]);
        const float mu   = s * (1.f/32.f);
        const float var  = q2 * (1.f/32.f) - mu*mu;
        const float rstd = rsqrtf(var + EPS_);
        const int row = 4*lh + r;
        #pragma unroll
        for (int hh = 0; hh < 2; ++hh){
          const float qv = bf2f(QLl[n & 1][row*40 + 16*hh + li]);
          const float o  = qv + (yac[hh][r] - mu)*rstd*lw[hh] + lbv[hh];
          outp[(size_t)(n*16 + row)*D_ + 16*hh + li] = f2bf(o);
        }
      }
    };

    P1 cur = ld1(0);
    wgbar();

    f32x4 yprev[2] = {};
    bf16x8 pPrev = {};
    #pragma unroll 1
    for (int n = 0; n < NM_; ++n){
      const int sl = n & 1;
      bf16x8 Wf0 = *(const bf16x8*)(&WTl[sl][0] + li*40 + 8*lh);
      bf16x8 Wf1 = *(const bf16x8*)(&WTl[sl][0] + (16 + li)*40 + 8*lh);
      const float bb0 = BBl[sl][0][li];
      const float bb1 = BBl[sl][1][li];

      if (n > 0){
        bf16x8 gf0 = *(const bf16x8*)(&GTl[sl ^ 1][0] + li*24 + gcol);
        bf16x8 gf1 = *(const bf16x8*)(&GTl[sl ^ 1][0] + (16 + li)*24 + gcol);
        yprev[0] = __builtin_amdgcn_mfma_f32_16x16x32_bf16(pPrev, gf0, yprev[0], 0,0,0);
        yprev[1] = __builtin_amdgcn_mfma_f32_16x16x32_bf16(pPrev, gf1, yprev[1], 0,0,0);
        outln(n - 1, yprev);
      }

      P1 nxt = ld1(n + 1 < NM_ ? n + 1 : NM_ - 1);
      const bf16x8 qAf = __builtin_bit_cast(bf16x8, cur.qA);
      const bf16x8 kAf = __builtin_bit_cast(bf16x8, cur.kA);

      *(s16x8*)(&QLl[sl][0] + li*40 + 8*lh) = cur.qA;

      f32x4 aac = {};
      aac = __builtin_amdgcn_mfma_f32_16x16x32_bf16(qAf, kAf, aac, 0,0,0);
      #pragma unroll
      for (int r = 0; r < 4; ++r)
        AT[(4*lh + r)*20 + li] = aac[r];

      f32x4 arA = {}, arB = {};
      if (lh < 2){
        arA = *(const f32x4*)(AT + li*20 + 8*lh);
        arB = *(const f32x4*)(AT + li*20 + 8*lh + 4);
      }
      const f32x4 plA = (lh & 1) ? cur.lr2 : cur.lr0;
      const f32x4 plB = (lh & 1) ? cur.lr3 : cur.lr1;
      float pv[8];
      #pragma unroll
      for (int jj = 0; jj < 8; ++jj){
        const float av  = (jj < 4) ? arA[jj] : arB[jj - 4];
        const float lrv = (jj < 4) ? plA[jj] : plB[jj - 4];
        const bool ok = (lh < 2) && (8*lh + jj <= li);
        pv[jj] = ok ? -tok_i * lrv * (1.f + av) : 0.f;
      }
      u32x4 ppv;
      ppv[0] = cvtpk(pv[0], pv[1]); ppv[1] = cvtpk(pv[2], pv[3]);
      ppv[2] = cvtpk(pv[4], pv[5]); ppv[3] = cvtpk(pv[6], pv[7]);
      pPrev = __builtin_bit_cast(bf16x8, ppv);

      { f32x4 c0; c0[0]=bb0; c0[1]=bb0; c0[2]=bb0; c0[3]=bb0;
        yprev[0] = __builtin_amdgcn_mfma_f32_16x16x32_bf16(qAf, Wf0, c0, 0,0,0); }
      { f32x4 c0; c0[0]=bb1; c0[1]=bb1; c0[2]=bb1; c0[3]=bb1;
        yprev[1] = __builtin_amdgcn_mfma_f32_16x16x32_bf16(qAf, Wf1, c0, 0,0,0); }

      cur = nxt;
      wgbar();
    }
    {
      const int sl = (NM_ - 1) & 1;
      bf16x8 gf0 = *(const bf16x8*)(&GTl[sl][0] + li*24 + gcol);
      bf16x8 gf1 = *(const bf16x8*)(&GTl[sl][0] + (16 + li)*24 + gcol);
      yprev[0] = __builtin_amdgcn_mfma_f32_16x16x32_bf16(pPrev, gf0, yprev[0], 0,0,0);
      yprev[1] = __builtin_amdgcn_mfma_f32_16x16x32_bf16(pPrev, gf1, yprev[1], 0,0,0);
      outln(NM_ - 1, yprev);
    }
  }
}

// ---------------------------------------------------------------------------
extern "C" void kernel_launch(void* const* d_in, const int* in_sizes, int n_in,
                              void* d_out, int out_size, void* d_ws, size_t ws_size,
                              hipStream_t stream)
{
  const float* enc    = (const float*)d_in[0];
  const float* ln0_g  = (const float*)d_in[1];
  const float* ln0_b  = (const float*)d_in[2];
  const float* Wq     = (const float*)d_in[3];
  const float* Wk     = (const float*)d_in[4];
  const float* Wv     = (const float*)d_in[5];
  const float* Wo     = (const float*)d_in[6];
  const float* W1     = (const float*)d_in[7];
  const float* b1     = (const float*)d_in[8];
  const float* tdelta = (const float*)d_in[9];
  const float* lr_w   = (const float*)d_in[10];
  const float* lr_b   = (const float*)d_in[11];
  const float* ttt_g  = (const float*)d_in[12];
  const float* ttt_b  = (const float*)d_in[13];
  const float* post_g = (const float*)d_in[14];
  const float* post_b = (const float*)d_in[15];
  const float* ffn_g  = (const float*)d_in[16];
  const float* ffn_b  = (const float*)d_in[17];
  const float* fw1    = (const float*)d_in[18];
  const float* fb1    = (const float*)d_in[19];
  const float* fw2    = (const float*)d_in[20];
  const float* fb2    = (const float*)d_in[21];

  char* ws = (char*)d_ws;
  short* Q5    = (short*)(ws + 0);            // 134,217,728 B (scan tiles)
  short* XB    = (short*)(ws + 134217728);    //  33,554,432 B
  short* SCANB = (short*)(ws + 134217728);    //  alias XB
  short* WQKVT = (short*)(ws + 167772160);    //   6,291,456 B
  short* WOT   = (short*)(ws + 174063616);    //   2,097,152 B
  short* FW1T  = (short*)(ws + 176160768);    //   4,194,304 B
  short* FW2T  = (short*)(ws + 180355072);    //   4,194,304 B
  short* LRWB  = (short*)(ws + 184549376);    //      65,536 B
  float* CT    = (float*)(ws + 184614912);    //     131,072 B
  float* ST    = (float*)(ws + 184745984);    //     131,072 B
  float* ETA   = (float*)(ws + 184877056);    //   2,097,152 B
  short* YB    = (short*)(ws + 0);            // alias Q5 (post-scan)
  short* HB    = (short*)(ws + 33554432);     // alias Q5
  short* T1    = (short*)(ws + 67108864);     // alias Q5 (64 MB, ends 134M)
  short* R2B   = (short*)(ws + 134217728);    // alias SCANB (dead post-LN)
  float* R2    = (float*)d_out;

  dim3 b256(256), b512(512);
  TC4 tc;
  tc.s0 = Wq; tc.s1 = Wk; tc.s2 = Wv; tc.s3 = Wo;
  tc.d0 = WQKVT; tc.d1 = WQKVT + 1048576; tc.d2 = WQKVT + 2097152; tc.d3 = WOT;
  transpose_cast4<<<dim3(32,32,4), b256, 0, stream>>>(tc);
  transpose_cast<<<dim3(64,32), b256, 0, stream>>>(fw1, FW1T, D_, DI_);
  transpose_cast<<<dim3(32,64), b256, 0, stream>>>(fw2, FW2T, DI_, D_);
  misc_prep<<<dim3(256), b256, 0, stream>>>(lr_w, LRWB, CT, ST);

  ln_rows<<<BL_, b256, 0, stream>>>(enc, ln0_g, ln0_b, XB);
  gemm256<0,0,0,0,0,1><<<dim3(12,64), b512, 0, stream>>>(XB, WQKVT, nullptr, nullptr, nullptr,
                                                         nullptr, Q5, CT, ST, BL_, 3072, D_);
  eta_kernel<<<dim3(256), b256, 0, stream>>>(XB, LRWB, lr_b, ETA);
  scan_kernel<<<dim3(256), dim3(128), 0, stream>>>(Q5, ETA, W1, b1, tdelta,
                                                   ttt_g, ttt_b, SCANB);
  ln_rows_bf<<<BL_, b256, 0, stream>>>(SCANB, post_g, post_b, YB);
  // Wo + residual(enc) -> R2B (bf16)
  gemm256<0,1,0,1,0,0><<<dim3(4,64), b512, 0, stream>>>(YB, WOT, nullptr, enc, nullptr,
                                                        nullptr, R2B, nullptr, nullptr, BL_, D_, D_);
  ln_rows_bf<<<BL_, b256, 0, stream>>>(R2B, ffn_g, ffn_b, HB);
  gemm256<1,1,1,0,0,0><<<dim3(8,64), b512, 0, stream>>>(HB, FW1T, fb1, nullptr, nullptr,
                                                        nullptr, T1, nullptr, nullptr, BL_, DI_, D_);
  // FFN2 + residual(R2B) -> d_out (f32)
  gemm256<0,0,1,0,1,0><<<dim3(4,64), b512, 0, stream>>>(T1, FW2T, fb2, nullptr, R2B,
                                                        R2, nullptr, nullptr, nullptr, BL_, D_, DI_);
}

// Round 12
// 510.097 us; speedup vs baseline: 2.0694x; 1.0906x over previous
//
#include <hip/hip_runtime.h>
#include <hip/hip_bf16.h>
#include <stdint.h>

#define B_   8
#define L_   2048
#define D_   1024
#define NH_  32
#define M_   16
#define NM_  128
#define HD_  32
#define DI_  2048
#define BL_  16384
#define EPS_ 1e-6f

typedef __attribute__((ext_vector_type(8))) short  s16x8;
typedef __attribute__((ext_vector_type(4))) short  s16x4;
typedef __attribute__((ext_vector_type(8))) __bf16 bf16x8;
typedef __attribute__((ext_vector_type(4))) float  f32x4;
typedef __attribute__((ext_vector_type(4))) unsigned u32x4;

__device__ __forceinline__ float bf2f(short s){
  unsigned u = ((unsigned)(unsigned short)s) << 16;
  return __builtin_bit_cast(float, u);
}
__device__ __forceinline__ short f2bf(float f){
  unsigned u = __builtin_bit_cast(unsigned, f);
  u = u + 0x7FFFu + ((u >> 16) & 1u);   // RNE
  return (short)(u >> 16);
}
__device__ __forceinline__ unsigned cvtpk(float lo, float hi){
  unsigned r;
  asm("v_cvt_pk_bf16_f32 %0, %1, %2" : "=v"(r) : "v"(lo), "v"(hi));
  return r;
}
template<int N>
__device__ __forceinline__ float ror_add(float v){
  const int y = __builtin_amdgcn_update_dpp(
      0, __builtin_bit_cast(int, v), 0x120 + N, 0xF, 0xF, true);
  return v + __builtin_bit_cast(float, y);
}
__device__ __forceinline__ float rsum16d(float v){
  v = ror_add<1>(v); v = ror_add<2>(v); v = ror_add<4>(v); v = ror_add<8>(v);
  return v;
}
__device__ __forceinline__ void wgbar(){
  asm volatile("s_waitcnt lgkmcnt(0)" ::: "memory");
  __builtin_amdgcn_s_barrier();
  __builtin_amdgcn_sched_barrier(0);
}
__device__ __forceinline__ void gl16(const void* g, void* l){
  __builtin_amdgcn_global_load_lds(
      (const __attribute__((address_space(1))) void*)g,
      (__attribute__((address_space(3))) void*)l, 16, 0, 0);
}

// ---------------- transpose + fp32->bf16 cast: out(Cc,R) = in(R,Cc)^T ------
__global__ __launch_bounds__(256) void transpose_cast(
    const float* __restrict__ in, short* __restrict__ out, int R, int Cc)
{
  __shared__ float t[32][33];
  const int lx = threadIdx.x & 31, ly = threadIdx.x >> 5;
  const int r0 = blockIdx.y * 32, c0 = blockIdx.x * 32;
  #pragma unroll
  for (int s = 0; s < 4; ++s){
    const int r = ly + s*8;
    t[r][lx] = in[(size_t)(r0 + r)*Cc + c0 + lx];
  }
  __syncthreads();
  #pragma unroll
  for (int s = 0; s < 4; ++s){
    const int r = ly + s*8;
    out[(size_t)(c0 + r)*R + r0 + lx] = f2bf(t[lx][r]);
  }
}

struct TC4 { const float *s0,*s1,*s2,*s3; short *d0,*d1,*d2,*d3; };
__global__ __launch_bounds__(256) void transpose_cast4(TC4 p)
{
  __shared__ float t[32][33];
  const int z = blockIdx.z;
  const float* in = (z==0)?p.s0:(z==1)?p.s1:(z==2)?p.s2:p.s3;
  short* out      = (z==0)?p.d0:(z==1)?p.d1:(z==2)?p.d2:p.d3;
  const int lx = threadIdx.x & 31, ly = threadIdx.x >> 5;
  const int r0 = blockIdx.y * 32, c0 = blockIdx.x * 32;
  #pragma unroll
  for (int s = 0; s < 4; ++s){
    const int r = ly + s*8;
    t[r][lx] = in[(size_t)(r0 + r)*1024 + c0 + lx];
  }
  __syncthreads();
  #pragma unroll
  for (int s = 0; s < 4; ++s){
    const int r = ly + s*8;
    out[(size_t)(c0 + r)*1024 + r0 + lx] = f2bf(t[lx][r]);
  }
}

// ---------------- misc prep: lr_w cast + rope tables -----------------------
__global__ __launch_bounds__(256) void misc_prep(
    const float* __restrict__ lr_w, short* __restrict__ lrwb,
    float* __restrict__ ct, float* __restrict__ st)
{
  const int idx = blockIdx.x*256 + threadIdx.x;
  if (idx < NH_*D_){
    lrwb[idx] = f2bf(lr_w[idx]);
  } else {
    const int k = idx - NH_*D_;
    const int l = k >> 4, j = k & 15;
    const float inv = powf(10000.f, -(float)j * (1.f/16.f));
    const float fr  = (float)l * inv;
    ct[k] = cosf(fr);
    st[k] = sinf(fr);
  }
}

// ---------------- row layernorm fp32 -> bf16 (D=1024) ----------------------
__global__ __launch_bounds__(256) void ln_rows(
    const float* __restrict__ in, const float* __restrict__ g,
    const float* __restrict__ bta, short* __restrict__ out)
{
  const int row = blockIdx.x, tid = threadIdx.x;
  const float4 v = ((const float4*)(in + (size_t)row*D_))[tid];
  float s  = v.x + v.y + v.z + v.w;
  float s2 = v.x*v.x + v.y*v.y + v.z*v.z + v.w*v.w;
  #pragma unroll
  for (int m = 1; m < 64; m <<= 1){ s += __shfl_xor(s, m); s2 += __shfl_xor(s2, m); }
  __shared__ float rs[4], rq[4];
  if ((tid & 63) == 0){ rs[tid>>6] = s; rq[tid>>6] = s2; }
  __syncthreads();
  s  = rs[0] + rs[1] + rs[2] + rs[3];
  s2 = rq[0] + rq[1] + rq[2] + rq[3];
  const float mu   = s  * (1.f/D_);
  const float var  = s2 * (1.f/D_) - mu*mu;
  const float rstd = rsqrtf(var + EPS_);
  const float4 gg = ((const float4*)g)[tid];
  const float4 bb = ((const float4*)bta)[tid];
  s16x4 o;
  o[0] = f2bf((v.x - mu)*rstd*gg.x + bb.x);
  o[1] = f2bf((v.y - mu)*rstd*gg.y + bb.y);
  o[2] = f2bf((v.z - mu)*rstd*gg.z + bb.z);
  o[3] = f2bf((v.w - mu)*rstd*gg.w + bb.w);
  ((s16x4*)(out + (size_t)row*D_))[tid] = o;
}

// ---------------- row layernorm bf16 -> bf16 (D=1024) ----------------------
__global__ __launch_bounds__(256) void ln_rows_bf(
    const short* __restrict__ in, const float* __restrict__ g,
    const float* __restrict__ bta, short* __restrict__ out)
{
  const int row = blockIdx.x, tid = threadIdx.x;
  const s16x4 v4 = ((const s16x4*)(in + (size_t)row*D_))[tid];
  float v[4];
  #pragma unroll
  for (int e = 0; e < 4; ++e) v[e] = bf2f(v4[e]);
  float s  = v[0]+v[1]+v[2]+v[3];
  float s2 = v[0]*v[0]+v[1]*v[1]+v[2]*v[2]+v[3]*v[3];
  #pragma unroll
  for (int m = 1; m < 64; m <<= 1){ s += __shfl_xor(s, m); s2 += __shfl_xor(s2, m); }
  __shared__ float rs[4], rq[4];
  if ((tid & 63) == 0){ rs[tid>>6] = s; rq[tid>>6] = s2; }
  __syncthreads();
  s  = rs[0] + rs[1] + rs[2] + rs[3];
  s2 = rq[0] + rq[1] + rq[2] + rq[3];
  const float mu   = s  * (1.f/D_);
  const float var  = s2 * (1.f/D_) - mu*mu;
  const float rstd = rsqrtf(var + EPS_);
  const float4 gg = ((const float4*)g)[tid];
  const float4 bb = ((const float4*)bta)[tid];
  s16x4 o;
  #pragma unroll
  for (int e = 0; e < 4; ++e){
    const float gv = (e==0)?gg.x:(e==1)?gg.y:(e==2)?gg.z:gg.w;
    const float bv = (e==0)?bb.x:(e==1)?bb.y:(e==2)?bb.z:bb.w;
    o[e] = f2bf((v[e] - mu)*rstd*gv + bv);
  }
  ((s16x4*)(out + (size_t)row*D_))[tid] = o;
}

// ---------------- 256x256 8-wave bf16 GEMM, BK=32, 4-deep pipeline ---------
// v3: ONE barrier per K-tile, counted vmcnt, compiler-scheduled lgkmcnt.
// LDS swizzle: chunk' = chunk ^ ((row>>1)&3).
template<int ACT, int OUTBF, int BIAS, int RES, int RESB, int QKVOUT>
__global__ __launch_bounds__(512, 2) void gemm256(
    const short* __restrict__ A, const short* __restrict__ Bt,
    const float* __restrict__ bias, const float* __restrict__ res,
    const short* __restrict__ resb,
    float* __restrict__ Cf, short* __restrict__ Cb,
    const float* __restrict__ ct, const float* __restrict__ st,
    int Mr, int N, int K)
{
  __shared__ __align__(16) short As[4][8192];
  __shared__ __align__(16) short Bs[4][8192];
  const int tid  = threadIdx.x;
  const int lane = tid & 63, wid = tid >> 6;
  const int wr = wid >> 2, wc = wid & 3;
  const int nwg = gridDim.x * gridDim.y;
  const int wg  = blockIdx.y * gridDim.x + blockIdx.x;
  const int swz = (wg & 7) * (nwg >> 3) + (wg >> 3);
  const int bx  = swz % gridDim.x, by = swz / gridDim.x;
  const int row0 = by * 256, col0 = bx * 256;

  f32x4 acc[8][4] = {};

  const int kswz = (((tid & 3) ^ ((tid >> 3) & 3)) << 3);
  const short* gAb = A  + (size_t)(row0 + (tid >> 2)) * K + kswz;
  const short* gBb = Bt + (size_t)(col0 + (tid >> 2)) * K + kswz;
  short* lAb = &As[0][0] + tid*8;
  short* lBb = &Bs[0][0] + tid*8;

  auto stage = [&](int bt2, int t2){
    const size_t kb = (size_t)t2 * 32;
    gl16(gAb + kb,                   lAb + bt2*8192);
    gl16(gAb + kb + 128*(size_t)K,   lAb + bt2*8192 + 4096);
    gl16(gBb + kb,                   lBb + bt2*8192);
    gl16(gBb + kb + 128*(size_t)K,   lBb + bt2*8192 + 4096);
  };

  const int fr = lane & 15;
  const int k0 = (((lane >> 4) ^ ((lane >> 1) & 3)) << 3);

  const int nK = K >> 5;
  stage(0, 0); stage(1, 1); stage(2, 2);
  asm volatile("s_waitcnt vmcnt(8)" ::: "memory");
  __builtin_amdgcn_s_barrier();

  for (int kt = 0; kt < nK; ++kt){
    const int bt = kt & 3;
    const short* Ab = &As[0][0] + bt*8192 + wr*4096;
    const short* Bb = &Bs[0][0] + bt*8192 + (wc >> 1)*4096 + (wc & 1)*2048;
    bf16x8 af[8], bfv[4];
    #pragma unroll
    for (int m = 0; m < 8; ++m)
      af[m] = *(const bf16x8*)(Ab + (m*16 + fr)*32 + k0);
    #pragma unroll
    for (int n = 0; n < 4; ++n)
      bfv[n] = *(const bf16x8*)(Bb + (n*16 + fr)*32 + k0);
    if (kt + 3 < nK) stage((kt + 3) & 3, kt + 3);
    __builtin_amdgcn_s_setprio(1);
    #pragma unroll
    for (int m = 0; m < 8; ++m)
      #pragma unroll
      for (int n = 0; n < 4; ++n)
        acc[m][n] = __builtin_amdgcn_mfma_f32_16x16x32_bf16(af[m], bfv[n], acc[m][n], 0,0,0);
    __builtin_amdgcn_s_setprio(0);
    if (kt + 3 < nK)      asm volatile("s_waitcnt vmcnt(8)" ::: "memory");
    else if (kt + 2 < nK) asm volatile("s_waitcnt vmcnt(4)" ::: "memory");
    else if (kt + 1 < nK) asm volatile("s_waitcnt vmcnt(0)" ::: "memory");
    __builtin_amdgcn_s_barrier();
  }

  const int cr = (lane >> 4) * 4, cc = lane & 15;
  if (QKVOUT){
    const int part = col0 >> 10;
    #pragma unroll
    for (int m = 0; m < 8; ++m){
      const int gr0 = row0 + wr*128 + m*16 + cr;
      const int bidx = gr0 >> 11, l0 = gr0 & (L_-1);
      const int nn = l0 >> 4;
      if (part < 2){
        #pragma unroll
        for (int np = 0; np < 2; ++np){
          const int gc = col0 + wc*64 + np*32 + cc;
          const int hh = (gc & 1023) >> 5;
          short* tile = Cb + ((size_t)(bidx*NH_ + hh)*NM_ + nn)*2048;
          s16x4 r0v, r1v;
          #pragma unroll
          for (int r = 0; r < 4; ++r){
            const int l = l0 + r;
            const float cv = ct[l*16 + cc], sv = st[l*16 + cc];
            const float x0 = acc[m][np*2][r], x1 = acc[m][np*2+1][r];
            const short q0 = f2bf(x0*cv - x1*sv);
            const short q1 = f2bf(x1*cv + x0*sv);
            tile[part*512 + (cr + r)*32 + cc]      = q0;
            tile[part*512 + (cr + r)*32 + cc + 16] = q1;
            r0v[r] = q0; r1v[r] = q1;
          }
          if (part == 1){
            *(s16x4*)(tile + 1024 + cc*16 + cr)      = r0v;
            *(s16x4*)(tile + 1024 + (cc+16)*16 + cr) = r1v;
          }
        }
      } else {
        #pragma unroll
        for (int n = 0; n < 4; ++n){
          const int gc = col0 + wc*64 + n*16 + cc;
          const int hh = (gc & 1023) >> 5, dd = gc & 31;
          short* tile = Cb + ((size_t)(bidx*NH_ + hh)*NM_ + nn)*2048;
          s16x4 p;
          #pragma unroll
          for (int r = 0; r < 4; ++r) p[r] = f2bf(acc[m][n][r]);
          *(s16x4*)(tile + 1536 + dd*16 + cr) = p;
        }
      }
    }
    return;
  }
  #pragma unroll
  for (int m = 0; m < 8; ++m){
    #pragma unroll
    for (int n = 0; n < 4; ++n){
      const int gc = col0 + wc*64 + n*16 + cc;
      float bv = 0.f;
      if (BIAS) bv = bias[gc];
      #pragma unroll
      for (int r = 0; r < 4; ++r){
        const int gr = row0 + wr*128 + m*16 + cr + r;
        float v = acc[m][n][r] + bv;
        if (RES)  v += res[(size_t)gr*N + gc];
        if (RESB) v += bf2f(resb[(size_t)gr*N + gc]);
        if (ACT == 1) v = fmaxf(v, 0.f);
        if (OUTBF) Cb[(size_t)gr*N + gc] = f2bf(v);
        else       Cf[(size_t)gr*N + gc] = v;
      }
    }
  }
}

// ---------------- eta v2: MFMA GEMM sigmoid(X @ lr_w^T + b)/32 -------------
__global__ __launch_bounds__(256) void eta_kernel(
    const short* __restrict__ xb, const short* __restrict__ lrwb,
    const float* __restrict__ lr_b, float* __restrict__ eta)
{
  __shared__ __align__(16) short wl[NH_*1032];   // 66 KB, padded rows
  const int tid = threadIdx.x;
  const int lane = tid & 63, wv = tid >> 6;
  const int li = lane & 15, lh = lane >> 4;
  #pragma unroll
  for (int s = 0; s < 16; ++s){
    const int e = tid + 256*s;
    const int hrow = e >> 7, c = (e & 127) * 8;
    *(s16x8*)(wl + hrow*1032 + c) = ((const s16x8*)lrwb)[e];
  }
  __syncthreads();

  const int t0 = (blockIdx.x*4 + wv) * 16;
  const short* xrow = xb + (size_t)(t0 + li)*1024 + 8*lh;
  const short* w0p = wl + li*1032 + 8*lh;
  const short* w1p = wl + (16 + li)*1032 + 8*lh;
  f32x4 acc0 = {}, acc1 = {};
  #pragma unroll 4
  for (int s = 0; s < 32; ++s){
    const bf16x8 a  = *(const bf16x8*)(xrow + s*32);
    const bf16x8 b0 = *(const bf16x8*)(w0p + s*32);
    const bf16x8 b1 = *(const bf16x8*)(w1p + s*32);
    acc0 = __builtin_amdgcn_mfma_f32_16x16x32_bf16(a, b0, acc0, 0,0,0);
    acc1 = __builtin_amdgcn_mfma_f32_16x16x32_bf16(a, b1, acc1, 0,0,0);
  }
  const int t = t0 + 4*lh;
  const int bidx = t >> 11, l = t & (L_-1), n = l >> 4, im = l & 15;
  float* e0 = eta + ((size_t)(bidx*NH_ + li)*NM_ + n)*M_ + im;
  float* e1 = eta + ((size_t)(bidx*NH_ + 16 + li)*NM_ + n)*M_ + im;
  const float lb0 = lr_b[li], lb1 = lr_b[16 + li];
  #pragma unroll
  for (int r = 0; r < 4; ++r){
    e0[r] = 1.f/(1.f + __expf(-(acc0[r] + lb0))) * (1.f/32.f);
    e1[r] = 1.f/(1.f + __expf(-(acc1[r] + lb1))) * (1.f/32.f);
  }
}

// ---------------- TTT scan v7c: 2 waves, 1 barrier/step --------------------
__global__ __launch_bounds__(128) void scan_kernel(
    const short* __restrict__ Q5, const float* __restrict__ eta,
    const float* __restrict__ W1, const float* __restrict__ b1,
    const float* __restrict__ tdelta, const float* __restrict__ lng,
    const float* __restrict__ lnb, short* __restrict__ out)
{
  const int bh = blockIdx.x;
  const int h = bh & 31, b = bh >> 5;
  const int lane = threadIdx.x & 63;
  const int wv = threadIdx.x >> 6;
  const int li = lane & 15, lh = lane >> 4;

  __shared__ __align__(16) short WTl[2][32*40];
  __shared__ __align__(16) short GTl[2][32*24];
  __shared__ float BBl[2][2][16];
  __shared__ __align__(16) float AT[16*20];
  __shared__ __align__(16) short QLl[2][16*40];

  const short* chain = Q5 + (size_t)bh * (NM_*2048);
  const float* ech   = eta + (size_t)bh * (NM_*16);

  float lw[2], lbv[2];
  #pragma unroll
  for (int hh = 0; hh < 2; ++hh){
    lw[hh]  = lng[h*32 + 16*hh + li];
    lbv[hh] = lnb[h*32 + 16*hh + li];
  }

  if (wv == 0){
    f32x4 Wq[2][2];
    #pragma unroll
    for (int rb = 0; rb < 2; ++rb)
      #pragma unroll
      for (int cb = 0; cb < 2; ++cb)
        #pragma unroll
        for (int r = 0; r < 4; ++r)
          Wq[rb][cb][r] = W1[h*1024 + (16*rb + 4*lh + r)*32 + 16*cb + li];
    float bb[2];
    bb[0] = b1[h*32 + li];  bb[1] = b1[h*32 + 16 + li];
    const float lef = fmaxf(1.f/16.f + tdelta[15], 0.f);

    auto writeWT = [&](int sl){
      #pragma unroll
      for (int cb = 0; cb < 2; ++cb)
        #pragma unroll
        for (int rb = 0; rb < 2; ++rb){
          const unsigned p0 = cvtpk(Wq[rb][cb][0], Wq[rb][cb][1]);
          const unsigned p1 = cvtpk(Wq[rb][cb][2], Wq[rb][cb][3]);
          *(uint64_t*)(&WTl[sl][0] + (16*cb + li)*40 + 16*rb + 4*lh) =
              ((uint64_t)p1 << 32) | p0;
        }
    };
    auto readWf = [&](int sl, bf16x8* Wf){
      Wf[0] = *(const bf16x8*)(&WTl[sl][0] + li*40 + 8*lh);
      Wf[1] = *(const bf16x8*)(&WTl[sl][0] + (16 + li)*40 + 8*lh);
    };

    writeWT(0);
    if (lh == 0){ BBl[0][0][li] = bb[0]; BBl[0][1][li] = bb[1]; }
    bf16x8 Wf[2];
    readWf(0, Wf);

    struct P0 { s16x8 kA, kTq0, kTq1; s16x4 kTe0, kTe1, vTe0, vTe1;
                f32x4 lr0, lr1, lr2, lr3; };
    auto ld0 = [&](int n) -> P0 {
      const short* t = chain + (size_t)n*2048;
      const float* e = ech + n*16;
      P0 p;
      p.kA   = *(const s16x8*)(t + 512 + li*32 + 8*lh);
      p.kTq0 = *(const s16x8*)(t + 1024 + li*16 + 8*(lh & 1));
      p.kTq1 = *(const s16x8*)(t + 1024 + (16 + li)*16 + 8*(lh & 1));
      p.kTe0 = *(const s16x4*)(t + 1024 + li*16 + 4*lh);
      p.kTe1 = *(const s16x4*)(t + 1024 + (16 + li)*16 + 4*lh);
      p.vTe0 = *(const s16x4*)(t + 1536 + li*16 + 4*lh);
      p.vTe1 = *(const s16x4*)(t + 1536 + (16 + li)*16 + 4*lh);
      p.lr0 = *(const f32x4*)(e);     p.lr1 = *(const f32x4*)(e + 4);
      p.lr2 = *(const f32x4*)(e + 8); p.lr3 = *(const f32x4*)(e + 12);
      return p;
    };

    P0 cur = ld0(0);
    wgbar();

    const int gcol = (8*lh) & 15;
    #pragma unroll 1
    for (int n = 0; n < NM_; ++n){
      const int sl = n & 1;
      P0 nxt = ld0(n + 1 < NM_ ? n + 1 : NM_ - 1);
      const bf16x8 kAf = __builtin_bit_cast(bf16x8, cur.kA);

      f32x4 zac[2];
      #pragma unroll
      for (int hh = 0; hh < 2; ++hh){
        f32x4 c0; c0[0]=bb[hh]; c0[1]=bb[hh]; c0[2]=bb[hh]; c0[3]=bb[hh];
        zac[hh] = __builtin_amdgcn_mfma_f32_16x16x32_bf16(kAf, Wf[hh], c0, 0,0,0);
      }

      float xh[2][4], grad[2][4], rstdv[4];
      #pragma unroll
      for (int r = 0; r < 4; ++r){
        float s  = rsum16d(zac[0][r] + zac[1][r]);
        float q2 = rsum16d(zac[0][r]*zac[0][r] + zac[1][r]*zac[1][r]);
        const float mu  = s * (1.f/32.f);
        const float var = q2 * (1.f/32.f) - mu*mu;
        const float rstd = rsqrtf(var + EPS_);
        rstdv[r] = rstd;
        xh[0][r] = (zac[0][r] - mu) * rstd;
        xh[1][r] = (zac[1][r] - mu) * rstd;
      }
      #pragma unroll
      for (int r = 0; r < 4; ++r){
        const float t0 = bf2f(cur.vTe0[r]) - bf2f(cur.kTe0[r]);
        const float t1 = bf2f(cur.vTe1[r]) - bf2f(cur.kTe1[r]);
        const float g0 = (xh[0][r]*lw[0] + lbv[0] - t0)*lw[0];
        const float g1 = (xh[1][r]*lw[1] + lbv[1] - t1)*lw[1];
        const float sg  = rsum16d(g0 + g1);
        const float sgx = rsum16d(g0*xh[0][r] + g1*xh[1][r]);
        const float f = rstdv[r] * (1.f/32.f);
        grad[0][r] = (32.f*g0 - sg - xh[0][r]*sgx) * f;
        grad[1][r] = (32.f*g1 - sg - xh[1][r]*sgx) * f;
      }

      #pragma unroll
      for (int hh = 0; hh < 2; ++hh){
        const unsigned p0 = cvtpk(grad[hh][0], grad[hh][1]);
        const unsigned p1 = cvtpk(grad[hh][2], grad[hh][3]);
        *(uint64_t*)(&GTl[sl][0] + (16*hh + li)*24 + 4*lh) =
            ((uint64_t)p1 << 32) | p0;
      }
      bf16x8 gf[2];
      gf[0] = *(const bf16x8*)(&GTl[sl][0] + li*24 + gcol);
      gf[1] = *(const bf16x8*)(&GTl[sl][0] + (16 + li)*24 + gcol);

      const f32x4 plA = (lh & 1) ? cur.lr2 : cur.lr0;
      const f32x4 plB = (lh & 1) ? cur.lr3 : cur.lr1;
      #pragma unroll
      for (int rb = 0; rb < 2; ++rb){
        const s16x8 kq = rb ? cur.kTq1 : cur.kTq0;
        float av8[8];
        #pragma unroll
        for (int jj = 0; jj < 8; ++jj){
          const float lrv = (jj < 4) ? plA[jj] : plB[jj - 4];
          av8[jj] = (lh < 2) ? -lef * lrv * bf2f(kq[jj]) : 0.f;
        }
        u32x4 auv;
        auv[0] = cvtpk(av8[0], av8[1]); auv[1] = cvtpk(av8[2], av8[3]);
        auv[2] = cvtpk(av8[4], av8[5]); auv[3] = cvtpk(av8[6], av8[7]);
        const bf16x8 af = __builtin_bit_cast(bf16x8, auv);
        #pragma unroll
        for (int cb = 0; cb < 2; ++cb)
          Wq[rb][cb] = __builtin_amdgcn_mfma_f32_16x16x32_bf16(af, gf[cb], Wq[rb][cb], 0,0,0);
      }

      // publish W(n+1) and immediately issue the read-back (latency overlaps
      // the b-update below)
      writeWT(sl ^ 1);
      readWf(sl ^ 1, Wf);

      f32x4 lrq;
      { const f32x4 t0 = (lh & 1) ? cur.lr1 : cur.lr0;
        const f32x4 t1 = (lh & 1) ? cur.lr3 : cur.lr2;
        lrq = (lh & 2) ? t1 : t0; }
      #pragma unroll
      for (int hh = 0; hh < 2; ++hh){
        float t = 0.f;
        #pragma unroll
        for (int r = 0; r < 4; ++r) t += lrq[r]*grad[hh][r];
        t += __shfl_xor(t, 16); t += __shfl_xor(t, 32);
        bb[hh] -= lef * t;
      }
      if (lh == 0){ BBl[sl ^ 1][0][li] = bb[0]; BBl[sl ^ 1][1][li] = bb[1]; }
      cur = nxt;
      wgbar();
    }
  } else {
    const float tok_i = fmaxf(1.f/(float)(li+1) + tdelta[li], 0.f);
    short* outp = out + (size_t)b*L_*D_ + h*32;
    const int gcol = (8*lh) & 15;

    struct P1 { s16x8 qA, kA; f32x4 lr0, lr1, lr2, lr3; };
    auto ld1 = [&](int n) -> P1 {
      const short* t = chain + (size_t)n*2048;
      const float* e = ech + n*16;
      P1 p;
      p.qA = *(const s16x8*)(t + li*32 + 8*lh);
      p.kA = *(const s16x8*)(t + 512 + li*32 + 8*lh);
      p.lr0 = *(const f32x4*)(e);     p.lr1 = *(const f32x4*)(e + 4);
      p.lr2 = *(const f32x4*)(e + 8); p.lr3 = *(const f32x4*)(e + 12);
      return p;
    };

    auto outln = [&](int n, const f32x4* yac){
      #pragma unroll
      for (int r = 0; r < 4; ++r){
        const float s  = rsum16d(yac[0][r] + yac[1][r]);
        const float q2 = rsum16d(yac[0][r]*yac[0][r] + yac[1][r]*yac[1][r]);
        const float mu   = s * (1.f/32.f);
        const float var  = q2 * (1.f/32.f) - mu*mu;
        const float rstd = rsqrtf(var + EPS_);
        const int row = 4*lh + r;
        #pragma unroll
        for (int hh = 0; hh < 2; ++hh){
          const float qv = bf2f(QLl[n & 1][row*40 + 16*hh + li]);
          const float o  = qv + (yac[hh][r] - mu)*rstd*lw[hh] + lbv[hh];
          outp[(size_t)(n*16 + row)*D_ + 16*hh + li] = f2bf(o);
        }
      }
    };

    P1 cur = ld1(0);
    wgbar();

    f32x4 yprev[2] = {};
    bf16x8 pPrev = {};
    #pragma unroll 1
    for (int n = 0; n < NM_; ++n){
      const int sl = n & 1;
      bf16x8 Wf0 = *(const bf16x8*)(&WTl[sl][0] + li*40 + 8*lh);
      bf16x8 Wf1 = *(const bf16x8*)(&WTl[sl][0] + (16 + li)*40 + 8*lh);
      const float bb0 = BBl[sl][0][li];
      const float bb1 = BBl[sl][1][li];

      if (n > 0){
        bf16x8 gf0 = *(const bf16x8*)(&GTl[sl ^ 1][0] + li*24 + gcol);
        bf16x8 gf1 = *(const bf16x8*)(&GTl[sl ^ 1][0] + (16 + li)*24 + gcol);
        yprev[0] = __builtin_amdgcn_mfma_f32_16x16x32_bf16(pPrev, gf0, yprev[0], 0,0,0);
        yprev[1] = __builtin_amdgcn_mfma_f32_16x16x32_bf16(pPrev, gf1, yprev[1], 0,0,0);
        outln(n - 1, yprev);
      }

      P1 nxt = ld1(n + 1 < NM_ ? n + 1 : NM_ - 1);
      const bf16x8 qAf = __builtin_bit_cast(bf16x8, cur.qA);
      const bf16x8 kAf = __builtin_bit_cast(bf16x8, cur.kA);

      *(s16x8*)(&QLl[sl][0] + li*40 + 8*lh) = cur.qA;

      f32x4 aac = {};
      aac = __builtin_amdgcn_mfma_f32_16x16x32_bf16(qAf, kAf, aac, 0,0,0);
      #pragma unroll
      for (int r = 0; r < 4; ++r)
        AT[(4*lh + r)*20 + li] = aac[r];

      f32x4 arA = {}, arB = {};
      if (lh < 2){
        arA = *(const f32x4*)(AT + li*20 + 8*lh);
        arB = *(const f32x4*)(AT + li*20 + 8*lh + 4);
      }
      const f32x4 plA = (lh & 1) ? cur.lr2 : cur.lr0;
      const f32x4 plB = (lh & 1) ? cur.lr3 : cur.lr1;
      float pv[8];
      #pragma unroll
      for (int jj = 0; jj < 8; ++jj){
        const float av  = (jj < 4) ? arA[jj] : arB[jj - 4];
        const float lrv = (jj < 4) ? plA[jj] : plB[jj - 4];
        const bool ok = (lh < 2) && (8*lh + jj <= li);
        pv[jj] = ok ? -tok_i * lrv * (1.f + av) : 0.f;
      }
      u32x4 ppv;
      ppv[0] = cvtpk(pv[0], pv[1]); ppv[1] = cvtpk(pv[2], pv[3]);
      ppv[2] = cvtpk(pv[4], pv[5]); ppv[3] = cvtpk(pv[6], pv[7]);
      pPrev = __builtin_bit_cast(bf16x8, ppv);

      { f32x4 c0; c0[0]=bb0; c0[1]=bb0; c0[2]=bb0; c0[3]=bb0;
        yprev[0] = __builtin_amdgcn_mfma_f32_16x16x32_bf16(qAf, Wf0, c0, 0,0,0); }
      { f32x4 c0; c0[0]=bb1; c0[1]=bb1; c0[2]=bb1; c0[3]=bb1;
        yprev[1] = __builtin_amdgcn_mfma_f32_16x16x32_bf16(qAf, Wf1, c0, 0,0,0); }

      cur = nxt;
      wgbar();
    }
    {
      const int sl = (NM_ - 1) & 1;
      bf16x8 gf0 = *(const bf16x8*)(&GTl[sl][0] + li*24 + gcol);
      bf16x8 gf1 = *(const bf16x8*)(&GTl[sl][0] + (16 + li)*24 + gcol);
      yprev[0] = __builtin_amdgcn_mfma_f32_16x16x32_bf16(pPrev, gf0, yprev[0], 0,0,0);
      yprev[1] = __builtin_amdgcn_mfma_f32_16x16x32_bf16(pPrev, gf1, yprev[1], 0,0,0);
      outln(NM_ - 1, yprev);
    }
  }
}

// ---------------------------------------------------------------------------
extern "C" void kernel_launch(void* const* d_in, const int* in_sizes, int n_in,
                              void* d_out, int out_size, void* d_ws, size_t ws_size,
                              hipStream_t stream)
{
  const float* enc    = (const float*)d_in[0];
  const float* ln0_g  = (const float*)d_in[1];
  const float* ln0_b  = (const float*)d_in[2];
  const float* Wq     = (const float*)d_in[3];
  const float* Wk     = (const float*)d_in[4];
  const float* Wv     = (const float*)d_in[5];
  const float* Wo     = (const float*)d_in[6];
  const float* W1     = (const float*)d_in[7];
  const float* b1     = (const float*)d_in[8];
  const float* tdelta = (const float*)d_in[9];
  const float* lr_w   = (const float*)d_in[10];
  const float* lr_b   = (const float*)d_in[11];
  const float* ttt_g  = (const float*)d_in[12];
  const float* ttt_b  = (const float*)d_in[13];
  const float* post_g = (const float*)d_in[14];
  const float* post_b = (const float*)d_in[15];
  const float* ffn_g  = (const float*)d_in[16];
  const float* ffn_b  = (const float*)d_in[17];
  const float* fw1    = (const float*)d_in[18];
  const float* fb1    = (const float*)d_in[19];
  const float* fw2    = (const float*)d_in[20];
  const float* fb2    = (const float*)d_in[21];

  char* ws = (char*)d_ws;
  short* Q5    = (short*)(ws + 0);            // 134,217,728 B (scan tiles)
  short* XB    = (short*)(ws + 134217728);    //  33,554,432 B
  short* SCANB = (short*)(ws + 134217728);    //  alias XB
  short* WQKVT = (short*)(ws + 167772160);    //   6,291,456 B
  short* WOT   = (short*)(ws + 174063616);    //   2,097,152 B
  short* FW1T  = (short*)(ws + 176160768);    //   4,194,304 B
  short* FW2T  = (short*)(ws + 180355072);    //   4,194,304 B
  short* LRWB  = (short*)(ws + 184549376);    //      65,536 B
  float* CT    = (float*)(ws + 184614912);    //     131,072 B
  float* ST    = (float*)(ws + 184745984);    //     131,072 B
  float* ETA   = (float*)(ws + 184877056);    //   2,097,152 B
  short* YB    = (short*)(ws + 0);            // alias Q5 (post-scan)
  short* HB    = (short*)(ws + 33554432);     // alias Q5
  short* T1    = (short*)(ws + 67108864);     // alias Q5 (64 MB, ends 134M)
  short* R2B   = (short*)(ws + 134217728);    // alias SCANB (dead post-LN)
  float* R2    = (float*)d_out;

  dim3 b256(256), b512(512);
  TC4 tc;
  tc.s0 = Wq; tc.s1 = Wk; tc.s2 = Wv; tc.s3 = Wo;
  tc.d0 = WQKVT; tc.d1 = WQKVT + 1048576; tc.d2 = WQKVT + 2097152; tc.d3 = WOT;
  transpose_cast4<<<dim3(32,32,4), b256, 0, stream>>>(tc);
  transpose_cast<<<dim3(64,32), b256, 0, stream>>>(fw1, FW1T, D_, DI_);
  transpose_cast<<<dim3(32,64), b256, 0, stream>>>(fw2, FW2T, DI_, D_);
  misc_prep<<<dim3(256), b256, 0, stream>>>(lr_w, LRWB, CT, ST);

  ln_rows<<<BL_, b256, 0, stream>>>(enc, ln0_g, ln0_b, XB);
  gemm256<0,0,0,0,0,1><<<dim3(12,64), b512, 0, stream>>>(XB, WQKVT, nullptr, nullptr, nullptr,
                                                         nullptr, Q5, CT, ST, BL_, 3072, D_);
  eta_kernel<<<dim3(256), b256, 0, stream>>>(XB, LRWB, lr_b, ETA);
  scan_kernel<<<dim3(256), dim3(128), 0, stream>>>(Q5, ETA, W1, b1, tdelta,
                                                   ttt_g, ttt_b, SCANB);
  ln_rows_bf<<<BL_, b256, 0, stream>>>(SCANB, post_g, post_b, YB);
  gemm256<0,1,0,1,0,0><<<dim3(4,64), b512, 0, stream>>>(YB, WOT, nullptr, enc, nullptr,
                                                        nullptr, R2B, nullptr, nullptr, BL_, D_, D_);
  ln_rows_bf<<<BL_, b256, 0, stream>>>(R2B, ffn_g, ffn_b, HB);
  gemm256<1,1,1,0,0,0><<<dim3(8,64), b512, 0, stream>>>(HB, FW1T, fb1, nullptr, nullptr,
                                                        nullptr, T1, nullptr, nullptr, BL_, DI_, D_);
  gemm256<0,0,1,0,1,0><<<dim3(4,64), b512, 0, stream>>>(T1, FW2T, fb2, nullptr, R2B,
                                                        R2, nullptr, nullptr, nullptr, BL_, D_, DI_);
}

// Round 13
// 504.792 us; speedup vs baseline: 2.0912x; 1.0105x over previous
//
#include <hip/hip_runtime.h>
#include <hip/hip_bf16.h>
#include <stdint.h>

#define B_   8
#define L_   2048
#define D_   1024
#define NH_  32
#define M_   16
#define NM_  128
#define HD_  32
#define DI_  2048
#define BL_  16384
#define EPS_ 1e-6f

typedef __attribute__((ext_vector_type(8))) short  s16x8;
typedef __attribute__((ext_vector_type(4))) short  s16x4;
typedef __attribute__((ext_vector_type(8))) __bf16 bf16x8;
typedef __attribute__((ext_vector_type(4))) float  f32x4;
typedef __attribute__((ext_vector_type(4))) unsigned u32x4;

__device__ __forceinline__ float bf2f(short s){
  unsigned u = ((unsigned)(unsigned short)s) << 16;
  return __builtin_bit_cast(float, u);
}
__device__ __forceinline__ short f2bf(float f){
  unsigned u = __builtin_bit_cast(unsigned, f);
  u = u + 0x7FFFu + ((u >> 16) & 1u);   // RNE
  return (short)(u >> 16);
}
__device__ __forceinline__ unsigned cvtpk(float lo, float hi){
  unsigned r;
  asm("v_cvt_pk_bf16_f32 %0, %1, %2" : "=v"(r) : "v"(lo), "v"(hi));
  return r;
}
template<int N>
__device__ __forceinline__ float ror_add(float v){
  const int y = __builtin_amdgcn_update_dpp(
      0, __builtin_bit_cast(int, v), 0x120 + N, 0xF, 0xF, true);
  return v + __builtin_bit_cast(float, y);
}
__device__ __forceinline__ float rsum16d(float v){
  v = ror_add<1>(v); v = ror_add<2>(v); v = ror_add<4>(v); v = ror_add<8>(v);
  return v;
}
__device__ __forceinline__ void wgbar(){
  asm volatile("s_waitcnt lgkmcnt(0)" ::: "memory");
  __builtin_amdgcn_s_barrier();
  __builtin_amdgcn_sched_barrier(0);
}
__device__ __forceinline__ void gl16(const void* g, void* l){
  __builtin_amdgcn_global_load_lds(
      (const __attribute__((address_space(1))) void*)g,
      (__attribute__((address_space(3))) void*)l, 16, 0, 0);
}

// ---------------- transpose + fp32->bf16 cast: out(Cc,R) = in(R,Cc)^T ------
__global__ __launch_bounds__(256) void transpose_cast(
    const float* __restrict__ in, short* __restrict__ out, int R, int Cc)
{
  __shared__ float t[32][33];
  const int lx = threadIdx.x & 31, ly = threadIdx.x >> 5;
  const int r0 = blockIdx.y * 32, c0 = blockIdx.x * 32;
  #pragma unroll
  for (int s = 0; s < 4; ++s){
    const int r = ly + s*8;
    t[r][lx] = in[(size_t)(r0 + r)*Cc + c0 + lx];
  }
  __syncthreads();
  #pragma unroll
  for (int s = 0; s < 4; ++s){
    const int r = ly + s*8;
    out[(size_t)(c0 + r)*R + r0 + lx] = f2bf(t[lx][r]);
  }
}

struct TC4 { const float *s0,*s1,*s2,*s3; short *d0,*d1,*d2,*d3; };
__global__ __launch_bounds__(256) void transpose_cast4(TC4 p)
{
  __shared__ float t[32][33];
  const int z = blockIdx.z;
  const float* in = (z==0)?p.s0:(z==1)?p.s1:(z==2)?p.s2:p.s3;
  short* out      = (z==0)?p.d0:(z==1)?p.d1:(z==2)?p.d2:p.d3;
  const int lx = threadIdx.x & 31, ly = threadIdx.x >> 5;
  const int r0 = blockIdx.y * 32, c0 = blockIdx.x * 32;
  #pragma unroll
  for (int s = 0; s < 4; ++s){
    const int r = ly + s*8;
    t[r][lx] = in[(size_t)(r0 + r)*1024 + c0 + lx];
  }
  __syncthreads();
  #pragma unroll
  for (int s = 0; s < 4; ++s){
    const int r = ly + s*8;
    out[(size_t)(c0 + r)*1024 + r0 + lx] = f2bf(t[lx][r]);
  }
}

// ---------------- misc prep: lr_w cast + rope tables -----------------------
__global__ __launch_bounds__(256) void misc_prep(
    const float* __restrict__ lr_w, short* __restrict__ lrwb,
    float* __restrict__ ct, float* __restrict__ st)
{
  const int idx = blockIdx.x*256 + threadIdx.x;
  if (idx < NH_*D_){
    lrwb[idx] = f2bf(lr_w[idx]);
  } else {
    const int k = idx - NH_*D_;
    const int l = k >> 4, j = k & 15;
    const float inv = powf(10000.f, -(float)j * (1.f/16.f));
    const float fr  = (float)l * inv;
    ct[k] = cosf(fr);
    st[k] = sinf(fr);
  }
}

// ---------------- row layernorm fp32 -> bf16 (D=1024) ----------------------
__global__ __launch_bounds__(256) void ln_rows(
    const float* __restrict__ in, const float* __restrict__ g,
    const float* __restrict__ bta, short* __restrict__ out)
{
  const int row = blockIdx.x, tid = threadIdx.x;
  const float4 v = ((const float4*)(in + (size_t)row*D_))[tid];
  float s  = v.x + v.y + v.z + v.w;
  float s2 = v.x*v.x + v.y*v.y + v.z*v.z + v.w*v.w;
  #pragma unroll
  for (int m = 1; m < 64; m <<= 1){ s += __shfl_xor(s, m); s2 += __shfl_xor(s2, m); }
  __shared__ float rs[4], rq[4];
  if ((tid & 63) == 0){ rs[tid>>6] = s; rq[tid>>6] = s2; }
  __syncthreads();
  s  = rs[0] + rs[1] + rs[2] + rs[3];
  s2 = rq[0] + rq[1] + rq[2] + rq[3];
  const float mu   = s  * (1.f/D_);
  const float var  = s2 * (1.f/D_) - mu*mu;
  const float rstd = rsqrtf(var + EPS_);
  const float4 gg = ((const float4*)g)[tid];
  const float4 bb = ((const float4*)bta)[tid];
  s16x4 o;
  o[0] = f2bf((v.x - mu)*rstd*gg.x + bb.x);
  o[1] = f2bf((v.y - mu)*rstd*gg.y + bb.y);
  o[2] = f2bf((v.z - mu)*rstd*gg.z + bb.z);
  o[3] = f2bf((v.w - mu)*rstd*gg.w + bb.w);
  ((s16x4*)(out + (size_t)row*D_))[tid] = o;
}

// ---------------- row layernorm bf16 -> bf16 (D=1024) ----------------------
__global__ __launch_bounds__(256) void ln_rows_bf(
    const short* __restrict__ in, const float* __restrict__ g,
    const float* __restrict__ bta, short* __restrict__ out)
{
  const int row = blockIdx.x, tid = threadIdx.x;
  const s16x4 v4 = ((const s16x4*)(in + (size_t)row*D_))[tid];
  float v[4];
  #pragma unroll
  for (int e = 0; e < 4; ++e) v[e] = bf2f(v4[e]);
  float s  = v[0]+v[1]+v[2]+v[3];
  float s2 = v[0]*v[0]+v[1]*v[1]+v[2]*v[2]+v[3]*v[3];
  #pragma unroll
  for (int m = 1; m < 64; m <<= 1){ s += __shfl_xor(s, m); s2 += __shfl_xor(s2, m); }
  __shared__ float rs[4], rq[4];
  if ((tid & 63) == 0){ rs[tid>>6] = s; rq[tid>>6] = s2; }
  __syncthreads();
  s  = rs[0] + rs[1] + rs[2] + rs[3];
  s2 = rq[0] + rq[1] + rq[2] + rq[3];
  const float mu   = s  * (1.f/D_);
  const float var  = s2 * (1.f/D_) - mu*mu;
  const float rstd = rsqrtf(var + EPS_);
  const float4 gg = ((const float4*)g)[tid];
  const float4 bb = ((const float4*)bta)[tid];
  s16x4 o;
  #pragma unroll
  for (int e = 0; e < 4; ++e){
    const float gv = (e==0)?gg.x:(e==1)?gg.y:(e==2)?gg.z:gg.w;
    const float bv = (e==0)?bb.x:(e==1)?bb.y:(e==2)?bb.z:bb.w;
    o[e] = f2bf((v[e] - mu)*rstd*gv + bv);
  }
  ((s16x4*)(out + (size_t)row*D_))[tid] = o;
}

// ---------------- 256x256 8-wave bf16 GEMM, BK=32, 4-deep pipeline ---------
// v3: ONE barrier per K-tile, counted vmcnt. Swizzle: chunk^=((row>>1)&3).
template<int ACT, int OUTBF, int BIAS, int RES, int RESB, int QKVOUT>
__global__ __launch_bounds__(512, 2) void gemm256(
    const short* __restrict__ A, const short* __restrict__ Bt,
    const float* __restrict__ bias, const float* __restrict__ res,
    const short* __restrict__ resb,
    float* __restrict__ Cf, short* __restrict__ Cb,
    const float* __restrict__ ct, const float* __restrict__ st,
    int Mr, int N, int K)
{
  __shared__ __align__(16) short As[4][8192];
  __shared__ __align__(16) short Bs[4][8192];
  const int tid  = threadIdx.x;
  const int lane = tid & 63, wid = tid >> 6;
  const int wr = wid >> 2, wc = wid & 3;
  const int nwg = gridDim.x * gridDim.y;
  const int wg  = blockIdx.y * gridDim.x + blockIdx.x;
  const int swz = (wg & 7) * (nwg >> 3) + (wg >> 3);
  const int bx  = swz % gridDim.x, by = swz / gridDim.x;
  const int row0 = by * 256, col0 = bx * 256;

  f32x4 acc[8][4] = {};

  const int kswz = (((tid & 3) ^ ((tid >> 3) & 3)) << 3);
  const short* gAb = A  + (size_t)(row0 + (tid >> 2)) * K + kswz;
  const short* gBb = Bt + (size_t)(col0 + (tid >> 2)) * K + kswz;
  short* lAb = &As[0][0] + tid*8;
  short* lBb = &Bs[0][0] + tid*8;

  auto stage = [&](int bt2, int t2){
    const size_t kb = (size_t)t2 * 32;
    gl16(gAb + kb,                   lAb + bt2*8192);
    gl16(gAb + kb + 128*(size_t)K,   lAb + bt2*8192 + 4096);
    gl16(gBb + kb,                   lBb + bt2*8192);
    gl16(gBb + kb + 128*(size_t)K,   lBb + bt2*8192 + 4096);
  };

  const int fr = lane & 15;
  const int k0 = (((lane >> 4) ^ ((lane >> 1) & 3)) << 3);

  const int nK = K >> 5;
  stage(0, 0); stage(1, 1); stage(2, 2);
  asm volatile("s_waitcnt vmcnt(8)" ::: "memory");
  __builtin_amdgcn_s_barrier();

  for (int kt = 0; kt < nK; ++kt){
    const int bt = kt & 3;
    const short* Ab = &As[0][0] + bt*8192 + wr*4096;
    const short* Bb = &Bs[0][0] + bt*8192 + (wc >> 1)*4096 + (wc & 1)*2048;
    bf16x8 af[8], bfv[4];
    #pragma unroll
    for (int m = 0; m < 8; ++m)
      af[m] = *(const bf16x8*)(Ab + (m*16 + fr)*32 + k0);
    #pragma unroll
    for (int n = 0; n < 4; ++n)
      bfv[n] = *(const bf16x8*)(Bb + (n*16 + fr)*32 + k0);
    if (kt + 3 < nK) stage((kt + 3) & 3, kt + 3);
    __builtin_amdgcn_s_setprio(1);
    #pragma unroll
    for (int m = 0; m < 8; ++m)
      #pragma unroll
      for (int n = 0; n < 4; ++n)
        acc[m][n] = __builtin_amdgcn_mfma_f32_16x16x32_bf16(af[m], bfv[n], acc[m][n], 0,0,0);
    __builtin_amdgcn_s_setprio(0);
    if (kt + 3 < nK)      asm volatile("s_waitcnt vmcnt(8)" ::: "memory");
    else if (kt + 2 < nK) asm volatile("s_waitcnt vmcnt(4)" ::: "memory");
    else if (kt + 1 < nK) asm volatile("s_waitcnt vmcnt(0)" ::: "memory");
    __builtin_amdgcn_s_barrier();
  }

  const int cr = (lane >> 4) * 4, cc = lane & 15;
  if (QKVOUT){
    const int part = col0 >> 10;
    #pragma unroll
    for (int m = 0; m < 8; ++m){
      const int gr0 = row0 + wr*128 + m*16 + cr;
      const int bidx = gr0 >> 11, l0 = gr0 & (L_-1);
      const int nn = l0 >> 4;
      if (part < 2){
        #pragma unroll
        for (int np = 0; np < 2; ++np){
          const int gc = col0 + wc*64 + np*32 + cc;
          const int hh = (gc & 1023) >> 5;
          short* tile = Cb + ((size_t)(bidx*NH_ + hh)*NM_ + nn)*2048;
          s16x4 r0v, r1v;
          #pragma unroll
          for (int r = 0; r < 4; ++r){
            const int l = l0 + r;
            const float cv = ct[l*16 + cc], sv = st[l*16 + cc];
            const float x0 = acc[m][np*2][r], x1 = acc[m][np*2+1][r];
            const short q0 = f2bf(x0*cv - x1*sv);
            const short q1 = f2bf(x1*cv + x0*sv);
            tile[part*512 + (cr + r)*32 + cc]      = q0;
            tile[part*512 + (cr + r)*32 + cc + 16] = q1;
            r0v[r] = q0; r1v[r] = q1;
          }
          if (part == 1){
            *(s16x4*)(tile + 1024 + cc*16 + cr)      = r0v;
            *(s16x4*)(tile + 1024 + (cc+16)*16 + cr) = r1v;
          }
        }
      } else {
        #pragma unroll
        for (int n = 0; n < 4; ++n){
          const int gc = col0 + wc*64 + n*16 + cc;
          const int hh = (gc & 1023) >> 5, dd = gc & 31;
          short* tile = Cb + ((size_t)(bidx*NH_ + hh)*NM_ + nn)*2048;
          s16x4 p;
          #pragma unroll
          for (int r = 0; r < 4; ++r) p[r] = f2bf(acc[m][n][r]);
          *(s16x4*)(tile + 1536 + dd*16 + cr) = p;
        }
      }
    }
    return;
  }
  #pragma unroll
  for (int m = 0; m < 8; ++m){
    #pragma unroll
    for (int n = 0; n < 4; ++n){
      const int gc = col0 + wc*64 + n*16 + cc;
      float bv = 0.f;
      if (BIAS) bv = bias[gc];
      #pragma unroll
      for (int r = 0; r < 4; ++r){
        const int gr = row0 + wr*128 + m*16 + cr + r;
        float v = acc[m][n][r] + bv;
        if (RES)  v += res[(size_t)gr*N + gc];
        if (RESB) v += bf2f(resb[(size_t)gr*N + gc]);
        if (ACT == 1) v = fmaxf(v, 0.f);
        if (OUTBF) Cb[(size_t)gr*N + gc] = f2bf(v);
        else       Cf[(size_t)gr*N + gc] = v;
      }
    }
  }
}

// ---------------- eta v2: MFMA GEMM sigmoid(X @ lr_w^T + b)/32 -------------
__global__ __launch_bounds__(256) void eta_kernel(
    const short* __restrict__ xb, const short* __restrict__ lrwb,
    const float* __restrict__ lr_b, float* __restrict__ eta)
{
  __shared__ __align__(16) short wl[NH_*1032];   // 66 KB, padded rows
  const int tid = threadIdx.x;
  const int lane = tid & 63, wv = tid >> 6;
  const int li = lane & 15, lh = lane >> 4;
  #pragma unroll
  for (int s = 0; s < 16; ++s){
    const int e = tid + 256*s;
    const int hrow = e >> 7, c = (e & 127) * 8;
    *(s16x8*)(wl + hrow*1032 + c) = ((const s16x8*)lrwb)[e];
  }
  __syncthreads();

  const int t0 = (blockIdx.x*4 + wv) * 16;
  const short* xrow = xb + (size_t)(t0 + li)*1024 + 8*lh;
  const short* w0p = wl + li*1032 + 8*lh;
  const short* w1p = wl + (16 + li)*1032 + 8*lh;
  f32x4 acc0 = {}, acc1 = {};
  #pragma unroll 4
  for (int s = 0; s < 32; ++s){
    const bf16x8 a  = *(const bf16x8*)(xrow + s*32);
    const bf16x8 b0 = *(const bf16x8*)(w0p + s*32);
    const bf16x8 b1 = *(const bf16x8*)(w1p + s*32);
    acc0 = __builtin_amdgcn_mfma_f32_16x16x32_bf16(a, b0, acc0, 0,0,0);
    acc1 = __builtin_amdgcn_mfma_f32_16x16x32_bf16(a, b1, acc1, 0,0,0);
  }
  const int t = t0 + 4*lh;
  const int bidx = t >> 11, l = t & (L_-1), n = l >> 4, im = l & 15;
  float* e0 = eta + ((size_t)(bidx*NH_ + li)*NM_ + n)*M_ + im;
  float* e1 = eta + ((size_t)(bidx*NH_ + 16 + li)*NM_ + n)*M_ + im;
  const float lb0 = lr_b[li], lb1 = lr_b[16 + li];
  #pragma unroll
  for (int r = 0; r < 4; ++r){
    e0[r] = 1.f/(1.f + __expf(-(acc0[r] + lb0))) * (1.f/32.f);
    e1[r] = 1.f/(1.f + __expf(-(acc1[r] + lb1))) * (1.f/32.f);
  }
}

// ---------------- TTT scan v8: 3 waves (state + 2 output by parity) --------
__global__ __launch_bounds__(192) void scan_kernel(
    const short* __restrict__ Q5, const float* __restrict__ eta,
    const float* __restrict__ W1, const float* __restrict__ b1,
    const float* __restrict__ tdelta, const float* __restrict__ lng,
    const float* __restrict__ lnb, short* __restrict__ out)
{
  const int bh = blockIdx.x;
  const int h = bh & 31, b = bh >> 5;
  const int lane = threadIdx.x & 63;
  const int wv = threadIdx.x >> 6;
  const int li = lane & 15, lh = lane >> 4;

  __shared__ __align__(16) short WTl[2][32*40];
  __shared__ __align__(16) short GTl[2][32*24];
  __shared__ float BBl[2][2][16];
  __shared__ __align__(16) float AT[16*20];
  __shared__ __align__(16) short QLl[2][16*40];

  const short* chain = Q5 + (size_t)bh * (NM_*2048);
  const float* ech   = eta + (size_t)bh * (NM_*16);

  float lw[2], lbv[2];
  #pragma unroll
  for (int hh = 0; hh < 2; ++hh){
    lw[hh]  = lng[h*32 + 16*hh + li];
    lbv[hh] = lnb[h*32 + 16*hh + li];
  }

  if (wv == 0){
    // =================== STATE WAVE ===================
    f32x4 Wq[2][2];
    #pragma unroll
    for (int rb = 0; rb < 2; ++rb)
      #pragma unroll
      for (int cb = 0; cb < 2; ++cb)
        #pragma unroll
        for (int r = 0; r < 4; ++r)
          Wq[rb][cb][r] = W1[h*1024 + (16*rb + 4*lh + r)*32 + 16*cb + li];
    float bb[2];
    bb[0] = b1[h*32 + li];  bb[1] = b1[h*32 + 16 + li];
    const float lef = fmaxf(1.f/16.f + tdelta[15], 0.f);

    auto writeWT = [&](int sl){
      #pragma unroll
      for (int cb = 0; cb < 2; ++cb)
        #pragma unroll
        for (int rb = 0; rb < 2; ++rb){
          const unsigned p0 = cvtpk(Wq[rb][cb][0], Wq[rb][cb][1]);
          const unsigned p1 = cvtpk(Wq[rb][cb][2], Wq[rb][cb][3]);
          *(uint64_t*)(&WTl[sl][0] + (16*cb + li)*40 + 16*rb + 4*lh) =
              ((uint64_t)p1 << 32) | p0;
        }
    };
    auto readWf = [&](int sl, bf16x8* Wf){
      Wf[0] = *(const bf16x8*)(&WTl[sl][0] + li*40 + 8*lh);
      Wf[1] = *(const bf16x8*)(&WTl[sl][0] + (16 + li)*40 + 8*lh);
    };

    writeWT(0);
    if (lh == 0){ BBl[0][0][li] = bb[0]; BBl[0][1][li] = bb[1]; }
    bf16x8 Wf[2];
    readWf(0, Wf);

    struct P0 { s16x8 kA, kTq0, kTq1; s16x4 kTe0, kTe1, vTe0, vTe1;
                f32x4 lr0, lr1, lr2, lr3; };
    auto ld0 = [&](int n) -> P0 {
      const short* t = chain + (size_t)n*2048;
      const float* e = ech + n*16;
      P0 p;
      p.kA   = *(const s16x8*)(t + 512 + li*32 + 8*lh);
      p.kTq0 = *(const s16x8*)(t + 1024 + li*16 + 8*(lh & 1));
      p.kTq1 = *(const s16x8*)(t + 1024 + (16 + li)*16 + 8*(lh & 1));
      p.kTe0 = *(const s16x4*)(t + 1024 + li*16 + 4*lh);
      p.kTe1 = *(const s16x4*)(t + 1024 + (16 + li)*16 + 4*lh);
      p.vTe0 = *(const s16x4*)(t + 1536 + li*16 + 4*lh);
      p.vTe1 = *(const s16x4*)(t + 1536 + (16 + li)*16 + 4*lh);
      p.lr0 = *(const f32x4*)(e);     p.lr1 = *(const f32x4*)(e + 4);
      p.lr2 = *(const f32x4*)(e + 8); p.lr3 = *(const f32x4*)(e + 12);
      return p;
    };

    P0 cur = ld0(0);
    wgbar();

    const int gcol = (8*lh) & 15;
    #pragma unroll 1
    for (int p = 0; p <= NM_; ++p){
      if (p < NM_){
        const int n = p;
        const int sl = n & 1;
        P0 nxt = ld0(n + 1 < NM_ ? n + 1 : NM_ - 1);
        const bf16x8 kAf = __builtin_bit_cast(bf16x8, cur.kA);

        f32x4 zac[2];
        #pragma unroll
        for (int hh = 0; hh < 2; ++hh){
          f32x4 c0; c0[0]=bb[hh]; c0[1]=bb[hh]; c0[2]=bb[hh]; c0[3]=bb[hh];
          zac[hh] = __builtin_amdgcn_mfma_f32_16x16x32_bf16(kAf, Wf[hh], c0, 0,0,0);
        }

        float xh[2][4], grad[2][4], rstdv[4];
        #pragma unroll
        for (int r = 0; r < 4; ++r){
          float s  = rsum16d(zac[0][r] + zac[1][r]);
          float q2 = rsum16d(zac[0][r]*zac[0][r] + zac[1][r]*zac[1][r]);
          const float mu  = s * (1.f/32.f);
          const float var = q2 * (1.f/32.f) - mu*mu;
          const float rstd = rsqrtf(var + EPS_);
          rstdv[r] = rstd;
          xh[0][r] = (zac[0][r] - mu) * rstd;
          xh[1][r] = (zac[1][r] - mu) * rstd;
        }
        #pragma unroll
        for (int r = 0; r < 4; ++r){
          const float t0 = bf2f(cur.vTe0[r]) - bf2f(cur.kTe0[r]);
          const float t1 = bf2f(cur.vTe1[r]) - bf2f(cur.kTe1[r]);
          const float g0 = (xh[0][r]*lw[0] + lbv[0] - t0)*lw[0];
          const float g1 = (xh[1][r]*lw[1] + lbv[1] - t1)*lw[1];
          const float sg  = rsum16d(g0 + g1);
          const float sgx = rsum16d(g0*xh[0][r] + g1*xh[1][r]);
          const float f = rstdv[r] * (1.f/32.f);
          grad[0][r] = (32.f*g0 - sg - xh[0][r]*sgx) * f;
          grad[1][r] = (32.f*g1 - sg - xh[1][r]*sgx) * f;
        }

        #pragma unroll
        for (int hh = 0; hh < 2; ++hh){
          const unsigned p0 = cvtpk(grad[hh][0], grad[hh][1]);
          const unsigned p1 = cvtpk(grad[hh][2], grad[hh][3]);
          *(uint64_t*)(&GTl[sl][0] + (16*hh + li)*24 + 4*lh) =
              ((uint64_t)p1 << 32) | p0;
        }
        bf16x8 gf[2];
        gf[0] = *(const bf16x8*)(&GTl[sl][0] + li*24 + gcol);
        gf[1] = *(const bf16x8*)(&GTl[sl][0] + (16 + li)*24 + gcol);

        const f32x4 plA = (lh & 1) ? cur.lr2 : cur.lr0;
        const f32x4 plB = (lh & 1) ? cur.lr3 : cur.lr1;
        #pragma unroll
        for (int rb = 0; rb < 2; ++rb){
          const s16x8 kq = rb ? cur.kTq1 : cur.kTq0;
          float av8[8];
          #pragma unroll
          for (int jj = 0; jj < 8; ++jj){
            const float lrv = (jj < 4) ? plA[jj] : plB[jj - 4];
            av8[jj] = (lh < 2) ? -lef * lrv * bf2f(kq[jj]) : 0.f;
          }
          u32x4 auv;
          auv[0] = cvtpk(av8[0], av8[1]); auv[1] = cvtpk(av8[2], av8[3]);
          auv[2] = cvtpk(av8[4], av8[5]); auv[3] = cvtpk(av8[6], av8[7]);
          const bf16x8 af = __builtin_bit_cast(bf16x8, auv);
          #pragma unroll
          for (int cb = 0; cb < 2; ++cb)
            Wq[rb][cb] = __builtin_amdgcn_mfma_f32_16x16x32_bf16(af, gf[cb], Wq[rb][cb], 0,0,0);
        }

        writeWT(sl ^ 1);
        readWf(sl ^ 1, Wf);

        f32x4 lrq;
        { const f32x4 t0 = (lh & 1) ? cur.lr1 : cur.lr0;
          const f32x4 t1 = (lh & 1) ? cur.lr3 : cur.lr2;
          lrq = (lh & 2) ? t1 : t0; }
        #pragma unroll
        for (int hh = 0; hh < 2; ++hh){
          float t = 0.f;
          #pragma unroll
          for (int r = 0; r < 4; ++r) t += lrq[r]*grad[hh][r];
          t += __shfl_xor(t, 16); t += __shfl_xor(t, 32);
          bb[hh] -= lef * t;
        }
        if (lh == 0){ BBl[sl ^ 1][0][li] = bb[0]; BBl[sl ^ 1][1][li] = bb[1]; }
        cur = nxt;
      }
      wgbar();
    }
  } else {
    // =================== OUTPUT WAVES (step parity = wv-1) ===================
    const int par = wv - 1;
    const float tok_i = fmaxf(1.f/(float)(li+1) + tdelta[li], 0.f);
    short* outp = out + (size_t)b*L_*D_ + h*32;
    const int gcol = (8*lh) & 15;

    struct P1 { s16x8 qA, kA; f32x4 lr0, lr1, lr2, lr3; };
    auto ld1 = [&](int n) -> P1 {
      const short* t = chain + (size_t)n*2048;
      const float* e = ech + n*16;
      P1 p;
      p.qA = *(const s16x8*)(t + li*32 + 8*lh);
      p.kA = *(const s16x8*)(t + 512 + li*32 + 8*lh);
      p.lr0 = *(const f32x4*)(e);     p.lr1 = *(const f32x4*)(e + 4);
      p.lr2 = *(const f32x4*)(e + 8); p.lr3 = *(const f32x4*)(e + 12);
      return p;
    };

    auto outln = [&](int n, const f32x4* yac){
      #pragma unroll
      for (int r = 0; r < 4; ++r){
        const float s  = rsum16d(yac[0][r] + yac[1][r]);
        const float q2 = rsum16d(yac[0][r]*yac[0][r] + yac[1][r]*yac[1][r]);
        const float mu   = s * (1.f/32.f);
        const float var  = q2 * (1.f/32.f) - mu*mu;
        const float rstd = rsqrtf(var + EPS_);
        const int row = 4*lh + r;
        #pragma unroll
        for (int hh = 0; hh < 2; ++hh){
          const float qv = bf2f(QLl[n & 1][row*40 + 16*hh + li]);
          const float o  = qv + (yac[hh][r] - mu)*rstd*lw[hh] + lbv[hh];
          outp[(size_t)(n*16 + row)*D_ + 16*hh + li] = f2bf(o);
        }
      }
    };

    P1 cur = ld1(par);
    wgbar();

    f32x4 ycur[2] = {};
    bf16x8 pCur = {};
    #pragma unroll 1
    for (int p = 0; p <= NM_; ++p){
      if (p >= 1 && ((p - 1) & 1) == par){
        // phase 2: finish step p-1 (grad published during period p-1)
        const int m = p - 1;
        const int sl = m & 1;
        bf16x8 gf0 = *(const bf16x8*)(&GTl[sl][0] + li*24 + gcol);
        bf16x8 gf1 = *(const bf16x8*)(&GTl[sl][0] + (16 + li)*24 + gcol);
        ycur[0] = __builtin_amdgcn_mfma_f32_16x16x32_bf16(pCur, gf0, ycur[0], 0,0,0);
        ycur[1] = __builtin_amdgcn_mfma_f32_16x16x32_bf16(pCur, gf1, ycur[1], 0,0,0);
        outln(m, ycur);
      }
      if (p < NM_ && (p & 1) == par){
        // phase 1: start step p (W(p), b(p) published during period p-1)
        const int sl = p & 1;
        bf16x8 Wf0 = *(const bf16x8*)(&WTl[sl][0] + li*40 + 8*lh);
        bf16x8 Wf1 = *(const bf16x8*)(&WTl[sl][0] + (16 + li)*40 + 8*lh);
        const float bb0 = BBl[sl][0][li];
        const float bb1 = BBl[sl][1][li];

        P1 nxt = ld1(p + 2 < NM_ ? p + 2 : p);
        const bf16x8 qAf = __builtin_bit_cast(bf16x8, cur.qA);
        const bf16x8 kAf = __builtin_bit_cast(bf16x8, cur.kA);

        *(s16x8*)(&QLl[sl][0] + li*40 + 8*lh) = cur.qA;

        f32x4 aac = {};
        aac = __builtin_amdgcn_mfma_f32_16x16x32_bf16(qAf, kAf, aac, 0,0,0);
        #pragma unroll
        for (int r = 0; r < 4; ++r)
          AT[(4*lh + r)*20 + li] = aac[r];

        f32x4 arA = {}, arB = {};
        if (lh < 2){
          arA = *(const f32x4*)(AT + li*20 + 8*lh);
          arB = *(const f32x4*)(AT + li*20 + 8*lh + 4);
        }
        const f32x4 plA = (lh & 1) ? cur.lr2 : cur.lr0;
        const f32x4 plB = (lh & 1) ? cur.lr3 : cur.lr1;
        float pv[8];
        #pragma unroll
        for (int jj = 0; jj < 8; ++jj){
          const float av  = (jj < 4) ? arA[jj] : arB[jj - 4];
          const float lrv = (jj < 4) ? plA[jj] : plB[jj - 4];
          const bool ok = (lh < 2) && (8*lh + jj <= li);
          pv[jj] = ok ? -tok_i * lrv * (1.f + av) : 0.f;
        }
        u32x4 ppv;
        ppv[0] = cvtpk(pv[0], pv[1]); ppv[1] = cvtpk(pv[2], pv[3]);
        ppv[2] = cvtpk(pv[4], pv[5]); ppv[3] = cvtpk(pv[6], pv[7]);
        pCur = __builtin_bit_cast(bf16x8, ppv);

        { f32x4 c0; c0[0]=bb0; c0[1]=bb0; c0[2]=bb0; c0[3]=bb0;
          ycur[0] = __builtin_amdgcn_mfma_f32_16x16x32_bf16(qAf, Wf0, c0, 0,0,0); }
        { f32x4 c0; c0[0]=bb1; c0[1]=bb1; c0[2]=bb1; c0[3]=bb1;
          ycur[1] = __builtin_amdgcn_mfma_f32_16x16x32_bf16(qAf, Wf1, c0, 0,0,0); }

        cur = nxt;
      }
      wgbar();
    }
  }
}

// ---------------------------------------------------------------------------
extern "C" void kernel_launch(void* const* d_in, const int* in_sizes, int n_in,
                              void* d_out, int out_size, void* d_ws, size_t ws_size,
                              hipStream_t stream)
{
  const float* enc    = (const float*)d_in[0];
  const float* ln0_g  = (const float*)d_in[1];
  const float* ln0_b  = (const float*)d_in[2];
  const float* Wq     = (const float*)d_in[3];
  const float* Wk     = (const float*)d_in[4];
  const float* Wv     = (const float*)d_in[5];
  const float* Wo     = (const float*)d_in[6];
  const float* W1     = (const float*)d_in[7];
  const float* b1     = (const float*)d_in[8];
  const float* tdelta = (const float*)d_in[9];
  const float* lr_w   = (const float*)d_in[10];
  const float* lr_b   = (const float*)d_in[11];
  const float* ttt_g  = (const float*)d_in[12];
  const float* ttt_b  = (const float*)d_in[13];
  const float* post_g = (const float*)d_in[14];
  const float* post_b = (const float*)d_in[15];
  const float* ffn_g  = (const float*)d_in[16];
  const float* ffn_b  = (const float*)d_in[17];
  const float* fw1    = (const float*)d_in[18];
  const float* fb1    = (const float*)d_in[19];
  const float* fw2    = (const float*)d_in[20];
  const float* fb2    = (const float*)d_in[21];

  char* ws = (char*)d_ws;
  short* Q5    = (short*)(ws + 0);            // 134,217,728 B (scan tiles)
  short* XB    = (short*)(ws + 134217728);    //  33,554,432 B
  short* SCANB = (short*)(ws + 134217728);    //  alias XB
  short* WQKVT = (short*)(ws + 167772160);    //   6,291,456 B
  short* WOT   = (short*)(ws + 174063616);    //   2,097,152 B
  short* FW1T  = (short*)(ws + 176160768);    //   4,194,304 B
  short* FW2T  = (short*)(ws + 180355072);    //   4,194,304 B
  short* LRWB  = (short*)(ws + 184549376);    //      65,536 B
  float* CT    = (float*)(ws + 184614912);    //     131,072 B
  float* ST    = (float*)(ws + 184745984);    //     131,072 B
  float* ETA   = (float*)(ws + 184877056);    //   2,097,152 B
  short* YB    = (short*)(ws + 0);            // alias Q5 (post-scan)
  short* HB    = (short*)(ws + 33554432);     // alias Q5
  short* T1    = (short*)(ws + 67108864);     // alias Q5 (64 MB, ends 134M)
  short* R2B   = (short*)(ws + 134217728);    // alias SCANB (dead post-LN)
  float* R2    = (float*)d_out;

  dim3 b256(256), b512(512);
  TC4 tc;
  tc.s0 = Wq; tc.s1 = Wk; tc.s2 = Wv; tc.s3 = Wo;
  tc.d0 = WQKVT; tc.d1 = WQKVT + 1048576; tc.d2 = WQKVT + 2097152; tc.d3 = WOT;
  transpose_cast4<<<dim3(32,32,4), b256, 0, stream>>>(tc);
  transpose_cast<<<dim3(64,32), b256, 0, stream>>>(fw1, FW1T, D_, DI_);
  transpose_cast<<<dim3(32,64), b256, 0, stream>>>(fw2, FW2T, DI_, D_);
  misc_prep<<<dim3(256), b256, 0, stream>>>(lr_w, LRWB, CT, ST);

  ln_rows<<<BL_, b256, 0, stream>>>(enc, ln0_g, ln0_b, XB);
  gemm256<0,0,0,0,0,1><<<dim3(12,64), b512, 0, stream>>>(XB, WQKVT, nullptr, nullptr, nullptr,
                                                         nullptr, Q5, CT, ST, BL_, 3072, D_);
  eta_kernel<<<dim3(256), b256, 0, stream>>>(XB, LRWB, lr_b, ETA);
  scan_kernel<<<dim3(256), dim3(192), 0, stream>>>(Q5, ETA, W1, b1, tdelta,
                                                   ttt_g, ttt_b, SCANB);
  ln_rows_bf<<<BL_, b256, 0, stream>>>(SCANB, post_g, post_b, YB);
  gemm256<0,1,0,1,0,0><<<dim3(4,64), b512, 0, stream>>>(YB, WOT, nullptr, enc, nullptr,
                                                        nullptr, R2B, nullptr, nullptr, BL_, D_, D_);
  ln_rows_bf<<<BL_, b256, 0, stream>>>(R2B, ffn_g, ffn_b, HB);
  gemm256<1,1,1,0,0,0><<<dim3(8,64), b512, 0, stream>>>(HB, FW1T, fb1, nullptr, nullptr,
                                                        nullptr, T1, nullptr, nullptr, BL_, DI_, D_);
  gemm256<0,0,1,0,1,0><<<dim3(4,64), b512, 0, stream>>>(T1, FW2T, fb2, nullptr, R2B,
                                                        R2, nullptr, nullptr, nullptr, BL_, D_, DI_);
}